// Round 1
// 316.274 us; speedup vs baseline: 1.0329x; 1.0329x over previous
//
#include <hip/hip_runtime.h>
#include <hip/hip_fp16.h>
#include <hip/hip_fp8.h>
#include <math.h>

// ---------------- problem constants ----------------
constexpr int NN   = 50000;          // nodes
constexpr int NE   = 800000;         // edges (before self loops)
constexpr int ETOT = NE + NN;        // 850000 with self loops
constexpr int F_IN = 128;
constexpr int HID  = 64;
constexpr int HEADS = 4;
constexpr int HC1  = HEADS * HID;    // 256
constexpr int NG   = 64;             // graphs
constexpr float SLOPE = 0.2f;
constexpr int TW_TOT = F_IN * HC1 + HC1 * HID;   // transpose work items (49152)
constexpr int CAP  = 128;            // bucket capacity per dst (max deg ~45 for this input)
constexpr int GEMM1_B = NN / 16;     // 3125 gemm blocks

// ---- two-phase counting scatter ----
// Phase 1: LDS histogram over coarse buckets (cb = d>>8) + ONE global atomic per
//          (block, touched bucket) to reserve a contiguous chunk -> ~81K global
//          atomics instead of 850K returning atomics (the measured serializer).
// Phase 2: one block owns one coarse bucket exclusively -> final slot assignment
//          is pure LDS atomics, bucket writes land in a 128KB L2-resident window.
constexpr int NCB  = 196;            // coarse buckets: d < 50000 -> d>>8 < 196
constexpr int CCAP = 6144;           // per-coarse-bucket capacity (mean 4337, sigma ~66)
constexpr int CPAD = 16;             // pad coarse counters: 1 per 64B line
constexpr int SEPB = 2048;           // edges per scatter block (8 per thread)
constexpr int SCAT2_B = (ETOT + SEPB - 1) / SEPB;   // 416 scatter blocks

typedef _Float16 half8 __attribute__((ext_vector_type(8)));
typedef float f32x4 __attribute__((ext_vector_type(4)));

__device__ __forceinline__ float lrelu(float v) { return v >= 0.f ? v : SLOPE * v; }
__device__ __forceinline__ float elu(float v) { return v > 0.f ? v : expm1f(v); }

// pack 8 floats -> 8 fp16 as one uint4
__device__ __forceinline__ uint4 pack8_h(const float* v) {
  union { __half2 h[4]; uint4 u; } pk;
  pk.h[0] = __floats2half2_rn(v[0], v[1]);
  pk.h[1] = __floats2half2_rn(v[2], v[3]);
  pk.h[2] = __floats2half2_rn(v[4], v[5]);
  pk.h[3] = __floats2half2_rn(v[6], v[7]);
  return pk.u;
}

// ---- fp8 e4m3 helpers (OCP; gfx950 HW cvt when available) ----
__device__ __forceinline__ unsigned pack_fp8x4(float a, float b, float c, float d) {
#if __has_builtin(__builtin_amdgcn_cvt_pk_fp8_f32)
  int v = 0;
  v = __builtin_amdgcn_cvt_pk_fp8_f32(a, b, v, false);
  v = __builtin_amdgcn_cvt_pk_fp8_f32(c, d, v, true);
  return (unsigned)v;
#else
  __hip_fp8_e4m3 fa(a), fb(b), fc(c), fd(d);
  return (unsigned)fa.__x | ((unsigned)fb.__x << 8) |
         ((unsigned)fc.__x << 16) | ((unsigned)fd.__x << 24);
#endif
}

__device__ __forceinline__ float fp8_1(unsigned byte) {   // manual e4m3fn -> f32
  unsigned s = (byte & 0x80u) << 24;
  unsigned em = (byte & 0x7fu) << 20;
  return __uint_as_float(s | em) * 0x1p+120f;
}

// scalar-form fp8x4 accumulate (R12-measured best)
__device__ __forceinline__ void fma_fp8x4(float* acc, unsigned v, float alpha) {
#if __has_builtin(__builtin_amdgcn_cvt_pk_f32_fp8)
  auto lo = __builtin_amdgcn_cvt_pk_f32_fp8((int)v, false);
  auto hi = __builtin_amdgcn_cvt_pk_f32_fp8((int)v, true);
  acc[0] += alpha * lo[0]; acc[1] += alpha * lo[1];
  acc[2] += alpha * hi[0]; acc[3] += alpha * hi[1];
#else
  acc[0] += alpha * fp8_1(v & 0xffu);
  acc[1] += alpha * fp8_1((v >> 8) & 0xffu);
  acc[2] += alpha * fp8_1((v >> 16) & 0xffu);
  acc[3] += alpha * fp8_1(v >> 24);
#endif
}

// ================= prep: weight transposes + coarse-cnt zeroing ======================
__global__ void prep_kernel(const float* __restrict__ W1, const float* __restrict__ W2,
                            __half* __restrict__ W1T, __half* __restrict__ W2T,
                            int* __restrict__ ccnt) {
  int i = blockIdx.x * blockDim.x + threadIdx.x;
  if (i < F_IN * HC1) {                       // W1 [128][256] -> W1T [256][128]
    int k = i / HC1, n = i - k * HC1;
    W1T[n * F_IN + k] = __float2half(W1[i]);
  } else if (i < TW_TOT) {                    // W2 [256][64] -> W2T [64][256]
    int j = i - F_IN * HC1;
    int k = j / HID, n = j - k * HID;
    W2T[n * HC1 + k] = __float2half(W2[j]);
  } else if (i < TW_TOT + NCB * CPAD) {
    ccnt[i - TW_TOT] = 0;
  }
}

// ================= mega kernel: coarse-scatter blocks || gemm1 blocks ================
// blocks [0, SCAT2_B): phase-1 coarse scatter (LDS histogram + chunk reservation)
// blocks [SCAT2_B, SCAT2_B+GEMM1_B): h1 = fp8(x @ W1) + attention scores (MFMA)
__global__ __launch_bounds__(256) void gemm1_scatter_kernel(
    const float* __restrict__ x, const __half* __restrict__ W1T,
    const float* __restrict__ asrc, const float* __restrict__ adst,
    unsigned char* __restrict__ h1, float* __restrict__ ssrc, float* __restrict__ sdst,
    const int* __restrict__ esrc, const int* __restrict__ edst,
    int* __restrict__ ccnt, int* __restrict__ coarse) {
  const int t = threadIdx.x;
  if (blockIdx.x < SCAT2_B) {
    // ---- phase-1 scatter ----
    __shared__ int hist[NCB];
    __shared__ int hbase[NCB];
    if (t < NCB) hist[t] = 0;
    __syncthreads();
    const int e0 = blockIdx.x * SEPB + t * 8;
    const bool valid = e0 < ETOT;             // ETOT%8==0, e0%8==0 -> all-or-nothing
    int sarr[8], darr[8];
    if (valid) {
      if (e0 < NE) {                          // NE%8==0 -> no straddle
        int4 a = *(const int4*)(esrc + e0);
        int4 b = *(const int4*)(esrc + e0 + 4);
        int4 c = *(const int4*)(edst + e0);
        int4 d4 = *(const int4*)(edst + e0 + 4);
        sarr[0]=a.x; sarr[1]=a.y; sarr[2]=a.z; sarr[3]=a.w;
        sarr[4]=b.x; sarr[5]=b.y; sarr[6]=b.z; sarr[7]=b.w;
        darr[0]=c.x; darr[1]=c.y; darr[2]=c.z; darr[3]=c.w;
        darr[4]=d4.x; darr[5]=d4.y; darr[6]=d4.z; darr[7]=d4.w;
      } else {                                // self-loops
#pragma unroll
        for (int k = 0; k < 8; ++k) { sarr[k] = e0 - NE + k; darr[k] = sarr[k]; }
      }
    }
    int cbv[8], lv[8], pkv[8];
    if (valid) {
#pragma unroll
      for (int k = 0; k < 8; ++k) {
        int d = darr[k];
        cbv[k] = d >> 8;
        pkv[k] = sarr[k] | ((d & 255) << 16);      // src < 65536 fits 16 bits
        lv[k]  = atomicAdd(&hist[cbv[k]], 1);      // LDS atomic (cheap)
      }
    }
    __syncthreads();
    if (t < NCB) {
      int c = hist[t];
      hbase[t] = c ? atomicAdd(&ccnt[t * CPAD], c) : 0;   // ~196 global atomics/block
    }
    __syncthreads();
    if (valid) {
#pragma unroll
      for (int k = 0; k < 8; ++k) {
        int b = hbase[cbv[k]] + lv[k];
        if (b < CCAP) coarse[cbv[k] * CCAP + b] = pkv[k];
      }
    }
    return;
  }
  // ---- gemm1 part ----
  __shared__ float hs[16][HC1 + 1];
  const int m0 = (blockIdx.x - SCAT2_B) * 16;
  const int wv = t >> 6, lane = t & 63;
  const int lm = lane & 15, quad = lane >> 4;
  const int n0 = wv * 64;
  f32x4 acc[4] = {{0.f,0.f,0.f,0.f},{0.f,0.f,0.f,0.f},{0.f,0.f,0.f,0.f},{0.f,0.f,0.f,0.f}};
  const float* arow = x + (size_t)(m0 + lm) * F_IN + quad * 8;
#pragma unroll
  for (int kc = 0; kc < F_IN; kc += 32) {
    float4 u = *(const float4*)(arow + kc);
    float4 v = *(const float4*)(arow + kc + 4);
    half8 a;
    a[0]=(_Float16)u.x; a[1]=(_Float16)u.y; a[2]=(_Float16)u.z; a[3]=(_Float16)u.w;
    a[4]=(_Float16)v.x; a[5]=(_Float16)v.y; a[6]=(_Float16)v.z; a[7]=(_Float16)v.w;
#pragma unroll
    for (int tn = 0; tn < 4; ++tn) {
      half8 b = *(const half8*)(W1T + (size_t)(n0 + tn * 16 + lm) * F_IN + kc + quad * 8);
      acc[tn] = __builtin_amdgcn_mfma_f32_16x16x32_f16(a, b, acc[tn], 0, 0, 0);
    }
  }
#pragma unroll
  for (int tn = 0; tn < 4; ++tn)
#pragma unroll
    for (int r = 0; r < 4; ++r)
      hs[quad * 4 + r][n0 + tn * 16 + lm] = acc[tn][r];
  __syncthreads();
  // h1 fp8 write: 16 rows x 256 ch; thread t -> row t>>4, 16 ch at (t&15)*16
  {
    int row = t >> 4, cb = (t & 15) * 16;
    const float* hr = &hs[row][cb];
    uint4 pk;
    pk.x = pack_fp8x4(hr[0],  hr[1],  hr[2],  hr[3]);
    pk.y = pack_fp8x4(hr[4],  hr[5],  hr[6],  hr[7]);
    pk.z = pack_fp8x4(hr[8],  hr[9],  hr[10], hr[11]);
    pk.w = pack_fp8x4(hr[12], hr[13], hr[14], hr[15]);
    *(uint4*)(h1 + (size_t)(m0 + row) * HC1 + cb) = pk;
  }
  // scores: 128 tasks (16 rows x 4 heads x {src,dst}) x 2 threads each
  {
    int task = t >> 1, part = t & 1;
    int r = task >> 3, hh = (task >> 1) & 3, isdst = task & 1;
    const float* a = isdst ? adst : asrc;
    float s = 0.f;
    int c0 = part * 32;
    for (int c = c0; c < c0 + 32; ++c) s += hs[r][hh * HID + c] * a[hh * HID + c];
    s += __shfl_xor(s, 1, 64);
    if (part == 0) (isdst ? sdst : ssrc)[(m0 + r) * HEADS + hh] = s;
  }
}

// ================= phase-2: build per-dst buckets from coarse buckets ================
// One block per coarse bucket -> exclusive ownership of 256 dst values -> slot
// assignment is pure LDS atomics; bucket writes confined to a 128KB window.
__global__ __launch_bounds__(1024) void bucket_build_kernel(
    const int* __restrict__ ccnt, const int* __restrict__ coarse,
    int* __restrict__ cnt, int* __restrict__ bucket) {
  __shared__ int hist2[256];
  const int cb = blockIdx.x, t = threadIdx.x;
  if (t < 256) hist2[t] = 0;
  __syncthreads();
  const int n = min(ccnt[cb * CPAD], CCAP);
  const int* cbase = coarse + cb * CCAP;
  int j = t;
  int v = (j < n) ? cbase[j] : 0;
  while (j < n) {
    int jn = j + 1024;
    int vn = (jn < n) ? cbase[jn] : 0;        // prefetch next round
    int s = v & 0xFFFF, dlow = (v >> 16) & 0xFF;
    int l = atomicAdd(&hist2[dlow], 1);
    if (l < CAP) bucket[(size_t)((cb << 8) | dlow) * CAP + l] = s;
    j = jn; v = vn;
  }
  __syncthreads();
  int d = (cb << 8) | t;
  if (t < 256 && d < NN) cnt[d] = hist2[t];
}

// ================= fused GAT gather, layer 1 (H=4, fp8 h): one wave per dst ===========
__global__ __launch_bounds__(256) void gat_gather4_kernel(
    const int* __restrict__ cnt, const int* __restrict__ bucket,
    const float* __restrict__ ss, const float* __restrict__ sd,
    const unsigned char* __restrict__ h, const float* __restrict__ bias,
    __half* __restrict__ outp) {
  const int d    = (blockIdx.x * 256 + threadIdx.x) >> 6;
  const int lane = threadIdx.x & 63;
  if (d >= NN) return;
  const int start = d * CAP;
  const int deg   = min(cnt[d], CAP);
  const int hsel  = lane & 3;     // score-phase head
  const int eg    = lane >> 4;    // agg edge subgroup (0..3)
  const int cpos  = lane & 15;    // 16B chunk within 256B row
  const int hh    = cpos >> 2;    // agg-phase head of these channels
  const float sdv = sd[d * 4 + hsel];
  float accv[16];
#pragma unroll
  for (int k = 0; k < 16; ++k) accv[k] = 0.f;

  auto agg4 = [&](int sj, float alpha) {
    uint4 u = *(const uint4*)(h + (unsigned)(sj * HC1 + cpos * 16));   // 32-bit addressing
    fma_fp8x4(accv + 0,  u.x, alpha);
    fma_fp8x4(accv + 4,  u.y, alpha);
    fma_fp8x4(accv + 8,  u.z, alpha);
    fma_fp8x4(accv + 12, u.w, alpha);
  };

  if (deg <= 32) {
    const int j0 = lane >> 2;
    int s0 = 0, s1 = 0;
    float v0 = -INFINITY, v1 = -INFINITY;
    if (j0 < deg)      { s0 = bucket[start + j0];      v0 = lrelu(ss[s0 * 4 + hsel] + sdv); }
    if (j0 + 16 < deg) { s1 = bucket[start + j0 + 16]; v1 = lrelu(ss[s1 * 4 + hsel] + sdv); }
    float mx = fmaxf(v0, v1);
#pragma unroll
    for (int o = 4; o < 64; o <<= 1) mx = fmaxf(mx, __shfl_xor(mx, o, 64));
    float p0 = (j0 < deg)      ? __expf(v0 - mx) : 0.f;
    float p1 = (j0 + 16 < deg) ? __expf(v1 - mx) : 0.f;
    float den = p0 + p1;
#pragma unroll
    for (int o = 4; o < 64; o <<= 1) den += __shfl_xor(den, o, 64);
    const float inv = 1.f / (den + 1e-16f);
    const float pa0 = p0 * inv, pa1 = p1 * inv;
    const int m1 = min(deg, 16);
    for (int j = 0; j < m1; j += 8) {
      {
        int jj = j + eg;
        bool ok = jj < m1;
        float alpha = ok ? __shfl(pa0, jj * 4 + hh, 64) : 0.f;
        int   sj    = __shfl(s0, (ok ? jj : 0) * 4, 64);
        agg4(sj, alpha);
      }
      if (j + 4 < m1) {                         // wave-uniform gate
        int jj = j + 4 + eg;
        bool ok = jj < m1;
        float alpha = ok ? __shfl(pa0, jj * 4 + hh, 64) : 0.f;
        int   sj    = __shfl(s0, (ok ? jj : 0) * 4, 64);
        agg4(sj, alpha);
      }
    }
    if (deg > 16) {
      for (int j = 16; j < deg; j += 8) {
        {
          int jj = j + eg;
          bool ok = jj < deg;
          int i1 = jj - 16;
          float alpha = ok ? __shfl(pa1, i1 * 4 + hh, 64) : 0.f;
          int   sj    = __shfl(s1, (ok ? i1 : 0) * 4, 64);
          agg4(sj, alpha);
        }
        if (j + 4 < deg) {                      // wave-uniform gate
          int jj = j + 4 + eg;
          bool ok = jj < deg;
          int i1 = jj - 16;
          float alpha = ok ? __shfl(pa1, (ok ? i1 : 0) * 4 + hh, 64) : 0.f;
          int   sj    = __shfl(s1, (ok ? i1 : 0) * 4, 64);
          agg4(sj, alpha);
        }
      }
    }
  } else {
    // chunked (rare for this input): 16 edges per chunk
    float mx = -INFINITY;
    for (int base = 0; base < deg; base += 16) {
      int j = base + (lane >> 2);
      float v = (j < deg) ? lrelu(ss[bucket[start + j] * 4 + hsel] + sdv) : -INFINITY;
#pragma unroll
      for (int o = 4; o < 64; o <<= 1) v = fmaxf(v, __shfl_xor(v, o, 64));
      mx = fmaxf(mx, v);
    }
    float den = 0.f;
    for (int base = 0; base < deg; base += 16) {
      int j = base + (lane >> 2);
      float p = (j < deg) ? __expf(lrelu(ss[bucket[start + j] * 4 + hsel] + sdv) - mx) : 0.f;
#pragma unroll
      for (int o = 4; o < 64; o <<= 1) p += __shfl_xor(p, o, 64);
      den += p;
    }
    const float inv = 1.f / (den + 1e-16f);
    for (int base = 0; base < deg; base += 16) {
      int j = base + (lane >> 2);
      int s = 0; float pa = 0.f;
      if (j < deg) {
        s = bucket[start + j];
        pa = __expf(lrelu(ss[s * 4 + hsel] + sdv) - mx) * inv;
      }
      int cnt2 = min(16, deg - base);
      for (int jc = 0; jc < cnt2; jc += 4) {
        int jj = jc + eg;
        bool ok = jj < cnt2;
        float alpha = ok ? __shfl(pa, jj * 4 + hh, 64) : 0.f;
        int   sj    = __shfl(s, (ok ? jj : 0) * 4, 64);
        agg4(sj, alpha);
      }
    }
  }
  // combine the 4 edge subgroups, lanes 0..15 write the fp16 row
#pragma unroll
  for (int o = 16; o < 64; o <<= 1) {
#pragma unroll
    for (int k = 0; k < 16; ++k) accv[k] += __shfl_xor(accv[k], o, 64);
  }
  if (eg == 0) {
    float e[16];
#pragma unroll
    for (int k = 0; k < 16; ++k) e[k] = elu(accv[k] + bias[cpos * 16 + k]);
    __half* op = outp + (size_t)d * HC1 + cpos * 16;
    *(uint4*)op = pack8_h(e);
    *(uint4*)(op + 8) = pack8_h(e + 8);
  }
}

// ================= gemm2 (MFMA): 256 threads, 4 waves x 1 col-tile; h2 out fp8 =========
__global__ __launch_bounds__(256) void gemm2_mfma(
    const __half* __restrict__ o1h, const __half* __restrict__ W2T,
    const float* __restrict__ asrc, const float* __restrict__ adst,
    unsigned char* __restrict__ h2, float* __restrict__ ssrc, float* __restrict__ sdst) {
  __shared__ float hs[16][HID + 1];
  const int m0 = blockIdx.x * 16;
  const int t = threadIdx.x;
  const int wv = t >> 6, lane = t & 63;
  const int lm = lane & 15, quad = lane >> 4;
  f32x4 acc = {0.f, 0.f, 0.f, 0.f};
  const __half* arow = o1h + (size_t)(m0 + lm) * HC1 + quad * 8;
#pragma unroll
  for (int kc = 0; kc < HC1; kc += 32) {
    half8 a = *(const half8*)(arow + kc);
    half8 b = *(const half8*)(W2T + (size_t)(wv * 16 + lm) * HC1 + kc + quad * 8);
    acc = __builtin_amdgcn_mfma_f32_16x16x32_f16(a, b, acc, 0, 0, 0);
  }
#pragma unroll
  for (int r = 0; r < 4; ++r)
    hs[quad * 4 + r][wv * 16 + lm] = acc[r];
  __syncthreads();
  {
    int row = t >> 4, c4 = (t & 15) * 4;
    unsigned pk = pack_fp8x4(hs[row][c4], hs[row][c4 + 1], hs[row][c4 + 2], hs[row][c4 + 3]);
    *(unsigned*)(h2 + (size_t)(m0 + row) * HID + c4) = pk;
  }
  if (t < 64) {
    int task = t >> 1, part = t & 1;
    int r = task >> 1, isdst = task & 1;
    const float* a = isdst ? adst : asrc;
    float s = 0.f;
    int c0 = part * 32;
    for (int c = c0; c < c0 + 32; ++c) s += hs[r][c] * a[c];
    s += __shfl_xor(s, 1, 64);
    if (part == 0) (isdst ? sdst : ssrc)[m0 + r] = s;
  }
}

// ================= fused GAT gather, layer 2 (H=1, fp8 h): one wave per dst =========
__global__ __launch_bounds__(256) void gat_gather1_kernel(
    const int* __restrict__ cnt, const int* __restrict__ bucket,
    const float* __restrict__ ss, const float* __restrict__ sd,
    const unsigned char* __restrict__ h, const float* __restrict__ bias,
    float* __restrict__ outp) {
  const int d    = (blockIdx.x * 256 + threadIdx.x) >> 6;
  const int lane = threadIdx.x & 63;
  if (d >= NN) return;
  const int start = d * CAP;
  const int deg   = min(cnt[d], CAP);
  const int eg   = lane >> 3;     // edge subgroup (0..7)
  const int cpos = lane & 7;      // 8B chunk within 64B fp8 row
  const float sdv = sd[d];
  float accv[8] = {0.f,0.f,0.f,0.f,0.f,0.f,0.f,0.f};

  auto agg8 = [&](int sj, float alpha) {
    uint2 u = *(const uint2*)(h + (unsigned)(sj * HID + cpos * 8));   // 32-bit addressing
    fma_fp8x4(accv + 0, u.x, alpha);
    fma_fp8x4(accv + 4, u.y, alpha);
  };

  if (deg <= 64) {
    int s = 0; float v = -INFINITY;
    if (lane < deg) { s = bucket[start + lane]; v = lrelu(ss[s] + sdv); }
    float mx = v;
#pragma unroll
    for (int o = 1; o < 64; o <<= 1) mx = fmaxf(mx, __shfl_xor(mx, o, 64));
    float p = (lane < deg) ? __expf(v - mx) : 0.f;
    float den = p;
#pragma unroll
    for (int o = 1; o < 64; o <<= 1) den += __shfl_xor(den, o, 64);
    const float pa = p / (den + 1e-16f);
    for (int j = 0; j < deg; j += 16) {
      {
        int jj = j + eg;
        float alpha = (jj < deg) ? __shfl(pa, jj < 63 ? jj : 63, 64) : 0.f;
        int   sj    = __shfl(s, jj < 63 ? jj : 63, 64);
        agg8(sj, alpha);
      }
      if (j + 8 < deg) {                        // wave-uniform gate
        int jj = j + 8 + eg;
        float alpha = (jj < deg) ? __shfl(pa, jj < 63 ? jj : 63, 64) : 0.f;
        int   sj    = __shfl(s, jj < 63 ? jj : 63, 64);
        agg8(sj, alpha);
      }
    }
  } else {
    float mx = -INFINITY;
    for (int base = 0; base < deg; base += 64) {
      int j = base + lane;
      float v = (j < deg) ? lrelu(ss[bucket[start + j]] + sdv) : -INFINITY;
#pragma unroll
      for (int o = 1; o < 64; o <<= 1) v = fmaxf(v, __shfl_xor(v, o, 64));
      mx = fmaxf(mx, v);
    }
    float den = 0.f;
    for (int base = 0; base < deg; base += 64) {
      int j = base + lane;
      float p = (j < deg) ? __expf(lrelu(ss[bucket[start + j]] + sdv) - mx) : 0.f;
#pragma unroll
      for (int o = 1; o < 64; o <<= 1) p += __shfl_xor(p, o, 64);
      den += p;
    }
    const float inv = 1.f / (den + 1e-16f);
    for (int base = 0; base < deg; base += 64) {
      int j = base + lane;
      int s = 0; float pa = 0.f;
      if (j < deg) { s = bucket[start + j]; pa = __expf(lrelu(ss[s] + sdv) - mx) * inv; }
      int cnt2 = min(64, deg - base);
      for (int jc = 0; jc < cnt2; jc += 8) {
        int jj = jc + eg;
        float alpha = (jj < cnt2) ? __shfl(pa, jj < 63 ? jj : 63, 64) : 0.f;
        int   sj    = __shfl(s, jj < 63 ? jj : 63, 64);
        agg8(sj, alpha);
      }
    }
  }
#pragma unroll
  for (int o = 8; o < 64; o <<= 1) {
#pragma unroll
    for (int k = 0; k < 8; ++k) accv[k] += __shfl_xor(accv[k], o, 64);
  }
  if (eg == 0) {
    float4 r0, r1;
    r0.x = elu(accv[0] + bias[cpos * 8 + 0]);
    r0.y = elu(accv[1] + bias[cpos * 8 + 1]);
    r0.z = elu(accv[2] + bias[cpos * 8 + 2]);
    r0.w = elu(accv[3] + bias[cpos * 8 + 3]);
    r1.x = elu(accv[4] + bias[cpos * 8 + 4]);
    r1.y = elu(accv[5] + bias[cpos * 8 + 5]);
    r1.z = elu(accv[6] + bias[cpos * 8 + 6]);
    r1.w = elu(accv[7] + bias[cpos * 8 + 7]);
    float* op = outp + (size_t)d * HID + cpos * 8;
    *(float4*)op = r0;
    *(float4*)(op + 4) = r1;
  }
}

// ---------------- fused pool + FC + log_softmax (gstart inline): one block/graph -------
__global__ __launch_bounds__(1024) void pool_head_kernel(const float* __restrict__ o2,
                                                         const int* __restrict__ batch,
                                                         const float* __restrict__ fcw,
                                                         const float* __restrict__ fcb,
                                                         float* __restrict__ out) {
  __shared__ float red[16][HID];
  __shared__ int sbound[2];
  int g = blockIdx.x;
  int t = threadIdx.x;
  if (t < 2) {                         // graph boundaries via binary search
    int gg = g + t, lo = 0, hi = NN;
    while (lo < hi) { int mid = (lo + hi) >> 1; if (batch[mid] < gg) lo = mid + 1; else hi = mid; }
    sbound[t] = lo;
  }
  __syncthreads();
  int s0 = sbound[0], s1 = sbound[1];
  int c = t & 63, r = t >> 6;          // 16 node-rows in flight
  float acc = 0.f;
  for (int n = s0 + r; n < s1; n += 16) acc += o2[(size_t)n * HID + c];
  red[r][c] = acc;
  __syncthreads();
  if (r == 0) {                        // threads 0..63 = one wave
    float v = 0.f;
#pragma unroll
    for (int k = 0; k < 16; ++k) v += red[k][c];
    v /= fmaxf((float)(s1 - s0), 1.f);
    float p0 = v * fcw[c * 2 + 0];
    float p1 = v * fcw[c * 2 + 1];
#pragma unroll
    for (int o = 1; o < 64; o <<= 1) {
      p0 += __shfl_xor(p0, o, 64);
      p1 += __shfl_xor(p1, o, 64);
    }
    if (c == 0) {
      float l0 = p0 + fcb[0], l1 = p1 + fcb[1];
      float mx = fmaxf(l0, l1);
      float lse = mx + logf(expf(l0 - mx) + expf(l1 - mx));
      out[g * 2 + 0] = l0 - lse;
      out[g * 2 + 1] = l1 - lse;
    }
  }
}

// ---------------- launch ----------------
extern "C" void kernel_launch(void* const* d_in, const int* in_sizes, int n_in,
                              void* d_out, int out_size, void* d_ws, size_t ws_size,
                              hipStream_t stream) {
  const float* x    = (const float*)d_in[0];
  const int*   ei   = (const int*)d_in[1];
  const int*   batch= (const int*)d_in[2];
  const float* W1   = (const float*)d_in[3];
  const float* as1  = (const float*)d_in[4];
  const float* ad1  = (const float*)d_in[5];
  const float* b1   = (const float*)d_in[6];
  const float* W2   = (const float*)d_in[7];
  const float* as2  = (const float*)d_in[8];
  const float* ad2  = (const float*)d_in[9];
  const float* b2   = (const float*)d_in[10];
  const float* fcw  = (const float*)d_in[11];
  const float* fcb  = (const float*)d_in[12];
  float* out = (float*)d_out;
  float* ws  = (float*)d_ws;

  const int* esrc = ei;
  const int* edst = ei + NE;

  // ---- workspace layout (float units) ----
  size_t off = 0;
  float* hreg  = ws + off; off += (size_t)NN * HC1 / 4;  // h1 fp8 [NN,256]
  float* o1reg = ws + off; off += (size_t)NN * HC1 / 2;  // o1 fp16 [NN,256]
  float* l2reg = ws + off; off += (size_t)NN * HC1 / 2;  // h2 fp8 + o2 fp32 (also coarse, earlier)
  float* ss1 = ws + off; off += (size_t)NN * HEADS;
  float* sd1 = ws + off; off += (size_t)NN * HEADS;
  float* ss2 = ws + off; off += NN;
  float* sd2 = ws + off; off += NN;
  __half* W1T = (__half*)(ws + off); off += (size_t)HC1 * F_IN / 2;
  __half* W2T = (__half*)(ws + off); off += (size_t)HID * HC1 / 2;
  int* bucket = (int*)(ws + off); off += (size_t)NN * CAP;   // 25.6 MB
  int* cnt    = (int*)(ws + off); off += NN;                 // fully written by phase-2
  unsigned char* h1 = (unsigned char*)hreg;            // [NN, 256] fp8 e4m3
  __half* o1h = (__half*)o1reg;                        // [NN, 256] fp16
  unsigned char* h2 = (unsigned char*)l2reg;           // [NN, 64] fp8 e4m3
  float*  o2  = l2reg + (size_t)NN * HID / 4;          // [NN, 64] fp32
  // coarse scatter buffers alias l2reg (dead until gemm2): 4.83 MB < 25.6 MB
  int* coarse = (int*)l2reg;                           // [NCB][CCAP] packed (src | dlow<<16)
  int* ccnt   = (int*)l2reg + (size_t)NCB * CCAP;      // [NCB*CPAD] padded counters

  // ---- prep: transposes + coarse-cnt zero ----
  prep_kernel<<<(TW_TOT + NCB * CPAD + 255) / 256, 256, 0, stream>>>(W1, W2, W1T, W2T, ccnt);

  // ---- phase-1 coarse scatter || layer-1 GEMM (independent; co-scheduled) ----
  gemm1_scatter_kernel<<<SCAT2_B + GEMM1_B, 256, 0, stream>>>(
      x, W1T, as1, ad1, h1, ss1, sd1, esrc, edst, ccnt, coarse);

  // ---- phase-2: LDS-atomic bucket build (one block per coarse bucket) ----
  bucket_build_kernel<<<NCB, 1024, 0, stream>>>(ccnt, coarse, cnt, bucket);

  // ---- layer 1 gather ----
  gat_gather4_kernel<<<(NN + 3) / 4, 256, 0, stream>>>(cnt, bucket, ss1, sd1, h1, b1, o1h);

  // ---- layer 2 ----
  gemm2_mfma<<<NN / 16, 256, 0, stream>>>(o1h, W2T, as2, ad2, h2, ss2, sd2);
  gat_gather1_kernel<<<(NN + 3) / 4, 256, 0, stream>>>(cnt, bucket, ss2, sd2, h2, b2, o2);

  // ---- pool + head (fused, gstart inline) ----
  pool_head_kernel<<<NG, 1024, 0, stream>>>(o2, batch, fcw, fcb, out);
}

// Round 2
// 314.540 us; speedup vs baseline: 1.0386x; 1.0055x over previous
//
#include <hip/hip_runtime.h>
#include <hip/hip_fp16.h>
#include <hip/hip_fp8.h>
#include <math.h>

// ---------------- problem constants ----------------
constexpr int NN   = 50000;          // nodes
constexpr int NE   = 800000;         // edges (before self loops)
constexpr int ETOT = NE + NN;        // 850000 with self loops
constexpr int F_IN = 128;
constexpr int HID  = 64;
constexpr int HEADS = 4;
constexpr int HC1  = HEADS * HID;    // 256
constexpr int NG   = 64;             // graphs
constexpr float SLOPE = 0.2f;
constexpr int TW_TOT = F_IN * HC1 + HC1 * HID;   // transpose work items (49152)
constexpr int CAP  = 128;            // bucket capacity per dst (max deg ~45 for this input)
constexpr int GEMM1_B = NN / 16;     // 3125 gemm blocks

// ---- two-phase counting scatter ----
constexpr int NCB  = 196;            // coarse buckets: d < 50000 -> d>>8 < 196
constexpr int CCAP = 6144;           // per-coarse-bucket capacity (mean 4337, sigma ~66)
constexpr int CPAD = 16;             // pad coarse counters: 1 per 64B line
constexpr int SEPB = 2048;           // edges per scatter block (8 per thread)
constexpr int SCAT2_B = (ETOT + SEPB - 1) / SEPB;   // 416 scatter blocks

typedef _Float16 half8 __attribute__((ext_vector_type(8)));
typedef float f32x4 __attribute__((ext_vector_type(4)));
typedef float f32x2 __attribute__((ext_vector_type(2)));

__device__ __forceinline__ float lrelu(float v) { return v >= 0.f ? v : SLOPE * v; }
__device__ __forceinline__ float elu(float v) { return v > 0.f ? v : expm1f(v); }

// pack 8 floats -> 8 fp16 as one uint4
__device__ __forceinline__ uint4 pack8_h(const float* v) {
  union { __half2 h[4]; uint4 u; } pk;
  pk.h[0] = __floats2half2_rn(v[0], v[1]);
  pk.h[1] = __floats2half2_rn(v[2], v[3]);
  pk.h[2] = __floats2half2_rn(v[4], v[5]);
  pk.h[3] = __floats2half2_rn(v[6], v[7]);
  return pk.u;
}

// ---- fp8 e4m3 helpers (OCP; gfx950 HW cvt when available) ----
__device__ __forceinline__ unsigned pack_fp8x4(float a, float b, float c, float d) {
#if __has_builtin(__builtin_amdgcn_cvt_pk_fp8_f32)
  int v = 0;
  v = __builtin_amdgcn_cvt_pk_fp8_f32(a, b, v, false);
  v = __builtin_amdgcn_cvt_pk_fp8_f32(c, d, v, true);
  return (unsigned)v;
#else
  __hip_fp8_e4m3 fa(a), fb(b), fc(c), fd(d);
  return (unsigned)fa.__x | ((unsigned)fb.__x << 8) |
         ((unsigned)fc.__x << 16) | ((unsigned)fd.__x << 24);
#endif
}

__device__ __forceinline__ float fp8_1(unsigned byte) {   // manual e4m3fn -> f32
  unsigned s = (byte & 0x80u) << 24;
  unsigned em = (byte & 0x7fu) << 20;
  return __uint_as_float(s | em) * 0x1p+120f;
}

// packed-f32 fp8x4 accumulate: 2 cvt_pk + 2 v_pk_fma_f32 (vs 2 cvt + 4 scalar fma).
// Same per-channel arithmetic order as the scalar form -> bit-identical results.
__device__ __forceinline__ void fma_fp8x4_pk(f32x2* acc, unsigned v, f32x2 a2) {
#if __has_builtin(__builtin_amdgcn_cvt_pk_f32_fp8)
  f32x2 lo = __builtin_amdgcn_cvt_pk_f32_fp8((int)v, false);
  f32x2 hi = __builtin_amdgcn_cvt_pk_f32_fp8((int)v, true);
  asm("v_pk_fma_f32 %0, %1, %2, %0" : "+v"(acc[0]) : "v"(lo), "v"(a2));
  asm("v_pk_fma_f32 %0, %1, %2, %0" : "+v"(acc[1]) : "v"(hi), "v"(a2));
#else
  float alpha = a2[0];
  acc[0][0] += alpha * fp8_1(v & 0xffu);
  acc[0][1] += alpha * fp8_1((v >> 8) & 0xffu);
  acc[1][0] += alpha * fp8_1((v >> 16) & 0xffu);
  acc[1][1] += alpha * fp8_1(v >> 24);
#endif
}

// ================= prep: weight transposes + coarse-cnt zeroing ======================
__global__ void prep_kernel(const float* __restrict__ W1, const float* __restrict__ W2,
                            __half* __restrict__ W1T, __half* __restrict__ W2T,
                            int* __restrict__ ccnt) {
  int i = blockIdx.x * blockDim.x + threadIdx.x;
  if (i < F_IN * HC1) {                       // W1 [128][256] -> W1T [256][128]
    int k = i / HC1, n = i - k * HC1;
    W1T[n * F_IN + k] = __float2half(W1[i]);
  } else if (i < TW_TOT) {                    // W2 [256][64] -> W2T [64][256]
    int j = i - F_IN * HC1;
    int k = j / HID, n = j - k * HID;
    W2T[n * HC1 + k] = __float2half(W2[j]);
  } else if (i < TW_TOT + NCB * CPAD) {
    ccnt[i - TW_TOT] = 0;
  }
}

// ================= mega kernel: coarse-scatter blocks || gemm1 blocks ================
__global__ __launch_bounds__(256) void gemm1_scatter_kernel(
    const float* __restrict__ x, const __half* __restrict__ W1T,
    const float* __restrict__ asrc, const float* __restrict__ adst,
    unsigned char* __restrict__ h1, float* __restrict__ ssrc, float* __restrict__ sdst,
    const int* __restrict__ esrc, const int* __restrict__ edst,
    int* __restrict__ ccnt, int* __restrict__ coarse) {
  const int t = threadIdx.x;
  if (blockIdx.x < SCAT2_B) {
    // ---- phase-1 scatter ----
    __shared__ int hist[NCB];
    __shared__ int hbase[NCB];
    if (t < NCB) hist[t] = 0;
    __syncthreads();
    const int e0 = blockIdx.x * SEPB + t * 8;
    const bool valid = e0 < ETOT;             // ETOT%8==0, e0%8==0 -> all-or-nothing
    int sarr[8], darr[8];
    if (valid) {
      if (e0 < NE) {                          // NE%8==0 -> no straddle
        int4 a = *(const int4*)(esrc + e0);
        int4 b = *(const int4*)(esrc + e0 + 4);
        int4 c = *(const int4*)(edst + e0);
        int4 d4 = *(const int4*)(edst + e0 + 4);
        sarr[0]=a.x; sarr[1]=a.y; sarr[2]=a.z; sarr[3]=a.w;
        sarr[4]=b.x; sarr[5]=b.y; sarr[6]=b.z; sarr[7]=b.w;
        darr[0]=c.x; darr[1]=c.y; darr[2]=c.z; darr[3]=c.w;
        darr[4]=d4.x; darr[5]=d4.y; darr[6]=d4.z; darr[7]=d4.w;
      } else {                                // self-loops
#pragma unroll
        for (int k = 0; k < 8; ++k) { sarr[k] = e0 - NE + k; darr[k] = sarr[k]; }
      }
    }
    int cbv[8], lv[8], pkv[8];
    if (valid) {
#pragma unroll
      for (int k = 0; k < 8; ++k) {
        int d = darr[k];
        cbv[k] = d >> 8;
        pkv[k] = sarr[k] | ((d & 255) << 16);      // src < 65536 fits 16 bits
        lv[k]  = atomicAdd(&hist[cbv[k]], 1);      // LDS atomic (cheap)
      }
    }
    __syncthreads();
    if (t < NCB) {
      int c = hist[t];
      hbase[t] = c ? atomicAdd(&ccnt[t * CPAD], c) : 0;   // ~196 global atomics/block
    }
    __syncthreads();
    if (valid) {
#pragma unroll
      for (int k = 0; k < 8; ++k) {
        int b = hbase[cbv[k]] + lv[k];
        if (b < CCAP) coarse[cbv[k] * CCAP + b] = pkv[k];
      }
    }
    return;
  }
  // ---- gemm1 part ----
  __shared__ float hs[16][HC1 + 1];
  const int m0 = (blockIdx.x - SCAT2_B) * 16;
  const int wv = t >> 6, lane = t & 63;
  const int lm = lane & 15, quad = lane >> 4;
  const int n0 = wv * 64;
  f32x4 acc[4] = {{0.f,0.f,0.f,0.f},{0.f,0.f,0.f,0.f},{0.f,0.f,0.f,0.f},{0.f,0.f,0.f,0.f}};
  const float* arow = x + (size_t)(m0 + lm) * F_IN + quad * 8;
#pragma unroll
  for (int kc = 0; kc < F_IN; kc += 32) {
    float4 u = *(const float4*)(arow + kc);
    float4 v = *(const float4*)(arow + kc + 4);
    half8 a;
    a[0]=(_Float16)u.x; a[1]=(_Float16)u.y; a[2]=(_Float16)u.z; a[3]=(_Float16)u.w;
    a[4]=(_Float16)v.x; a[5]=(_Float16)v.y; a[6]=(_Float16)v.z; a[7]=(_Float16)v.w;
#pragma unroll
    for (int tn = 0; tn < 4; ++tn) {
      half8 b = *(const half8*)(W1T + (size_t)(n0 + tn * 16 + lm) * F_IN + kc + quad * 8);
      acc[tn] = __builtin_amdgcn_mfma_f32_16x16x32_f16(a, b, acc[tn], 0, 0, 0);
    }
  }
#pragma unroll
  for (int tn = 0; tn < 4; ++tn)
#pragma unroll
    for (int r = 0; r < 4; ++r)
      hs[quad * 4 + r][n0 + tn * 16 + lm] = acc[tn][r];
  __syncthreads();
  // h1 fp8 write: 16 rows x 256 ch; thread t -> row t>>4, 16 ch at (t&15)*16
  {
    int row = t >> 4, cb = (t & 15) * 16;
    const float* hr = &hs[row][cb];
    uint4 pk;
    pk.x = pack_fp8x4(hr[0],  hr[1],  hr[2],  hr[3]);
    pk.y = pack_fp8x4(hr[4],  hr[5],  hr[6],  hr[7]);
    pk.z = pack_fp8x4(hr[8],  hr[9],  hr[10], hr[11]);
    pk.w = pack_fp8x4(hr[12], hr[13], hr[14], hr[15]);
    *(uint4*)(h1 + (size_t)(m0 + row) * HC1 + cb) = pk;
  }
  // scores: 128 tasks (16 rows x 4 heads x {src,dst}) x 2 threads each
  {
    int task = t >> 1, part = t & 1;
    int r = task >> 3, hh = (task >> 1) & 3, isdst = task & 1;
    const float* a = isdst ? adst : asrc;
    float s = 0.f;
    int c0 = part * 32;
    for (int c = c0; c < c0 + 32; ++c) s += hs[r][hh * HID + c] * a[hh * HID + c];
    s += __shfl_xor(s, 1, 64);
    if (part == 0) (isdst ? sdst : ssrc)[(m0 + r) * HEADS + hh] = s;
  }
}

// ================= phase-2: build per-dst buckets from coarse buckets ================
__global__ __launch_bounds__(1024) void bucket_build_kernel(
    const int* __restrict__ ccnt, const int* __restrict__ coarse,
    int* __restrict__ cnt, int* __restrict__ bucket) {
  __shared__ int hist2[256];
  const int cb = blockIdx.x, t = threadIdx.x;
  if (t < 256) hist2[t] = 0;
  __syncthreads();
  const int n = min(ccnt[cb * CPAD], CCAP);
  const int* cbase = coarse + cb * CCAP;
  int j = t;
  int v = (j < n) ? cbase[j] : 0;
  while (j < n) {
    int jn = j + 1024;
    int vn = (jn < n) ? cbase[jn] : 0;        // prefetch next round
    int s = v & 0xFFFF, dlow = (v >> 16) & 0xFF;
    int l = atomicAdd(&hist2[dlow], 1);
    if (l < CAP) bucket[(size_t)((cb << 8) | dlow) * CAP + l] = s;
    j = jn; v = vn;
  }
  __syncthreads();
  int d = (cb << 8) | t;
  if (t < 256 && d < NN) cnt[d] = hist2[t];
}

// ================= fused GAT gather, layer 1 (H=4, fp8 h): one wave per dst ===========
__global__ __launch_bounds__(256) void gat_gather4_kernel(
    const int* __restrict__ cnt, const int* __restrict__ bucket,
    const float* __restrict__ ss, const float* __restrict__ sd,
    const unsigned char* __restrict__ h, const float* __restrict__ bias,
    __half* __restrict__ outp) {
  const int d    = (blockIdx.x * 256 + threadIdx.x) >> 6;
  const int lane = threadIdx.x & 63;
  if (d >= NN) return;
  const int start = d * CAP;
  const int deg   = min(cnt[d], CAP);
  const int hsel  = lane & 3;     // score-phase head
  const int eg    = lane >> 4;    // agg edge subgroup (0..3)
  const int cpos  = lane & 15;    // 16B chunk within 256B row
  const int hh    = cpos >> 2;    // agg-phase head of these channels
  const float sdv = sd[d * 4 + hsel];
  f32x2 acc2[8];
#pragma unroll
  for (int k = 0; k < 8; ++k) acc2[k] = (f32x2){0.f, 0.f};

  auto agg4 = [&](int sj, float alpha) {
    uint4 u = *(const uint4*)(h + (unsigned)(sj * HC1 + cpos * 16));   // 32-bit addressing
    f32x2 a2 = {alpha, alpha};
    fma_fp8x4_pk(acc2 + 0, u.x, a2);
    fma_fp8x4_pk(acc2 + 2, u.y, a2);
    fma_fp8x4_pk(acc2 + 4, u.z, a2);
    fma_fp8x4_pk(acc2 + 6, u.w, a2);
  };

  if (deg <= 32) {
    const int j0 = lane >> 2;
    int s0 = 0, s1 = 0;
    float v0 = -INFINITY, v1 = -INFINITY;
    if (j0 < deg)      { s0 = bucket[start + j0];      v0 = lrelu(ss[s0 * 4 + hsel] + sdv); }
    if (j0 + 16 < deg) { s1 = bucket[start + j0 + 16]; v1 = lrelu(ss[s1 * 4 + hsel] + sdv); }
    float mx = fmaxf(v0, v1);
#pragma unroll
    for (int o = 4; o < 64; o <<= 1) mx = fmaxf(mx, __shfl_xor(mx, o, 64));
    float p0 = (j0 < deg)      ? __expf(v0 - mx) : 0.f;
    float p1 = (j0 + 16 < deg) ? __expf(v1 - mx) : 0.f;
    float den = p0 + p1;
#pragma unroll
    for (int o = 4; o < 64; o <<= 1) den += __shfl_xor(den, o, 64);
    const float inv = 1.f / (den + 1e-16f);
    const float pa0 = p0 * inv, pa1 = p1 * inv;
    const int m1 = min(deg, 16);
    for (int j = 0; j < m1; j += 8) {
      {
        int jj = j + eg;
        bool ok = jj < m1;
        float alpha = ok ? __shfl(pa0, jj * 4 + hh, 64) : 0.f;
        int   sj    = __shfl(s0, (ok ? jj : 0) * 4, 64);
        agg4(sj, alpha);
      }
      if (j + 4 < m1) {                         // wave-uniform gate
        int jj = j + 4 + eg;
        bool ok = jj < m1;
        float alpha = ok ? __shfl(pa0, jj * 4 + hh, 64) : 0.f;
        int   sj    = __shfl(s0, (ok ? jj : 0) * 4, 64);
        agg4(sj, alpha);
      }
    }
    if (deg > 16) {
      for (int j = 16; j < deg; j += 8) {
        {
          int jj = j + eg;
          bool ok = jj < deg;
          int i1 = jj - 16;
          float alpha = ok ? __shfl(pa1, i1 * 4 + hh, 64) : 0.f;
          int   sj    = __shfl(s1, (ok ? i1 : 0) * 4, 64);
          agg4(sj, alpha);
        }
        if (j + 4 < deg) {                      // wave-uniform gate
          int jj = j + 4 + eg;
          bool ok = jj < deg;
          int i1 = jj - 16;
          float alpha = ok ? __shfl(pa1, (ok ? i1 : 0) * 4 + hh, 64) : 0.f;
          int   sj    = __shfl(s1, (ok ? i1 : 0) * 4, 64);
          agg4(sj, alpha);
        }
      }
    }
  } else {
    // chunked (rare for this input): 16 edges per chunk
    float mx = -INFINITY;
    for (int base = 0; base < deg; base += 16) {
      int j = base + (lane >> 2);
      float v = (j < deg) ? lrelu(ss[bucket[start + j] * 4 + hsel] + sdv) : -INFINITY;
#pragma unroll
      for (int o = 4; o < 64; o <<= 1) v = fmaxf(v, __shfl_xor(v, o, 64));
      mx = fmaxf(mx, v);
    }
    float den = 0.f;
    for (int base = 0; base < deg; base += 16) {
      int j = base + (lane >> 2);
      float p = (j < deg) ? __expf(lrelu(ss[bucket[start + j] * 4 + hsel] + sdv) - mx) : 0.f;
#pragma unroll
      for (int o = 4; o < 64; o <<= 1) p += __shfl_xor(p, o, 64);
      den += p;
    }
    const float inv = 1.f / (den + 1e-16f);
    for (int base = 0; base < deg; base += 16) {
      int j = base + (lane >> 2);
      int s = 0; float pa = 0.f;
      if (j < deg) {
        s = bucket[start + j];
        pa = __expf(lrelu(ss[s * 4 + hsel] + sdv) - mx) * inv;
      }
      int cnt2 = min(16, deg - base);
      for (int jc = 0; jc < cnt2; jc += 4) {
        int jj = jc + eg;
        bool ok = jj < cnt2;
        float alpha = ok ? __shfl(pa, jj * 4 + hh, 64) : 0.f;
        int   sj    = __shfl(s, (ok ? jj : 0) * 4, 64);
        agg4(sj, alpha);
      }
    }
  }
  // combine the 4 edge subgroups, lanes 0..15 write the fp16 row
#pragma unroll
  for (int o = 16; o < 64; o <<= 1) {
#pragma unroll
    for (int k = 0; k < 8; ++k) {
      f32x2 tv;
      tv[0] = __shfl_xor(acc2[k][0], o, 64);
      tv[1] = __shfl_xor(acc2[k][1], o, 64);
      acc2[k] += tv;                            // v_pk_add_f32
    }
  }
  if (eg == 0) {
    float e[16];
#pragma unroll
    for (int k = 0; k < 16; ++k) e[k] = elu(acc2[k >> 1][k & 1] + bias[cpos * 16 + k]);
    __half* op = outp + (size_t)d * HC1 + cpos * 16;
    *(uint4*)op = pack8_h(e);
    *(uint4*)(op + 8) = pack8_h(e + 8);
  }
}

// ================= gemm2 (MFMA): 256 threads, 4 waves x 1 col-tile; h2 out fp8 =========
__global__ __launch_bounds__(256) void gemm2_mfma(
    const __half* __restrict__ o1h, const __half* __restrict__ W2T,
    const float* __restrict__ asrc, const float* __restrict__ adst,
    unsigned char* __restrict__ h2, float* __restrict__ ssrc, float* __restrict__ sdst) {
  __shared__ float hs[16][HID + 1];
  const int m0 = blockIdx.x * 16;
  const int t = threadIdx.x;
  const int wv = t >> 6, lane = t & 63;
  const int lm = lane & 15, quad = lane >> 4;
  f32x4 acc = {0.f, 0.f, 0.f, 0.f};
  const __half* arow = o1h + (size_t)(m0 + lm) * HC1 + quad * 8;
#pragma unroll
  for (int kc = 0; kc < HC1; kc += 32) {
    half8 a = *(const half8*)(arow + kc);
    half8 b = *(const half8*)(W2T + (size_t)(wv * 16 + lm) * HC1 + kc + quad * 8);
    acc = __builtin_amdgcn_mfma_f32_16x16x32_f16(a, b, acc, 0, 0, 0);
  }
#pragma unroll
  for (int r = 0; r < 4; ++r)
    hs[quad * 4 + r][wv * 16 + lm] = acc[r];
  __syncthreads();
  {
    int row = t >> 4, c4 = (t & 15) * 4;
    unsigned pk = pack_fp8x4(hs[row][c4], hs[row][c4 + 1], hs[row][c4 + 2], hs[row][c4 + 3]);
    *(unsigned*)(h2 + (size_t)(m0 + row) * HID + c4) = pk;
  }
  if (t < 64) {
    int task = t >> 1, part = t & 1;
    int r = task >> 1, isdst = task & 1;
    const float* a = isdst ? adst : asrc;
    float s = 0.f;
    int c0 = part * 32;
    for (int c = c0; c < c0 + 32; ++c) s += hs[r][c] * a[c];
    s += __shfl_xor(s, 1, 64);
    if (part == 0) (isdst ? sdst : ssrc)[m0 + r] = s;
  }
}

// ================= fused GAT gather, layer 2 (H=1, fp8 h): one wave per dst =========
__global__ __launch_bounds__(256) void gat_gather1_kernel(
    const int* __restrict__ cnt, const int* __restrict__ bucket,
    const float* __restrict__ ss, const float* __restrict__ sd,
    const unsigned char* __restrict__ h, const float* __restrict__ bias,
    float* __restrict__ outp) {
  const int d    = (blockIdx.x * 256 + threadIdx.x) >> 6;
  const int lane = threadIdx.x & 63;
  if (d >= NN) return;
  const int start = d * CAP;
  const int deg   = min(cnt[d], CAP);
  const int eg   = lane >> 3;     // edge subgroup (0..7)
  const int cpos = lane & 7;      // 8B chunk within 64B fp8 row
  const float sdv = sd[d];
  f32x2 acc2[4];
#pragma unroll
  for (int k = 0; k < 4; ++k) acc2[k] = (f32x2){0.f, 0.f};

  auto agg8 = [&](int sj, float alpha) {
    uint2 u = *(const uint2*)(h + (unsigned)(sj * HID + cpos * 8));   // 32-bit addressing
    f32x2 a2 = {alpha, alpha};
    fma_fp8x4_pk(acc2 + 0, u.x, a2);
    fma_fp8x4_pk(acc2 + 2, u.y, a2);
  };

  if (deg <= 64) {
    int s = 0; float v = -INFINITY;
    if (lane < deg) { s = bucket[start + lane]; v = lrelu(ss[s] + sdv); }
    float mx = v;
#pragma unroll
    for (int o = 1; o < 64; o <<= 1) mx = fmaxf(mx, __shfl_xor(mx, o, 64));
    float p = (lane < deg) ? __expf(v - mx) : 0.f;
    float den = p;
#pragma unroll
    for (int o = 1; o < 64; o <<= 1) den += __shfl_xor(den, o, 64);
    const float pa = p / (den + 1e-16f);
    for (int j = 0; j < deg; j += 16) {
      {
        int jj = j + eg;
        float alpha = (jj < deg) ? __shfl(pa, jj < 63 ? jj : 63, 64) : 0.f;
        int   sj    = __shfl(s, jj < 63 ? jj : 63, 64);
        agg8(sj, alpha);
      }
      if (j + 8 < deg) {                        // wave-uniform gate
        int jj = j + 8 + eg;
        float alpha = (jj < deg) ? __shfl(pa, jj < 63 ? jj : 63, 64) : 0.f;
        int   sj    = __shfl(s, jj < 63 ? jj : 63, 64);
        agg8(sj, alpha);
      }
    }
  } else {
    float mx = -INFINITY;
    for (int base = 0; base < deg; base += 64) {
      int j = base + lane;
      float v = (j < deg) ? lrelu(ss[bucket[start + j]] + sdv) : -INFINITY;
#pragma unroll
      for (int o = 1; o < 64; o <<= 1) v = fmaxf(v, __shfl_xor(v, o, 64));
      mx = fmaxf(mx, v);
    }
    float den = 0.f;
    for (int base = 0; base < deg; base += 64) {
      int j = base + lane;
      float p = (j < deg) ? __expf(lrelu(ss[bucket[start + j]] + sdv) - mx) : 0.f;
#pragma unroll
      for (int o = 1; o < 64; o <<= 1) p += __shfl_xor(p, o, 64);
      den += p;
    }
    const float inv = 1.f / (den + 1e-16f);
    for (int base = 0; base < deg; base += 64) {
      int j = base + lane;
      int s = 0; float pa = 0.f;
      if (j < deg) { s = bucket[start + j]; pa = __expf(lrelu(ss[s] + sdv) - mx) * inv; }
      int cnt2 = min(64, deg - base);
      for (int jc = 0; jc < cnt2; jc += 8) {
        int jj = jc + eg;
        float alpha = (jj < cnt2) ? __shfl(pa, jj < 63 ? jj : 63, 64) : 0.f;
        int   sj    = __shfl(s, jj < 63 ? jj : 63, 64);
        agg8(sj, alpha);
      }
    }
  }
#pragma unroll
  for (int o = 8; o < 64; o <<= 1) {
#pragma unroll
    for (int k = 0; k < 4; ++k) {
      f32x2 tv;
      tv[0] = __shfl_xor(acc2[k][0], o, 64);
      tv[1] = __shfl_xor(acc2[k][1], o, 64);
      acc2[k] += tv;
    }
  }
  if (eg == 0) {
    float4 r0, r1;
    r0.x = elu(acc2[0][0] + bias[cpos * 8 + 0]);
    r0.y = elu(acc2[0][1] + bias[cpos * 8 + 1]);
    r0.z = elu(acc2[1][0] + bias[cpos * 8 + 2]);
    r0.w = elu(acc2[1][1] + bias[cpos * 8 + 3]);
    r1.x = elu(acc2[2][0] + bias[cpos * 8 + 4]);
    r1.y = elu(acc2[2][1] + bias[cpos * 8 + 5]);
    r1.z = elu(acc2[3][0] + bias[cpos * 8 + 6]);
    r1.w = elu(acc2[3][1] + bias[cpos * 8 + 7]);
    float* op = outp + (size_t)d * HID + cpos * 8;
    *(float4*)op = r0;
    *(float4*)(op + 4) = r1;
  }
}

// ---------------- fused pool + FC + log_softmax (gstart inline): one block/graph -------
__global__ __launch_bounds__(1024) void pool_head_kernel(const float* __restrict__ o2,
                                                         const int* __restrict__ batch,
                                                         const float* __restrict__ fcw,
                                                         const float* __restrict__ fcb,
                                                         float* __restrict__ out) {
  __shared__ float red[16][HID];
  __shared__ int sbound[2];
  int g = blockIdx.x;
  int t = threadIdx.x;
  if (t < 2) {                         // graph boundaries via binary search
    int gg = g + t, lo = 0, hi = NN;
    while (lo < hi) { int mid = (lo + hi) >> 1; if (batch[mid] < gg) lo = mid + 1; else hi = mid; }
    sbound[t] = lo;
  }
  __syncthreads();
  int s0 = sbound[0], s1 = sbound[1];
  int c = t & 63, r = t >> 6;          // 16 node-rows in flight
  float acc = 0.f;
  for (int n = s0 + r; n < s1; n += 16) acc += o2[(size_t)n * HID + c];
  red[r][c] = acc;
  __syncthreads();
  if (r == 0) {                        // threads 0..63 = one wave
    float v = 0.f;
#pragma unroll
    for (int k = 0; k < 16; ++k) v += red[k][c];
    v /= fmaxf((float)(s1 - s0), 1.f);
    float p0 = v * fcw[c * 2 + 0];
    float p1 = v * fcw[c * 2 + 1];
#pragma unroll
    for (int o = 1; o < 64; o <<= 1) {
      p0 += __shfl_xor(p0, o, 64);
      p1 += __shfl_xor(p1, o, 64);
    }
    if (c == 0) {
      float l0 = p0 + fcb[0], l1 = p1 + fcb[1];
      float mx = fmaxf(l0, l1);
      float lse = mx + logf(expf(l0 - mx) + expf(l1 - mx));
      out[g * 2 + 0] = l0 - lse;
      out[g * 2 + 1] = l1 - lse;
    }
  }
}

// ---------------- launch ----------------
extern "C" void kernel_launch(void* const* d_in, const int* in_sizes, int n_in,
                              void* d_out, int out_size, void* d_ws, size_t ws_size,
                              hipStream_t stream) {
  const float* x    = (const float*)d_in[0];
  const int*   ei   = (const int*)d_in[1];
  const int*   batch= (const int*)d_in[2];
  const float* W1   = (const float*)d_in[3];
  const float* as1  = (const float*)d_in[4];
  const float* ad1  = (const float*)d_in[5];
  const float* b1   = (const float*)d_in[6];
  const float* W2   = (const float*)d_in[7];
  const float* as2  = (const float*)d_in[8];
  const float* ad2  = (const float*)d_in[9];
  const float* b2   = (const float*)d_in[10];
  const float* fcw  = (const float*)d_in[11];
  const float* fcb  = (const float*)d_in[12];
  float* out = (float*)d_out;
  float* ws  = (float*)d_ws;

  const int* esrc = ei;
  const int* edst = ei + NE;

  // ---- workspace layout (float units) ----
  size_t off = 0;
  float* hreg  = ws + off; off += (size_t)NN * HC1 / 4;  // h1 fp8 [NN,256]
  float* o1reg = ws + off; off += (size_t)NN * HC1 / 2;  // o1 fp16 [NN,256]
  float* l2reg = ws + off; off += (size_t)NN * HC1 / 2;  // h2 fp8 + o2 fp32 (also coarse, earlier)
  float* ss1 = ws + off; off += (size_t)NN * HEADS;
  float* sd1 = ws + off; off += (size_t)NN * HEADS;
  float* ss2 = ws + off; off += NN;
  float* sd2 = ws + off; off += NN;
  __half* W1T = (__half*)(ws + off); off += (size_t)HC1 * F_IN / 2;
  __half* W2T = (__half*)(ws + off); off += (size_t)HID * HC1 / 2;
  int* bucket = (int*)(ws + off); off += (size_t)NN * CAP;   // 25.6 MB
  int* cnt    = (int*)(ws + off); off += NN;                 // fully written by phase-2
  unsigned char* h1 = (unsigned char*)hreg;            // [NN, 256] fp8 e4m3
  __half* o1h = (__half*)o1reg;                        // [NN, 256] fp16
  unsigned char* h2 = (unsigned char*)l2reg;           // [NN, 64] fp8 e4m3
  float*  o2  = l2reg + (size_t)NN * HID / 4;          // [NN, 64] fp32
  // coarse scatter buffers alias l2reg (dead until gemm2): 4.83 MB < 25.6 MB
  int* coarse = (int*)l2reg;                           // [NCB][CCAP] packed (src | dlow<<16)
  int* ccnt   = (int*)l2reg + (size_t)NCB * CCAP;      // [NCB*CPAD] padded counters

  // ---- prep: transposes + coarse-cnt zero ----
  prep_kernel<<<(TW_TOT + NCB * CPAD + 255) / 256, 256, 0, stream>>>(W1, W2, W1T, W2T, ccnt);

  // ---- phase-1 coarse scatter || layer-1 GEMM (independent; co-scheduled) ----
  gemm1_scatter_kernel<<<SCAT2_B + GEMM1_B, 256, 0, stream>>>(
      x, W1T, as1, ad1, h1, ss1, sd1, esrc, edst, ccnt, coarse);

  // ---- phase-2: LDS-atomic bucket build (one block per coarse bucket) ----
  bucket_build_kernel<<<NCB, 1024, 0, stream>>>(ccnt, coarse, cnt, bucket);

  // ---- layer 1 gather ----
  gat_gather4_kernel<<<(NN + 3) / 4, 256, 0, stream>>>(cnt, bucket, ss1, sd1, h1, b1, o1h);

  // ---- layer 2 ----
  gemm2_mfma<<<NN / 16, 256, 0, stream>>>(o1h, W2T, as2, ad2, h2, ss2, sd2);
  gat_gather1_kernel<<<(NN + 3) / 4, 256, 0, stream>>>(cnt, bucket, ss2, sd2, h2, b2, o2);

  // ---- pool + head (fused, gstart inline) ----
  pool_head_kernel<<<NG, 1024, 0, stream>>>(o2, batch, fcw, fcb, out);
}

// Round 3
// 288.737 us; speedup vs baseline: 1.1314x; 1.0894x over previous
//
#include <hip/hip_runtime.h>
#include <hip/hip_fp16.h>
#include <hip/hip_fp8.h>
#include <math.h>

// ---------------- problem constants ----------------
constexpr int NN   = 50000;          // nodes
constexpr int NE   = 800000;         // edges (before self loops)
constexpr int ETOT = NE + NN;        // 850000 with self loops
constexpr int F_IN = 128;
constexpr int HID  = 64;
constexpr int HEADS = 4;
constexpr int HC1  = HEADS * HID;    // 256
constexpr int NG   = 64;             // graphs
constexpr float SLOPE = 0.2f;
constexpr int TW_TOT = F_IN * HC1 + HC1 * HID;   // transpose work items (49152)
constexpr int CAP  = 128;            // bucket capacity per dst (max deg ~45 for this input)
constexpr int GEMM1_B = NN / 16;     // 3125 gemm blocks

// ---- two-phase counting scatter ----
constexpr int CB_SHIFT = 7;                      // 128 dsts per coarse bucket
constexpr int NDB  = 1 << CB_SHIFT;              // 128
constexpr int NCB  = (NN + NDB - 1) >> CB_SHIFT; // 391 coarse buckets
constexpr int CCAP = 3072;           // per-coarse-bucket capacity (mean 2176, +20 sigma)
constexpr int CPAD = 16;             // pad coarse counters: 1 per 64B line
constexpr int SEPB = 2048;           // edges per scatter block (8 per thread)
constexpr int SCAT2_B = (ETOT + SEPB - 1) / SEPB;   // 416 scatter blocks

typedef _Float16 half8 __attribute__((ext_vector_type(8)));
typedef float f32x4 __attribute__((ext_vector_type(4)));
typedef float f32x2 __attribute__((ext_vector_type(2)));

__device__ __forceinline__ float lrelu(float v) { return v >= 0.f ? v : SLOPE * v; }
__device__ __forceinline__ float elu(float v) { return v > 0.f ? v : expm1f(v); }

// ---- fp8 e4m3 helpers (OCP; gfx950 HW cvt when available) ----
__device__ __forceinline__ unsigned pack_fp8x4(float a, float b, float c, float d) {
#if __has_builtin(__builtin_amdgcn_cvt_pk_fp8_f32)
  int v = 0;
  v = __builtin_amdgcn_cvt_pk_fp8_f32(a, b, v, false);
  v = __builtin_amdgcn_cvt_pk_fp8_f32(c, d, v, true);
  return (unsigned)v;
#else
  __hip_fp8_e4m3 fa(a), fb(b), fc(c), fd(d);
  return (unsigned)fa.__x | ((unsigned)fb.__x << 8) |
         ((unsigned)fc.__x << 16) | ((unsigned)fd.__x << 24);
#endif
}

__device__ __forceinline__ float fp8_1(unsigned byte) {   // manual e4m3fn -> f32
  unsigned s = (byte & 0x80u) << 24;
  unsigned em = (byte & 0x7fu) << 20;
  return __uint_as_float(s | em) * 0x1p+120f;
}

// 4-channel fp8 accumulate: acA gets ch{0,1}, acB gets ch{2,3} of the packed word.
// Same per-channel arithmetic order as scalar form -> bit-identical results.
__device__ __forceinline__ void agg_ch4(f32x2& acA, f32x2& acB, unsigned u, float al) {
#if __has_builtin(__builtin_amdgcn_cvt_pk_f32_fp8)
  f32x2 lo = __builtin_amdgcn_cvt_pk_f32_fp8((int)u, false);
  f32x2 hi = __builtin_amdgcn_cvt_pk_f32_fp8((int)u, true);
  f32x2 a2 = {al, al};
  asm("v_pk_fma_f32 %0, %1, %2, %0" : "+v"(acA) : "v"(lo), "v"(a2));
  asm("v_pk_fma_f32 %0, %1, %2, %0" : "+v"(acB) : "v"(hi), "v"(a2));
#else
  acA[0] += al * fp8_1(u & 0xffu);
  acA[1] += al * fp8_1((u >> 8) & 0xffu);
  acB[0] += al * fp8_1((u >> 16) & 0xffu);
  acB[1] += al * fp8_1(u >> 24);
#endif
}

// ================= prep: weight transposes + coarse-cnt zeroing ======================
__global__ void prep_kernel(const float* __restrict__ W1, const float* __restrict__ W2,
                            __half* __restrict__ W1T, __half* __restrict__ W2T,
                            int* __restrict__ ccnt) {
  int i = blockIdx.x * blockDim.x + threadIdx.x;
  if (i < F_IN * HC1) {                       // W1 [128][256] -> W1T [256][128]
    int k = i / HC1, n = i - k * HC1;
    W1T[n * F_IN + k] = __float2half(W1[i]);
  } else if (i < TW_TOT) {                    // W2 [256][64] -> W2T [64][256]
    int j = i - F_IN * HC1;
    int k = j / HID, n = j - k * HID;
    W2T[n * HC1 + k] = __float2half(W2[j]);
  } else if (i < TW_TOT + NCB * CPAD) {
    ccnt[i - TW_TOT] = 0;
  }
}

// ================= mega kernel: coarse-scatter blocks || gemm1 blocks ================
__global__ __launch_bounds__(256) void gemm1_scatter_kernel(
    const float* __restrict__ x, const __half* __restrict__ W1T,
    const float* __restrict__ asrc, const float* __restrict__ adst,
    unsigned char* __restrict__ h1, float* __restrict__ ssrc, float* __restrict__ sdst,
    const int* __restrict__ esrc, const int* __restrict__ edst,
    int* __restrict__ ccnt, int* __restrict__ coarse) {
  const int t = threadIdx.x;
  if (blockIdx.x < SCAT2_B) {
    // ---- phase-1 scatter ----
    __shared__ int hist[NCB];
    __shared__ int hbase[NCB];
    for (int i = t; i < NCB; i += 256) hist[i] = 0;
    __syncthreads();
    const int e0 = blockIdx.x * SEPB + t * 8;
    const bool valid = e0 < ETOT;             // ETOT%8==0, e0%8==0 -> all-or-nothing
    int sarr[8], darr[8];
    if (valid) {
      if (e0 < NE) {                          // NE%8==0 -> no straddle
        int4 a = *(const int4*)(esrc + e0);
        int4 b = *(const int4*)(esrc + e0 + 4);
        int4 c = *(const int4*)(edst + e0);
        int4 d4 = *(const int4*)(edst + e0 + 4);
        sarr[0]=a.x; sarr[1]=a.y; sarr[2]=a.z; sarr[3]=a.w;
        sarr[4]=b.x; sarr[5]=b.y; sarr[6]=b.z; sarr[7]=b.w;
        darr[0]=c.x; darr[1]=c.y; darr[2]=c.z; darr[3]=c.w;
        darr[4]=d4.x; darr[5]=d4.y; darr[6]=d4.z; darr[7]=d4.w;
      } else {                                // self-loops
#pragma unroll
        for (int k = 0; k < 8; ++k) { sarr[k] = e0 - NE + k; darr[k] = sarr[k]; }
      }
    }
    int cbv[8], lv[8], pkv[8];
    if (valid) {
#pragma unroll
      for (int k = 0; k < 8; ++k) {
        int d = darr[k];
        cbv[k] = d >> CB_SHIFT;
        pkv[k] = sarr[k] | ((d & (NDB - 1)) << 16);   // src < 65536 fits 16 bits
        lv[k]  = atomicAdd(&hist[cbv[k]], 1);         // LDS atomic (cheap)
      }
    }
    __syncthreads();
    for (int i = t; i < NCB; i += 256) {
      int c = hist[i];
      hbase[i] = c ? atomicAdd(&ccnt[i * CPAD], c) : 0;   // few hundred global atomics/block
    }
    __syncthreads();
    if (valid) {
#pragma unroll
      for (int k = 0; k < 8; ++k) {
        int b = hbase[cbv[k]] + lv[k];
        if (b < CCAP) coarse[cbv[k] * CCAP + b] = pkv[k];
      }
    }
    return;
  }
  // ---- gemm1 part ----
  __shared__ float hs[16][HC1 + 1];
  const int m0 = (blockIdx.x - SCAT2_B) * 16;
  const int wv = t >> 6, lane = t & 63;
  const int lm = lane & 15, quad = lane >> 4;
  const int n0 = wv * 64;
  f32x4 acc[4] = {{0.f,0.f,0.f,0.f},{0.f,0.f,0.f,0.f},{0.f,0.f,0.f,0.f},{0.f,0.f,0.f,0.f}};
  const float* arow = x + (size_t)(m0 + lm) * F_IN + quad * 8;
#pragma unroll
  for (int kc = 0; kc < F_IN; kc += 32) {
    float4 u = *(const float4*)(arow + kc);
    float4 v = *(const float4*)(arow + kc + 4);
    half8 a;
    a[0]=(_Float16)u.x; a[1]=(_Float16)u.y; a[2]=(_Float16)u.z; a[3]=(_Float16)u.w;
    a[4]=(_Float16)v.x; a[5]=(_Float16)v.y; a[6]=(_Float16)v.z; a[7]=(_Float16)v.w;
#pragma unroll
    for (int tn = 0; tn < 4; ++tn) {
      half8 b = *(const half8*)(W1T + (size_t)(n0 + tn * 16 + lm) * F_IN + kc + quad * 8);
      acc[tn] = __builtin_amdgcn_mfma_f32_16x16x32_f16(a, b, acc[tn], 0, 0, 0);
    }
  }
#pragma unroll
  for (int tn = 0; tn < 4; ++tn)
#pragma unroll
    for (int r = 0; r < 4; ++r)
      hs[quad * 4 + r][n0 + tn * 16 + lm] = acc[tn][r];
  __syncthreads();
  // h1 fp8 write: 16 rows x 256 ch; thread t -> row t>>4, 16 ch at (t&15)*16
  {
    int row = t >> 4, cb = (t & 15) * 16;
    const float* hr = &hs[row][cb];
    uint4 pk;
    pk.x = pack_fp8x4(hr[0],  hr[1],  hr[2],  hr[3]);
    pk.y = pack_fp8x4(hr[4],  hr[5],  hr[6],  hr[7]);
    pk.z = pack_fp8x4(hr[8],  hr[9],  hr[10], hr[11]);
    pk.w = pack_fp8x4(hr[12], hr[13], hr[14], hr[15]);
    *(uint4*)(h1 + (size_t)(m0 + row) * HC1 + cb) = pk;
  }
  // scores: 128 tasks (16 rows x 4 heads x {src,dst}) x 2 threads each
  {
    int task = t >> 1, part = t & 1;
    int r = task >> 3, hh = (task >> 1) & 3, isdst = task & 1;
    const float* a = isdst ? adst : asrc;
    float s = 0.f;
    int c0 = part * 32;
    for (int c = c0; c < c0 + 32; ++c) s += hs[r][hh * HID + c] * a[hh * HID + c];
    s += __shfl_xor(s, 1, 64);
    if (part == 0) (isdst ? sdst : ssrc)[(m0 + r) * HEADS + hh] = s;
  }
}

// ================= phase-2: build per-dst buckets from coarse buckets ================
__global__ __launch_bounds__(1024) void bucket_build_kernel(
    const int* __restrict__ ccnt, const int* __restrict__ coarse,
    int* __restrict__ cnt, int* __restrict__ bucket) {
  __shared__ int hist2[NDB];
  const int cb = blockIdx.x, t = threadIdx.x;
  if (t < NDB) hist2[t] = 0;
  __syncthreads();
  const int n = min(ccnt[cb * CPAD], CCAP);
  const int* cbase = coarse + cb * CCAP;
  int j = t;
  int v = (j < n) ? cbase[j] : 0;
  while (j < n) {
    int jn = j + 1024;
    int vn = (jn < n) ? cbase[jn] : 0;        // prefetch next round
    int s = v & 0xFFFF, dlow = (v >> 16) & (NDB - 1);
    int l = atomicAdd(&hist2[dlow], 1);
    if (l < CAP) bucket[(size_t)((cb << CB_SHIFT) | dlow) * CAP + l] = s;
    j = jn; v = vn;
  }
  __syncthreads();
  int d = (cb << CB_SHIFT) | t;
  if (t < NDB && d < NN) cnt[d] = hist2[t];
}

// ================= fused GAT gather, layer 1 (H=4, fp8 h) ===========================
// One wave per dst. NEW layout: lane owns 4 channels (ch = lane*4..+3); per edge the
// wave does ONE coalesced dword load of the full 256B row. Alphas staged in LDS
// (zero-padded -> branch-free quad loop); src quads read uniform from bucket (clamped).
// No cross-lane reduction, full-wave vector epilogue.
__global__ __launch_bounds__(256) void gat_gather4_kernel(
    const int* __restrict__ cnt, const int* __restrict__ bucket,
    const float* __restrict__ ss, const float* __restrict__ sd,
    const unsigned char* __restrict__ h, const float* __restrict__ bias,
    __half* __restrict__ outp) {
  __shared__ float paS[4][HEADS][40];    // [wave][head][slot], pitch 40 for bank spread
  const int wv   = threadIdx.x >> 6;
  const int lane = threadIdx.x & 63;
  const int d    = (blockIdx.x * 256 + threadIdx.x) >> 6;
  if (d >= NN) return;
  const int start = d * CAP;
  const int deg   = min(cnt[d], CAP);
  const int hsel  = lane & 3;            // score-phase head
  const int j0    = lane >> 2;           // score-phase edge
  const int head  = lane >> 4;           // agg-phase head of this lane's channels
  const float sdv = sd[d * 4 + hsel];
  float (*pa)[40] = paS[wv];

  f32x2 acA = {0.f, 0.f}, acB = {0.f, 0.f};
  const unsigned char* hb = h + (unsigned)(lane * 4);

  if (deg <= 32) {
    int s0 = 0, s1 = 0;
    float v0 = -INFINITY, v1 = -INFINITY;
    if (j0 < deg)      { s0 = bucket[start + j0];      v0 = lrelu(ss[s0 * 4 + hsel] + sdv); }
    if (j0 + 16 < deg) { s1 = bucket[start + j0 + 16]; v1 = lrelu(ss[s1 * 4 + hsel] + sdv); }
    float mx = fmaxf(v0, v1);
#pragma unroll
    for (int o = 4; o < 64; o <<= 1) mx = fmaxf(mx, __shfl_xor(mx, o, 64));
    float p0 = (j0 < deg)      ? __expf(v0 - mx) : 0.f;
    float p1 = (j0 + 16 < deg) ? __expf(v1 - mx) : 0.f;
    float den = p0 + p1;
#pragma unroll
    for (int o = 4; o < 64; o <<= 1) den += __shfl_xor(den, o, 64);
    const float inv = 1.f / (den + 1e-16f);
    pa[hsel][j0]      = p0 * inv;        // zeros where invalid -> pad slots are 0
    pa[hsel][j0 + 16] = p1 * inv;
    const int nq = (deg + 3) >> 2;
    for (int q = 0; q < nq; ++q) {
      int4   sv = *(const int4*)(bucket + start + q * 4);      // uniform
      float4 av = *(const float4*)&pa[head][q * 4];
      {
        unsigned sj = min((unsigned)sv.x, (unsigned)(NN - 1));
        agg_ch4(acA, acB, *(const unsigned*)(hb + (sj << 8)), av.x);
      }
      {
        unsigned sj = min((unsigned)sv.y, (unsigned)(NN - 1));
        agg_ch4(acA, acB, *(const unsigned*)(hb + (sj << 8)), av.y);
      }
      {
        unsigned sj = min((unsigned)sv.z, (unsigned)(NN - 1));
        agg_ch4(acA, acB, *(const unsigned*)(hb + (sj << 8)), av.z);
      }
      {
        unsigned sj = min((unsigned)sv.w, (unsigned)(NN - 1));
        agg_ch4(acA, acB, *(const unsigned*)(hb + (sj << 8)), av.w);
      }
    }
  } else {
    // chunked (rare): 16 edges per chunk, alphas staged per chunk
    float mx = -INFINITY;
    for (int base = 0; base < deg; base += 16) {
      int j = base + j0;
      float v = (j < deg) ? lrelu(ss[bucket[start + j] * 4 + hsel] + sdv) : -INFINITY;
#pragma unroll
      for (int o = 4; o < 64; o <<= 1) v = fmaxf(v, __shfl_xor(v, o, 64));
      mx = fmaxf(mx, v);
    }
    float den = 0.f;
    for (int base = 0; base < deg; base += 16) {
      int j = base + j0;
      float p = (j < deg) ? __expf(lrelu(ss[bucket[start + j] * 4 + hsel] + sdv) - mx) : 0.f;
#pragma unroll
      for (int o = 4; o < 64; o <<= 1) p += __shfl_xor(p, o, 64);
      den += p;
    }
    const float inv = 1.f / (den + 1e-16f);
    for (int base = 0; base < deg; base += 16) {
      int j = base + j0;
      float pav = 0.f;
      if (j < deg) pav = __expf(lrelu(ss[bucket[start + j] * 4 + hsel] + sdv) - mx) * inv;
      pa[hsel][j0] = pav;
      const int m  = min(16, deg - base);
      const int nq = (m + 3) >> 2;
      for (int q = 0; q < nq; ++q) {
        int4   sv = *(const int4*)(bucket + start + base + q * 4);
        float4 av = *(const float4*)&pa[head][q * 4];
        {
          unsigned sj = min((unsigned)sv.x, (unsigned)(NN - 1));
          agg_ch4(acA, acB, *(const unsigned*)(hb + (sj << 8)), av.x);
        }
        {
          unsigned sj = min((unsigned)sv.y, (unsigned)(NN - 1));
          agg_ch4(acA, acB, *(const unsigned*)(hb + (sj << 8)), av.y);
        }
        {
          unsigned sj = min((unsigned)sv.z, (unsigned)(NN - 1));
          agg_ch4(acA, acB, *(const unsigned*)(hb + (sj << 8)), av.z);
        }
        {
          unsigned sj = min((unsigned)sv.w, (unsigned)(NN - 1));
          agg_ch4(acA, acB, *(const unsigned*)(hb + (sj << 8)), av.w);
        }
      }
    }
  }
  // epilogue: bias + elu + fp16 store, all 64 lanes, 8B each (512B/wave contiguous)
  float4 bv = *(const float4*)(bias + lane * 4);
  float e0 = elu(acA[0] + bv.x), e1 = elu(acA[1] + bv.y);
  float e2 = elu(acB[0] + bv.z), e3 = elu(acB[1] + bv.w);
  union { __half2 h2[2]; uint2 u; } pk;
  pk.h2[0] = __floats2half2_rn(e0, e1);
  pk.h2[1] = __floats2half2_rn(e2, e3);
  *(uint2*)(outp + (size_t)d * HC1 + lane * 4) = pk.u;
}

// ================= fused GAT gather, layer 2 (H=1, fp8 h) ===========================
// One wave per dst. 16 lanes x 4ch cover the 64B row; 4 edge-subgroups; final
// reduce is only 2 shuffle rounds. Alphas staged in LDS, srcs direct from bucket.
__global__ __launch_bounds__(256) void gat_gather1_kernel(
    const int* __restrict__ cnt, const int* __restrict__ bucket,
    const float* __restrict__ ss, const float* __restrict__ sd,
    const unsigned char* __restrict__ h, const float* __restrict__ bias,
    float* __restrict__ outp) {
  __shared__ float paS[4][68];
  const int wv   = threadIdx.x >> 6;
  const int lane = threadIdx.x & 63;
  const int d    = (blockIdx.x * 256 + threadIdx.x) >> 6;
  if (d >= NN) return;
  const int start = d * CAP;
  const int deg   = min(cnt[d], CAP);
  const int eg    = lane >> 4;    // edge subgroup (0..3)
  const int cpos  = lane & 15;    // 4B chunk within 64B fp8 row
  const float sdv = sd[d];
  float* pa = paS[wv];
  f32x2 acA = {0.f, 0.f}, acB = {0.f, 0.f};
  const unsigned char* hb = h + (unsigned)(cpos * 4);

  if (deg <= 64) {
    int s = 0; float v = -INFINITY;
    if (lane < deg) { s = bucket[start + lane]; v = lrelu(ss[s] + sdv); }
    float mx = v;
#pragma unroll
    for (int o = 1; o < 64; o <<= 1) mx = fmaxf(mx, __shfl_xor(mx, o, 64));
    float p = (lane < deg) ? __expf(v - mx) : 0.f;
    float den = p;
#pragma unroll
    for (int o = 1; o < 64; o <<= 1) den += __shfl_xor(den, o, 64);
    pa[lane] = p / (den + 1e-16f);       // zeros where invalid -> pad slots are 0
    const int nq = (deg + 3) >> 2;
    for (int q = 0; q < nq; ++q) {
      int slot = q * 4 + eg;
      int sj = bucket[start + slot];
      float al = pa[slot];
      unsigned sc = min((unsigned)sj, (unsigned)(NN - 1));
      agg_ch4(acA, acB, *(const unsigned*)(hb + (sc << 6)), al);
    }
  } else {
    float mx = -INFINITY;
    for (int base = 0; base < deg; base += 64) {
      int j = base + lane;
      float v = (j < deg) ? lrelu(ss[bucket[start + j]] + sdv) : -INFINITY;
#pragma unroll
      for (int o = 1; o < 64; o <<= 1) v = fmaxf(v, __shfl_xor(v, o, 64));
      mx = fmaxf(mx, v);
    }
    float den = 0.f;
    for (int base = 0; base < deg; base += 64) {
      int j = base + lane;
      float p = (j < deg) ? __expf(lrelu(ss[bucket[start + j]] + sdv) - mx) : 0.f;
#pragma unroll
      for (int o = 1; o < 64; o <<= 1) p += __shfl_xor(p, o, 64);
      den += p;
    }
    const float inv = 1.f / (den + 1e-16f);
    for (int base = 0; base < deg; base += 64) {
      int j = base + lane;
      float pav = 0.f;
      if (j < deg) pav = __expf(lrelu(ss[bucket[start + j]] + sdv) - mx) * inv;
      pa[lane] = pav;
      const int m  = min(64, deg - base);
      const int nq = (m + 3) >> 2;
      for (int q = 0; q < nq; ++q) {
        int slot = q * 4 + eg;
        int sj = bucket[start + base + slot];
        float al = pa[slot];
        unsigned sc = min((unsigned)sj, (unsigned)(NN - 1));
        agg_ch4(acA, acB, *(const unsigned*)(hb + (sc << 6)), al);
      }
    }
  }
  // combine the 4 edge subgroups (2 shuffle rounds)
#pragma unroll
  for (int o = 16; o < 64; o <<= 1) {
    f32x2 tv;
    tv[0] = __shfl_xor(acA[0], o, 64); tv[1] = __shfl_xor(acA[1], o, 64); acA += tv;
    tv[0] = __shfl_xor(acB[0], o, 64); tv[1] = __shfl_xor(acB[1], o, 64); acB += tv;
  }
  if (eg == 0) {
    float4 bv = *(const float4*)(bias + cpos * 4);
    float4 r;
    r.x = elu(acA[0] + bv.x);
    r.y = elu(acA[1] + bv.y);
    r.z = elu(acB[0] + bv.z);
    r.w = elu(acB[1] + bv.w);
    *(float4*)(outp + (size_t)d * HID + cpos * 4) = r;
  }
}

// ================= gemm2 (MFMA): 256 threads, 4 waves x 1 col-tile; h2 out fp8 =========
__global__ __launch_bounds__(256) void gemm2_mfma(
    const __half* __restrict__ o1h, const __half* __restrict__ W2T,
    const float* __restrict__ asrc, const float* __restrict__ adst,
    unsigned char* __restrict__ h2, float* __restrict__ ssrc, float* __restrict__ sdst) {
  __shared__ float hs[16][HID + 1];
  const int m0 = blockIdx.x * 16;
  const int t = threadIdx.x;
  const int wv = t >> 6, lane = t & 63;
  const int lm = lane & 15, quad = lane >> 4;
  f32x4 acc = {0.f, 0.f, 0.f, 0.f};
  const __half* arow = o1h + (size_t)(m0 + lm) * HC1 + quad * 8;
#pragma unroll
  for (int kc = 0; kc < HC1; kc += 32) {
    half8 a = *(const half8*)(arow + kc);
    half8 b = *(const half8*)(W2T + (size_t)(wv * 16 + lm) * HC1 + kc + quad * 8);
    acc = __builtin_amdgcn_mfma_f32_16x16x32_f16(a, b, acc, 0, 0, 0);
  }
#pragma unroll
  for (int r = 0; r < 4; ++r)
    hs[quad * 4 + r][wv * 16 + lm] = acc[r];
  __syncthreads();
  {
    int row = t >> 4, c4 = (t & 15) * 4;
    unsigned pk = pack_fp8x4(hs[row][c4], hs[row][c4 + 1], hs[row][c4 + 2], hs[row][c4 + 3]);
    *(unsigned*)(h2 + (size_t)(m0 + row) * HID + c4) = pk;
  }
  if (t < 64) {
    int task = t >> 1, part = t & 1;
    int r = task >> 1, isdst = task & 1;
    const float* a = isdst ? adst : asrc;
    float s = 0.f;
    int c0 = part * 32;
    for (int c = c0; c < c0 + 32; ++c) s += hs[r][c] * a[c];
    s += __shfl_xor(s, 1, 64);
    if (part == 0) (isdst ? sdst : ssrc)[m0 + r] = s;
  }
}

// ---------------- fused pool + FC + log_softmax (gstart inline): one block/graph -------
__global__ __launch_bounds__(1024) void pool_head_kernel(const float* __restrict__ o2,
                                                         const int* __restrict__ batch,
                                                         const float* __restrict__ fcw,
                                                         const float* __restrict__ fcb,
                                                         float* __restrict__ out) {
  __shared__ float red[16][HID];
  __shared__ int sbound[2];
  int g = blockIdx.x;
  int t = threadIdx.x;
  if (t < 2) {                         // graph boundaries via binary search
    int gg = g + t, lo = 0, hi = NN;
    while (lo < hi) { int mid = (lo + hi) >> 1; if (batch[mid] < gg) lo = mid + 1; else hi = mid; }
    sbound[t] = lo;
  }
  __syncthreads();
  int s0 = sbound[0], s1 = sbound[1];
  int c = t & 63, r = t >> 6;          // 16 node-rows in flight
  float acc = 0.f;
  for (int n = s0 + r; n < s1; n += 16) acc += o2[(size_t)n * HID + c];
  red[r][c] = acc;
  __syncthreads();
  if (r == 0) {                        // threads 0..63 = one wave
    float v = 0.f;
#pragma unroll
    for (int k = 0; k < 16; ++k) v += red[k][c];
    v /= fmaxf((float)(s1 - s0), 1.f);
    float p0 = v * fcw[c * 2 + 0];
    float p1 = v * fcw[c * 2 + 1];
#pragma unroll
    for (int o = 1; o < 64; o <<= 1) {
      p0 += __shfl_xor(p0, o, 64);
      p1 += __shfl_xor(p1, o, 64);
    }
    if (c == 0) {
      float l0 = p0 + fcb[0], l1 = p1 + fcb[1];
      float mx = fmaxf(l0, l1);
      float lse = mx + logf(expf(l0 - mx) + expf(l1 - mx));
      out[g * 2 + 0] = l0 - lse;
      out[g * 2 + 1] = l1 - lse;
    }
  }
}

// ---------------- launch ----------------
extern "C" void kernel_launch(void* const* d_in, const int* in_sizes, int n_in,
                              void* d_out, int out_size, void* d_ws, size_t ws_size,
                              hipStream_t stream) {
  const float* x    = (const float*)d_in[0];
  const int*   ei   = (const int*)d_in[1];
  const int*   batch= (const int*)d_in[2];
  const float* W1   = (const float*)d_in[3];
  const float* as1  = (const float*)d_in[4];
  const float* ad1  = (const float*)d_in[5];
  const float* b1   = (const float*)d_in[6];
  const float* W2   = (const float*)d_in[7];
  const float* as2  = (const float*)d_in[8];
  const float* ad2  = (const float*)d_in[9];
  const float* b2   = (const float*)d_in[10];
  const float* fcw  = (const float*)d_in[11];
  const float* fcb  = (const float*)d_in[12];
  float* out = (float*)d_out;
  float* ws  = (float*)d_ws;

  const int* esrc = ei;
  const int* edst = ei + NE;

  // ---- workspace layout (float units) ----
  size_t off = 0;
  float* hreg  = ws + off; off += (size_t)NN * HC1 / 4;  // h1 fp8 [NN,256]
  float* o1reg = ws + off; off += (size_t)NN * HC1 / 2;  // o1 fp16 [NN,256]
  float* l2reg = ws + off; off += (size_t)NN * HC1 / 2;  // h2 fp8 + o2 fp32 (also coarse, earlier)
  float* ss1 = ws + off; off += (size_t)NN * HEADS;
  float* sd1 = ws + off; off += (size_t)NN * HEADS;
  float* ss2 = ws + off; off += NN;
  float* sd2 = ws + off; off += NN;
  __half* W1T = (__half*)(ws + off); off += (size_t)HC1 * F_IN / 2;
  __half* W2T = (__half*)(ws + off); off += (size_t)HID * HC1 / 2;
  int* bucket = (int*)(ws + off); off += (size_t)NN * CAP;   // 25.6 MB
  int* cnt    = (int*)(ws + off); off += NN;                 // fully written by phase-2
  unsigned char* h1 = (unsigned char*)hreg;            // [NN, 256] fp8 e4m3
  __half* o1h = (__half*)o1reg;                        // [NN, 256] fp16
  unsigned char* h2 = (unsigned char*)l2reg;           // [NN, 64] fp8 e4m3
  float*  o2  = l2reg + (size_t)NN * HID / 4;          // [NN, 64] fp32
  // coarse scatter buffers alias l2reg (dead until gemm2): ~4.8 MB < 25.6 MB
  int* coarse = (int*)l2reg;                           // [NCB][CCAP] packed (src | dlow<<16)
  int* ccnt   = (int*)l2reg + (size_t)NCB * CCAP;      // [NCB*CPAD] padded counters

  // ---- prep: transposes + coarse-cnt zero ----
  prep_kernel<<<(TW_TOT + NCB * CPAD + 255) / 256, 256, 0, stream>>>(W1, W2, W1T, W2T, ccnt);

  // ---- phase-1 coarse scatter || layer-1 GEMM (independent; co-scheduled) ----
  gemm1_scatter_kernel<<<SCAT2_B + GEMM1_B, 256, 0, stream>>>(
      x, W1T, as1, ad1, h1, ss1, sd1, esrc, edst, ccnt, coarse);

  // ---- phase-2: LDS-atomic bucket build (one block per coarse bucket) ----
  bucket_build_kernel<<<NCB, 1024, 0, stream>>>(ccnt, coarse, cnt, bucket);

  // ---- layer 1 gather ----
  gat_gather4_kernel<<<(NN + 3) / 4, 256, 0, stream>>>(cnt, bucket, ss1, sd1, h1, b1, o1h);

  // ---- layer 2 ----
  gemm2_mfma<<<NN / 16, 256, 0, stream>>>(o1h, W2T, as2, ad2, h2, ss2, sd2);
  gat_gather1_kernel<<<(NN + 3) / 4, 256, 0, stream>>>(cnt, bucket, ss2, sd2, h2, b2, o2);

  // ---- pool + head (fused, gstart inline) ----
  pool_head_kernel<<<NG, 1024, 0, stream>>>(o2, batch, fcw, fcb, out);
}

// Round 4
// 282.701 us; speedup vs baseline: 1.1556x; 1.0214x over previous
//
#include <hip/hip_runtime.h>
#include <hip/hip_fp16.h>
#include <hip/hip_fp8.h>
#include <math.h>

// ---------------- problem constants ----------------
constexpr int NN   = 50000;          // nodes
constexpr int NE   = 800000;         // edges (before self loops)
constexpr int ETOT = NE + NN;        // 850000 with self loops
constexpr int F_IN = 128;
constexpr int HID  = 64;
constexpr int HEADS = 4;
constexpr int HC1  = HEADS * HID;    // 256
constexpr int NG   = 64;             // graphs
constexpr float SLOPE = 0.2f;
constexpr int TW_TOT = F_IN * HC1 + HC1 * HID;   // transpose work items (49152)
constexpr int CAP  = 128;            // bucket capacity per dst (max deg ~45 for this input)
constexpr int GEMM1_B = NN / 16;     // 3125 gemm blocks

// ---- two-phase counting scatter ----
constexpr int CB_SHIFT = 7;                      // 128 dsts per coarse bucket
constexpr int NDB  = 1 << CB_SHIFT;              // 128
constexpr int NCB  = (NN + NDB - 1) >> CB_SHIFT; // 391 coarse buckets
constexpr int CCAP = 3072;           // per-coarse-bucket capacity (mean 2176, +20 sigma)
constexpr int CPAD = 16;             // pad coarse counters: 1 per 64B line
constexpr int SEPB = 2048;           // edges per scatter block (8 per thread)
constexpr int SCAT2_B = (ETOT + SEPB - 1) / SEPB;   // 416 scatter blocks

typedef _Float16 half8 __attribute__((ext_vector_type(8)));
typedef float f32x4 __attribute__((ext_vector_type(4)));
typedef float f32x2 __attribute__((ext_vector_type(2)));

__device__ __forceinline__ float lrelu(float v) { return v >= 0.f ? v : SLOPE * v; }
__device__ __forceinline__ float elu(float v) { return v > 0.f ? v : expm1f(v); }

// ---- fp8 e4m3 helpers (OCP; gfx950 HW cvt when available) ----
__device__ __forceinline__ unsigned pack_fp8x4(float a, float b, float c, float d) {
#if __has_builtin(__builtin_amdgcn_cvt_pk_fp8_f32)
  int v = 0;
  v = __builtin_amdgcn_cvt_pk_fp8_f32(a, b, v, false);
  v = __builtin_amdgcn_cvt_pk_fp8_f32(c, d, v, true);
  return (unsigned)v;
#else
  __hip_fp8_e4m3 fa(a), fb(b), fc(c), fd(d);
  return (unsigned)fa.__x | ((unsigned)fb.__x << 8) |
         ((unsigned)fc.__x << 16) | ((unsigned)fd.__x << 24);
#endif
}

__device__ __forceinline__ float fp8_1(unsigned byte) {   // manual e4m3fn -> f32
  unsigned s = (byte & 0x80u) << 24;
  unsigned em = (byte & 0x7fu) << 20;
  return __uint_as_float(s | em) * 0x1p+120f;
}

// 4-channel fp8 accumulate: acA gets ch{0,1}, acB gets ch{2,3} of the packed word.
__device__ __forceinline__ void agg_ch4(f32x2& acA, f32x2& acB, unsigned u, float al) {
#if __has_builtin(__builtin_amdgcn_cvt_pk_f32_fp8)
  f32x2 lo = __builtin_amdgcn_cvt_pk_f32_fp8((int)u, false);
  f32x2 hi = __builtin_amdgcn_cvt_pk_f32_fp8((int)u, true);
  f32x2 a2 = {al, al};
  asm("v_pk_fma_f32 %0, %1, %2, %0" : "+v"(acA) : "v"(lo), "v"(a2));
  asm("v_pk_fma_f32 %0, %1, %2, %0" : "+v"(acB) : "v"(hi), "v"(a2));
#else
  acA[0] += al * fp8_1(u & 0xffu);
  acA[1] += al * fp8_1((u >> 8) & 0xffu);
  acB[0] += al * fp8_1((u >> 16) & 0xffu);
  acB[1] += al * fp8_1(u >> 24);
#endif
}

// ================= prep: weight transposes + coarse-cnt zeroing ======================
__global__ void prep_kernel(const float* __restrict__ W1, const float* __restrict__ W2,
                            __half* __restrict__ W1T, __half* __restrict__ W2T,
                            int* __restrict__ ccnt) {
  int i = blockIdx.x * blockDim.x + threadIdx.x;
  if (i < F_IN * HC1) {                       // W1 [128][256] -> W1T [256][128]
    int k = i / HC1, n = i - k * HC1;
    W1T[n * F_IN + k] = __float2half(W1[i]);
  } else if (i < TW_TOT) {                    // W2 [256][64] -> W2T [64][256]
    int j = i - F_IN * HC1;
    int k = j / HID, n = j - k * HID;
    W2T[n * HC1 + k] = __float2half(W2[j]);
  } else if (i < TW_TOT + NCB * CPAD) {
    ccnt[i - TW_TOT] = 0;
  }
}

// ================= mega kernel: coarse-scatter blocks || gemm1 blocks ================
__global__ __launch_bounds__(256) void gemm1_scatter_kernel(
    const float* __restrict__ x, const __half* __restrict__ W1T,
    const float* __restrict__ asrc, const float* __restrict__ adst,
    unsigned char* __restrict__ h1, float* __restrict__ ssrc, float* __restrict__ sdst,
    const int* __restrict__ esrc, const int* __restrict__ edst,
    int* __restrict__ ccnt, int* __restrict__ coarse) {
  const int t = threadIdx.x;
  if (blockIdx.x < SCAT2_B) {
    // ---- phase-1 scatter ----
    __shared__ int hist[NCB];
    __shared__ int hbase[NCB];
    for (int i = t; i < NCB; i += 256) hist[i] = 0;
    __syncthreads();
    const int e0 = blockIdx.x * SEPB + t * 8;
    const bool valid = e0 < ETOT;             // ETOT%8==0, e0%8==0 -> all-or-nothing
    int sarr[8], darr[8];
    if (valid) {
      if (e0 < NE) {                          // NE%8==0 -> no straddle
        int4 a = *(const int4*)(esrc + e0);
        int4 b = *(const int4*)(esrc + e0 + 4);
        int4 c = *(const int4*)(edst + e0);
        int4 d4 = *(const int4*)(edst + e0 + 4);
        sarr[0]=a.x; sarr[1]=a.y; sarr[2]=a.z; sarr[3]=a.w;
        sarr[4]=b.x; sarr[5]=b.y; sarr[6]=b.z; sarr[7]=b.w;
        darr[0]=c.x; darr[1]=c.y; darr[2]=c.z; darr[3]=c.w;
        darr[4]=d4.x; darr[5]=d4.y; darr[6]=d4.z; darr[7]=d4.w;
      } else {                                // self-loops
#pragma unroll
        for (int k = 0; k < 8; ++k) { sarr[k] = e0 - NE + k; darr[k] = sarr[k]; }
      }
    }
    int cbv[8], lv[8], pkv[8];
    if (valid) {
#pragma unroll
      for (int k = 0; k < 8; ++k) {
        int d = darr[k];
        cbv[k] = d >> CB_SHIFT;
        pkv[k] = sarr[k] | ((d & (NDB - 1)) << 16);   // src < 65536 fits 16 bits
        lv[k]  = atomicAdd(&hist[cbv[k]], 1);         // LDS atomic (cheap)
      }
    }
    __syncthreads();
    for (int i = t; i < NCB; i += 256) {
      int c = hist[i];
      hbase[i] = c ? atomicAdd(&ccnt[i * CPAD], c) : 0;   // few hundred global atomics/block
    }
    __syncthreads();
    if (valid) {
#pragma unroll
      for (int k = 0; k < 8; ++k) {
        int b = hbase[cbv[k]] + lv[k];
        if (b < CCAP) coarse[cbv[k] * CCAP + b] = pkv[k];
      }
    }
    return;
  }
  // ---- gemm1 part ----
  __shared__ float hs[16][HC1 + 1];
  const int m0 = (blockIdx.x - SCAT2_B) * 16;
  const int wv = t >> 6, lane = t & 63;
  const int lm = lane & 15, quad = lane >> 4;
  const int n0 = wv * 64;       // wave wv owns head wv's 64 channels
  f32x4 acc[4] = {{0.f,0.f,0.f,0.f},{0.f,0.f,0.f,0.f},{0.f,0.f,0.f,0.f},{0.f,0.f,0.f,0.f}};
  const float* arow = x + (size_t)(m0 + lm) * F_IN + quad * 8;
#pragma unroll
  for (int kc = 0; kc < F_IN; kc += 32) {
    float4 u = *(const float4*)(arow + kc);
    float4 v = *(const float4*)(arow + kc + 4);
    half8 a;
    a[0]=(_Float16)u.x; a[1]=(_Float16)u.y; a[2]=(_Float16)u.z; a[3]=(_Float16)u.w;
    a[4]=(_Float16)v.x; a[5]=(_Float16)v.y; a[6]=(_Float16)v.z; a[7]=(_Float16)v.w;
#pragma unroll
    for (int tn = 0; tn < 4; ++tn) {
      half8 b = *(const half8*)(W1T + (size_t)(n0 + tn * 16 + lm) * F_IN + kc + quad * 8);
      acc[tn] = __builtin_amdgcn_mfma_f32_16x16x32_f16(a, b, acc[tn], 0, 0, 0);
    }
  }
  // acc[tn][r] = h[m0 + quad*4 + r][n0 + tn*16 + lm]
#pragma unroll
  for (int tn = 0; tn < 4; ++tn)
#pragma unroll
    for (int r = 0; r < 4; ++r)
      hs[quad * 4 + r][n0 + tn * 16 + lm] = acc[tn][r];
  // scores straight from MFMA registers (no LDS, no bank conflicts):
  // s[row][wv] = sum_{tn,lm} acc[tn][r] * a[n0 + tn*16 + lm]; reduce over lm group.
  {
    float asv[4], adv[4];
#pragma unroll
    for (int tn = 0; tn < 4; ++tn) {
      asv[tn] = asrc[n0 + tn * 16 + lm];
      adv[tn] = adst[n0 + tn * 16 + lm];
    }
#pragma unroll
    for (int r = 0; r < 4; ++r) {
      float ps = acc[0][r] * asv[0] + acc[1][r] * asv[1]
               + acc[2][r] * asv[2] + acc[3][r] * asv[3];
      float pd = acc[0][r] * adv[0] + acc[1][r] * adv[1]
               + acc[2][r] * adv[2] + acc[3][r] * adv[3];
#pragma unroll
      for (int o = 1; o < 16; o <<= 1) {
        ps += __shfl_xor(ps, o, 64);
        pd += __shfl_xor(pd, o, 64);
      }
      if (lm == 0) {
        int row = m0 + quad * 4 + r;
        ssrc[row * HEADS + wv] = ps;
        sdst[row * HEADS + wv] = pd;
      }
    }
  }
  __syncthreads();
  // h1 fp8 write: 16 rows x 256 ch; thread t -> row t>>4, 16 ch at (t&15)*16
  {
    int row = t >> 4, cb = (t & 15) * 16;
    const float* hr = &hs[row][cb];
    uint4 pk;
    pk.x = pack_fp8x4(hr[0],  hr[1],  hr[2],  hr[3]);
    pk.y = pack_fp8x4(hr[4],  hr[5],  hr[6],  hr[7]);
    pk.z = pack_fp8x4(hr[8],  hr[9],  hr[10], hr[11]);
    pk.w = pack_fp8x4(hr[12], hr[13], hr[14], hr[15]);
    *(uint4*)(h1 + (size_t)(m0 + row) * HC1 + cb) = pk;
  }
}

// ================= phase-2: build per-dst buckets from coarse buckets ================
__global__ __launch_bounds__(1024) void bucket_build_kernel(
    const int* __restrict__ ccnt, const int* __restrict__ coarse,
    int* __restrict__ cnt, int* __restrict__ bucket) {
  __shared__ int hist2[NDB];
  const int cb = blockIdx.x, t = threadIdx.x;
  if (t < NDB) hist2[t] = 0;
  __syncthreads();
  const int n = min(ccnt[cb * CPAD], CCAP);
  const int* cbase = coarse + cb * CCAP;
  int j = t;
  int v = (j < n) ? cbase[j] : 0;
  while (j < n) {
    int jn = j + 1024;
    int vn = (jn < n) ? cbase[jn] : 0;        // prefetch next round
    int s = v & 0xFFFF, dlow = (v >> 16) & (NDB - 1);
    int l = atomicAdd(&hist2[dlow], 1);
    if (l < CAP) bucket[(size_t)((cb << CB_SHIFT) | dlow) * CAP + l] = s;
    j = jn; v = vn;
  }
  __syncthreads();
  int d = (cb << CB_SHIFT) | t;
  if (t < NDB && d < NN) cnt[d] = hist2[t];
}

// ================= fused GAT gather, layer 1 (H=4, fp8 h) ===========================
// One wave per dst; lane owns 4 channels. Alphas staged in LDS (zero-padded),
// src quads read uniform from bucket (clamped). No cross-lane reduction.
__global__ __launch_bounds__(256) void gat_gather4_kernel(
    const int* __restrict__ cnt, const int* __restrict__ bucket,
    const float* __restrict__ ss, const float* __restrict__ sd,
    const unsigned char* __restrict__ h, const float* __restrict__ bias,
    __half* __restrict__ outp) {
  __shared__ float paS[4][HEADS][40];    // [wave][head][slot], pitch 40 for bank spread
  const int wv   = threadIdx.x >> 6;
  const int lane = threadIdx.x & 63;
  const int d    = (blockIdx.x * 256 + threadIdx.x) >> 6;
  if (d >= NN) return;
  const int start = d * CAP;
  const int deg   = min(cnt[d], CAP);
  const int hsel  = lane & 3;            // score-phase head
  const int j0    = lane >> 2;           // score-phase edge
  const int head  = lane >> 4;           // agg-phase head of this lane's channels
  const float sdv = sd[d * 4 + hsel];
  float (*pa)[40] = paS[wv];

  f32x2 acA = {0.f, 0.f}, acB = {0.f, 0.f};
  const unsigned char* hb = h + (unsigned)(lane * 4);

  if (deg <= 32) {
    int s0 = 0, s1 = 0;
    float v0 = -INFINITY, v1 = -INFINITY;
    if (j0 < deg)      { s0 = bucket[start + j0];      v0 = lrelu(ss[s0 * 4 + hsel] + sdv); }
    if (j0 + 16 < deg) { s1 = bucket[start + j0 + 16]; v1 = lrelu(ss[s1 * 4 + hsel] + sdv); }
    float mx = fmaxf(v0, v1);
#pragma unroll
    for (int o = 4; o < 64; o <<= 1) mx = fmaxf(mx, __shfl_xor(mx, o, 64));
    float p0 = (j0 < deg)      ? __expf(v0 - mx) : 0.f;
    float p1 = (j0 + 16 < deg) ? __expf(v1 - mx) : 0.f;
    float den = p0 + p1;
#pragma unroll
    for (int o = 4; o < 64; o <<= 1) den += __shfl_xor(den, o, 64);
    const float inv = 1.f / (den + 1e-16f);
    pa[hsel][j0]      = p0 * inv;        // zeros where invalid -> pad slots are 0
    pa[hsel][j0 + 16] = p1 * inv;
    const int nq = (deg + 3) >> 2;
    for (int q = 0; q < nq; ++q) {
      int4   sv = *(const int4*)(bucket + start + q * 4);      // uniform
      float4 av = *(const float4*)&pa[head][q * 4];
      {
        unsigned sj = min((unsigned)sv.x, (unsigned)(NN - 1));
        agg_ch4(acA, acB, *(const unsigned*)(hb + (sj << 8)), av.x);
      }
      {
        unsigned sj = min((unsigned)sv.y, (unsigned)(NN - 1));
        agg_ch4(acA, acB, *(const unsigned*)(hb + (sj << 8)), av.y);
      }
      {
        unsigned sj = min((unsigned)sv.z, (unsigned)(NN - 1));
        agg_ch4(acA, acB, *(const unsigned*)(hb + (sj << 8)), av.z);
      }
      {
        unsigned sj = min((unsigned)sv.w, (unsigned)(NN - 1));
        agg_ch4(acA, acB, *(const unsigned*)(hb + (sj << 8)), av.w);
      }
    }
  } else {
    // chunked (rare): 16 edges per chunk, alphas staged per chunk
    float mx = -INFINITY;
    for (int base = 0; base < deg; base += 16) {
      int j = base + j0;
      float v = (j < deg) ? lrelu(ss[bucket[start + j] * 4 + hsel] + sdv) : -INFINITY;
#pragma unroll
      for (int o = 4; o < 64; o <<= 1) v = fmaxf(v, __shfl_xor(v, o, 64));
      mx = fmaxf(mx, v);
    }
    float den = 0.f;
    for (int base = 0; base < deg; base += 16) {
      int j = base + j0;
      float p = (j < deg) ? __expf(lrelu(ss[bucket[start + j] * 4 + hsel] + sdv) - mx) : 0.f;
#pragma unroll
      for (int o = 4; o < 64; o <<= 1) p += __shfl_xor(p, o, 64);
      den += p;
    }
    const float inv = 1.f / (den + 1e-16f);
    for (int base = 0; base < deg; base += 16) {
      int j = base + j0;
      float pav = 0.f;
      if (j < deg) pav = __expf(lrelu(ss[bucket[start + j] * 4 + hsel] + sdv) - mx) * inv;
      pa[hsel][j0] = pav;
      const int m  = min(16, deg - base);
      const int nq = (m + 3) >> 2;
      for (int q = 0; q < nq; ++q) {
        int4   sv = *(const int4*)(bucket + start + base + q * 4);
        float4 av = *(const float4*)&pa[head][q * 4];
        {
          unsigned sj = min((unsigned)sv.x, (unsigned)(NN - 1));
          agg_ch4(acA, acB, *(const unsigned*)(hb + (sj << 8)), av.x);
        }
        {
          unsigned sj = min((unsigned)sv.y, (unsigned)(NN - 1));
          agg_ch4(acA, acB, *(const unsigned*)(hb + (sj << 8)), av.y);
        }
        {
          unsigned sj = min((unsigned)sv.z, (unsigned)(NN - 1));
          agg_ch4(acA, acB, *(const unsigned*)(hb + (sj << 8)), av.z);
        }
        {
          unsigned sj = min((unsigned)sv.w, (unsigned)(NN - 1));
          agg_ch4(acA, acB, *(const unsigned*)(hb + (sj << 8)), av.w);
        }
      }
    }
  }
  // epilogue: bias + elu + fp16 store, all 64 lanes, 8B each (512B/wave contiguous)
  float4 bv = *(const float4*)(bias + lane * 4);
  float e0 = elu(acA[0] + bv.x), e1 = elu(acA[1] + bv.y);
  float e2 = elu(acB[0] + bv.z), e3 = elu(acB[1] + bv.w);
  union { __half2 h2[2]; uint2 u; } pk;
  pk.h2[0] = __floats2half2_rn(e0, e1);
  pk.h2[1] = __floats2half2_rn(e2, e3);
  *(uint2*)(outp + (size_t)d * HC1 + lane * 4) = pk.u;
}

// ================= fused GAT gather, layer 2 (H=1, fp8 h) ===========================
__global__ __launch_bounds__(256) void gat_gather1_kernel(
    const int* __restrict__ cnt, const int* __restrict__ bucket,
    const float* __restrict__ ss, const float* __restrict__ sd,
    const unsigned char* __restrict__ h, const float* __restrict__ bias,
    float* __restrict__ outp) {
  __shared__ float paS[4][68];
  const int wv   = threadIdx.x >> 6;
  const int lane = threadIdx.x & 63;
  const int d    = (blockIdx.x * 256 + threadIdx.x) >> 6;
  if (d >= NN) return;
  const int start = d * CAP;
  const int deg   = min(cnt[d], CAP);
  const int eg    = lane >> 4;    // edge subgroup (0..3)
  const int cpos  = lane & 15;    // 4B chunk within 64B fp8 row
  const float sdv = sd[d];
  float* pa = paS[wv];
  f32x2 acA = {0.f, 0.f}, acB = {0.f, 0.f};
  const unsigned char* hb = h + (unsigned)(cpos * 4);

  if (deg <= 64) {
    int s = 0; float v = -INFINITY;
    if (lane < deg) { s = bucket[start + lane]; v = lrelu(ss[s] + sdv); }
    float mx = v;
#pragma unroll
    for (int o = 1; o < 64; o <<= 1) mx = fmaxf(mx, __shfl_xor(mx, o, 64));
    float p = (lane < deg) ? __expf(v - mx) : 0.f;
    float den = p;
#pragma unroll
    for (int o = 1; o < 64; o <<= 1) den += __shfl_xor(den, o, 64);
    pa[lane] = p / (den + 1e-16f);       // zeros where invalid -> pad slots are 0
    const int nq = (deg + 3) >> 2;
    for (int q = 0; q < nq; ++q) {
      int slot = q * 4 + eg;
      int sj = bucket[start + slot];
      float al = pa[slot];
      unsigned sc = min((unsigned)sj, (unsigned)(NN - 1));
      agg_ch4(acA, acB, *(const unsigned*)(hb + (sc << 6)), al);
    }
  } else {
    float mx = -INFINITY;
    for (int base = 0; base < deg; base += 64) {
      int j = base + lane;
      float v = (j < deg) ? lrelu(ss[bucket[start + j]] + sdv) : -INFINITY;
#pragma unroll
      for (int o = 1; o < 64; o <<= 1) v = fmaxf(v, __shfl_xor(v, o, 64));
      mx = fmaxf(mx, v);
    }
    float den = 0.f;
    for (int base = 0; base < deg; base += 64) {
      int j = base + lane;
      float p = (j < deg) ? __expf(lrelu(ss[bucket[start + j]] + sdv) - mx) : 0.f;
#pragma unroll
      for (int o = 1; o < 64; o <<= 1) p += __shfl_xor(p, o, 64);
      den += p;
    }
    const float inv = 1.f / (den + 1e-16f);
    for (int base = 0; base < deg; base += 64) {
      int j = base + lane;
      float pav = 0.f;
      if (j < deg) pav = __expf(lrelu(ss[bucket[start + j]] + sdv) - mx) * inv;
      pa[lane] = pav;
      const int m  = min(64, deg - base);
      const int nq = (m + 3) >> 2;
      for (int q = 0; q < nq; ++q) {
        int slot = q * 4 + eg;
        int sj = bucket[start + base + slot];
        float al = pa[slot];
        unsigned sc = min((unsigned)sj, (unsigned)(NN - 1));
        agg_ch4(acA, acB, *(const unsigned*)(hb + (sc << 6)), al);
      }
    }
  }
  // combine the 4 edge subgroups (2 shuffle rounds)
#pragma unroll
  for (int o = 16; o < 64; o <<= 1) {
    f32x2 tv;
    tv[0] = __shfl_xor(acA[0], o, 64); tv[1] = __shfl_xor(acA[1], o, 64); acA += tv;
    tv[0] = __shfl_xor(acB[0], o, 64); tv[1] = __shfl_xor(acB[1], o, 64); acB += tv;
  }
  if (eg == 0) {
    float4 bv = *(const float4*)(bias + cpos * 4);
    float4 r;
    r.x = elu(acA[0] + bv.x);
    r.y = elu(acA[1] + bv.y);
    r.z = elu(acB[0] + bv.z);
    r.w = elu(acB[1] + bv.w);
    *(float4*)(outp + (size_t)d * HID + cpos * 4) = r;
  }
}

// ================= gemm2 (MFMA): 256 threads, 4 waves x 1 col-tile; h2 out fp8 =========
__global__ __launch_bounds__(256) void gemm2_mfma(
    const __half* __restrict__ o1h, const __half* __restrict__ W2T,
    const float* __restrict__ asrc, const float* __restrict__ adst,
    unsigned char* __restrict__ h2, float* __restrict__ ssrc, float* __restrict__ sdst) {
  __shared__ float hs[16][HID + 1];
  const int m0 = blockIdx.x * 16;
  const int t = threadIdx.x;
  const int wv = t >> 6, lane = t & 63;
  const int lm = lane & 15, quad = lane >> 4;
  f32x4 acc = {0.f, 0.f, 0.f, 0.f};
  const __half* arow = o1h + (size_t)(m0 + lm) * HC1 + quad * 8;
#pragma unroll
  for (int kc = 0; kc < HC1; kc += 32) {
    half8 a = *(const half8*)(arow + kc);
    half8 b = *(const half8*)(W2T + (size_t)(wv * 16 + lm) * HC1 + kc + quad * 8);
    acc = __builtin_amdgcn_mfma_f32_16x16x32_f16(a, b, acc, 0, 0, 0);
  }
#pragma unroll
  for (int r = 0; r < 4; ++r)
    hs[quad * 4 + r][wv * 16 + lm] = acc[r];
  __syncthreads();
  {
    int row = t >> 4, c4 = (t & 15) * 4;
    unsigned pk = pack_fp8x4(hs[row][c4], hs[row][c4 + 1], hs[row][c4 + 2], hs[row][c4 + 3]);
    *(unsigned*)(h2 + (size_t)(m0 + row) * HID + c4) = pk;
  }
  if (t < 64) {
    int task = t >> 1, part = t & 1;
    int r = task >> 1, isdst = task & 1;
    const float* a = isdst ? adst : asrc;
    float s = 0.f;
    int c0 = part * 32;
    for (int c = c0; c < c0 + 32; ++c) s += hs[r][c] * a[c];
    s += __shfl_xor(s, 1, 64);
    if (part == 0) (isdst ? sdst : ssrc)[m0 + r] = s;
  }
}

// ---------------- fused pool + FC + log_softmax (gstart inline): one block/graph -------
__global__ __launch_bounds__(1024) void pool_head_kernel(const float* __restrict__ o2,
                                                         const int* __restrict__ batch,
                                                         const float* __restrict__ fcw,
                                                         const float* __restrict__ fcb,
                                                         float* __restrict__ out) {
  __shared__ float red[16][HID];
  __shared__ int sbound[2];
  int g = blockIdx.x;
  int t = threadIdx.x;
  if (t < 2) {                         // graph boundaries via binary search
    int gg = g + t, lo = 0, hi = NN;
    while (lo < hi) { int mid = (lo + hi) >> 1; if (batch[mid] < gg) lo = mid + 1; else hi = mid; }
    sbound[t] = lo;
  }
  __syncthreads();
  int s0 = sbound[0], s1 = sbound[1];
  int c = t & 63, r = t >> 6;          // 16 node-rows in flight
  float acc = 0.f;
  for (int n = s0 + r; n < s1; n += 16) acc += o2[(size_t)n * HID + c];
  red[r][c] = acc;
  __syncthreads();
  if (r == 0) {                        // threads 0..63 = one wave
    float v = 0.f;
#pragma unroll
    for (int k = 0; k < 16; ++k) v += red[k][c];
    v /= fmaxf((float)(s1 - s0), 1.f);
    float p0 = v * fcw[c * 2 + 0];
    float p1 = v * fcw[c * 2 + 1];
#pragma unroll
    for (int o = 1; o < 64; o <<= 1) {
      p0 += __shfl_xor(p0, o, 64);
      p1 += __shfl_xor(p1, o, 64);
    }
    if (c == 0) {
      float l0 = p0 + fcb[0], l1 = p1 + fcb[1];
      float mx = fmaxf(l0, l1);
      float lse = mx + logf(expf(l0 - mx) + expf(l1 - mx));
      out[g * 2 + 0] = l0 - lse;
      out[g * 2 + 1] = l1 - lse;
    }
  }
}

// ---------------- launch ----------------
extern "C" void kernel_launch(void* const* d_in, const int* in_sizes, int n_in,
                              void* d_out, int out_size, void* d_ws, size_t ws_size,
                              hipStream_t stream) {
  const float* x    = (const float*)d_in[0];
  const int*   ei   = (const int*)d_in[1];
  const int*   batch= (const int*)d_in[2];
  const float* W1   = (const float*)d_in[3];
  const float* as1  = (const float*)d_in[4];
  const float* ad1  = (const float*)d_in[5];
  const float* b1   = (const float*)d_in[6];
  const float* W2   = (const float*)d_in[7];
  const float* as2  = (const float*)d_in[8];
  const float* ad2  = (const float*)d_in[9];
  const float* b2   = (const float*)d_in[10];
  const float* fcw  = (const float*)d_in[11];
  const float* fcb  = (const float*)d_in[12];
  float* out = (float*)d_out;
  float* ws  = (float*)d_ws;

  const int* esrc = ei;
  const int* edst = ei + NE;

  // ---- workspace layout (float units) ----
  size_t off = 0;
  float* hreg  = ws + off; off += (size_t)NN * HC1 / 4;  // h1 fp8 [NN,256]
  float* o1reg = ws + off; off += (size_t)NN * HC1 / 2;  // o1 fp16 [NN,256]
  float* l2reg = ws + off; off += (size_t)NN * HC1 / 2;  // h2 fp8 + o2 fp32 (also coarse, earlier)
  float* ss1 = ws + off; off += (size_t)NN * HEADS;
  float* sd1 = ws + off; off += (size_t)NN * HEADS;
  float* ss2 = ws + off; off += NN;
  float* sd2 = ws + off; off += NN;
  __half* W1T = (__half*)(ws + off); off += (size_t)HC1 * F_IN / 2;
  __half* W2T = (__half*)(ws + off); off += (size_t)HID * HC1 / 2;
  int* bucket = (int*)(ws + off); off += (size_t)NN * CAP;   // 25.6 MB
  int* cnt    = (int*)(ws + off); off += NN;                 // fully written by phase-2
  unsigned char* h1 = (unsigned char*)hreg;            // [NN, 256] fp8 e4m3
  __half* o1h = (__half*)o1reg;                        // [NN, 256] fp16
  unsigned char* h2 = (unsigned char*)l2reg;           // [NN, 64] fp8 e4m3
  float*  o2  = l2reg + (size_t)NN * HID / 4;          // [NN, 64] fp32
  // coarse scatter buffers alias l2reg (dead until gemm2): ~4.8 MB < 25.6 MB
  int* coarse = (int*)l2reg;                           // [NCB][CCAP] packed (src | dlow<<16)
  int* ccnt   = (int*)l2reg + (size_t)NCB * CCAP;      // [NCB*CPAD] padded counters

  // ---- prep: transposes + coarse-cnt zero ----
  prep_kernel<<<(TW_TOT + NCB * CPAD + 255) / 256, 256, 0, stream>>>(W1, W2, W1T, W2T, ccnt);

  // ---- phase-1 coarse scatter || layer-1 GEMM (independent; co-scheduled) ----
  gemm1_scatter_kernel<<<SCAT2_B + GEMM1_B, 256, 0, stream>>>(
      x, W1T, as1, ad1, h1, ss1, sd1, esrc, edst, ccnt, coarse);

  // ---- phase-2: LDS-atomic bucket build (one block per coarse bucket) ----
  bucket_build_kernel<<<NCB, 1024, 0, stream>>>(ccnt, coarse, cnt, bucket);

  // ---- layer 1 gather ----
  gat_gather4_kernel<<<(NN + 3) / 4, 256, 0, stream>>>(cnt, bucket, ss1, sd1, h1, b1, o1h);

  // ---- layer 2 ----
  gemm2_mfma<<<NN / 16, 256, 0, stream>>>(o1h, W2T, as2, ad2, h2, ss2, sd2);
  gat_gather1_kernel<<<(NN + 3) / 4, 256, 0, stream>>>(cnt, bucket, ss2, sd2, h2, b2, o2);

  // ---- pool + head (fused, gstart inline) ----
  pool_head_kernel<<<NG, 1024, 0, stream>>>(o2, batch, fcw, fcb, out);
}

// Round 5
// 281.947 us; speedup vs baseline: 1.1587x; 1.0027x over previous
//
#include <hip/hip_runtime.h>
#include <hip/hip_fp16.h>
#include <hip/hip_fp8.h>
#include <math.h>

// ---------------- problem constants ----------------
constexpr int NN   = 50000;          // nodes
constexpr int NE   = 800000;         // edges (before self loops)
constexpr int ETOT = NE + NN;        // 850000 with self loops
constexpr int F_IN = 128;
constexpr int HID  = 64;
constexpr int HEADS = 4;
constexpr int HC1  = HEADS * HID;    // 256
constexpr int NG   = 64;             // graphs
constexpr float SLOPE = 0.2f;
constexpr int TW_TOT = F_IN * HC1 + HC1 * HID;   // transpose work items (49152)
constexpr int CAP  = 128;            // bucket capacity per dst (max deg ~45 for this input)
constexpr int GEMM1_B = NN / 16;     // 3125 gemm blocks

// ---- two-phase counting scatter ----
constexpr int CB_SHIFT = 7;                      // 128 dsts per coarse bucket
constexpr int NDB  = 1 << CB_SHIFT;              // 128
constexpr int NCB  = (NN + NDB - 1) >> CB_SHIFT; // 391 coarse buckets
constexpr int CCAP = 3072;           // per-coarse-bucket capacity (mean 2176, +20 sigma)
constexpr int CPAD = 16;             // pad coarse counters: 1 per 64B line
constexpr int SEPB = 2048;           // edges per scatter block (8 per thread)
constexpr int SCAT2_B = (ETOT + SEPB - 1) / SEPB;   // 416 scatter blocks

// h1/o1 channel permutation: group g = head*16 + lm (4 bytes tn=0..3),
// orig channel = head*64 + tn*16 + lm. Producer packs MFMA regs directly;
// consumers (gather4 groups, b1p, W2T K-axis) all use the same permutation.

typedef _Float16 half8 __attribute__((ext_vector_type(8)));
typedef float f32x4 __attribute__((ext_vector_type(4)));
typedef float f32x2 __attribute__((ext_vector_type(2)));

__device__ __forceinline__ float lrelu(float v) { return v >= 0.f ? v : SLOPE * v; }
__device__ __forceinline__ float elu(float v) { return v > 0.f ? v : expm1f(v); }

// ---- fp8 e4m3 helpers (OCP; gfx950 HW cvt when available) ----
__device__ __forceinline__ unsigned pack_fp8x4(float a, float b, float c, float d) {
#if __has_builtin(__builtin_amdgcn_cvt_pk_fp8_f32)
  int v = 0;
  v = __builtin_amdgcn_cvt_pk_fp8_f32(a, b, v, false);
  v = __builtin_amdgcn_cvt_pk_fp8_f32(c, d, v, true);
  return (unsigned)v;
#else
  __hip_fp8_e4m3 fa(a), fb(b), fc(c), fd(d);
  return (unsigned)fa.__x | ((unsigned)fb.__x << 8) |
         ((unsigned)fc.__x << 16) | ((unsigned)fd.__x << 24);
#endif
}

__device__ __forceinline__ float fp8_1(unsigned byte) {   // manual e4m3fn -> f32
  unsigned s = (byte & 0x80u) << 24;
  unsigned em = (byte & 0x7fu) << 20;
  return __uint_as_float(s | em) * 0x1p+120f;
}

// 4-channel fp8 accumulate: acA gets bytes{0,1}, acB gets bytes{2,3}.
__device__ __forceinline__ void agg_ch4(f32x2& acA, f32x2& acB, unsigned u, float al) {
#if __has_builtin(__builtin_amdgcn_cvt_pk_f32_fp8)
  f32x2 lo = __builtin_amdgcn_cvt_pk_f32_fp8((int)u, false);
  f32x2 hi = __builtin_amdgcn_cvt_pk_f32_fp8((int)u, true);
  f32x2 a2 = {al, al};
  asm("v_pk_fma_f32 %0, %1, %2, %0" : "+v"(acA) : "v"(lo), "v"(a2));
  asm("v_pk_fma_f32 %0, %1, %2, %0" : "+v"(acB) : "v"(hi), "v"(a2));
#else
  acA[0] += al * fp8_1(u & 0xffu);
  acA[1] += al * fp8_1((u >> 8) & 0xffu);
  acB[0] += al * fp8_1((u >> 16) & 0xffu);
  acB[1] += al * fp8_1(u >> 24);
#endif
}

// ================= prep: weight transposes + coarse-cnt zero + b1 permute ============
__global__ void prep_kernel(const float* __restrict__ W1, const float* __restrict__ W2,
                            const float* __restrict__ b1,
                            __half* __restrict__ W1T, __half* __restrict__ W2T,
                            int* __restrict__ ccnt, float* __restrict__ b1p) {
  int i = blockIdx.x * blockDim.x + threadIdx.x;
  if (i < F_IN * HC1) {                       // W1 [128][256] -> W1T [256][128]
    int k = i / HC1, n = i - k * HC1;
    W1T[n * F_IN + k] = __float2half(W1[i]);
  } else if (i < TW_TOT) {                    // W2 [256][64] -> W2T [64][256], K permuted
    int j = i - F_IN * HC1;
    int k = j / HID, n = j - k * HID;
    // kp(k): head=k>>6, tn=(k>>4)&3, lm=k&15 -> g=head*16+lm, k' = g*4+tn
    int kp = (((k >> 6) * 16 + (k & 15)) << 2) | ((k >> 4) & 3);
    W2T[n * HC1 + kp] = __float2half(W2[j]);
  } else if (i < TW_TOT + NCB * CPAD) {
    ccnt[i - TW_TOT] = 0;
  } else if (i < TW_TOT + NCB * CPAD + HC1) {
    int g4 = i - (TW_TOT + NCB * CPAD);
    int g = g4 >> 2, tn = g4 & 3;
    b1p[g4] = b1[(g >> 4) * 64 + tn * 16 + (g & 15)];
  }
}

// ================= mega kernel: coarse-scatter blocks || gemm1 blocks ================
__global__ __launch_bounds__(256) void gemm1_scatter_kernel(
    const float* __restrict__ x, const __half* __restrict__ W1T,
    const float* __restrict__ asrc, const float* __restrict__ adst,
    unsigned char* __restrict__ h1, float* __restrict__ ssrc, float* __restrict__ sdst,
    const int* __restrict__ esrc, const int* __restrict__ edst,
    int* __restrict__ ccnt, int* __restrict__ coarse) {
  const int t = threadIdx.x;
  if (blockIdx.x < SCAT2_B) {
    // ---- phase-1 scatter ----
    __shared__ int hist[NCB];
    __shared__ int hbase[NCB];
    for (int i = t; i < NCB; i += 256) hist[i] = 0;
    __syncthreads();
    const int e0 = blockIdx.x * SEPB + t * 8;
    const bool valid = e0 < ETOT;             // ETOT%8==0, e0%8==0 -> all-or-nothing
    int sarr[8], darr[8];
    if (valid) {
      if (e0 < NE) {                          // NE%8==0 -> no straddle
        int4 a = *(const int4*)(esrc + e0);
        int4 b = *(const int4*)(esrc + e0 + 4);
        int4 c = *(const int4*)(edst + e0);
        int4 d4 = *(const int4*)(edst + e0 + 4);
        sarr[0]=a.x; sarr[1]=a.y; sarr[2]=a.z; sarr[3]=a.w;
        sarr[4]=b.x; sarr[5]=b.y; sarr[6]=b.z; sarr[7]=b.w;
        darr[0]=c.x; darr[1]=c.y; darr[2]=c.z; darr[3]=c.w;
        darr[4]=d4.x; darr[5]=d4.y; darr[6]=d4.z; darr[7]=d4.w;
      } else {                                // self-loops
#pragma unroll
        for (int k = 0; k < 8; ++k) { sarr[k] = e0 - NE + k; darr[k] = sarr[k]; }
      }
    }
    int cbv[8], lv[8], pkv[8];
    if (valid) {
#pragma unroll
      for (int k = 0; k < 8; ++k) {
        int d = darr[k];
        cbv[k] = d >> CB_SHIFT;
        pkv[k] = sarr[k] | ((d & (NDB - 1)) << 16);   // src < 65536 fits 16 bits
        lv[k]  = atomicAdd(&hist[cbv[k]], 1);         // LDS atomic (cheap)
      }
    }
    __syncthreads();
    for (int i = t; i < NCB; i += 256) {
      int c = hist[i];
      hbase[i] = c ? atomicAdd(&ccnt[i * CPAD], c) : 0;   // few hundred global atomics/block
    }
    __syncthreads();
    if (valid) {
#pragma unroll
      for (int k = 0; k < 8; ++k) {
        int b = hbase[cbv[k]] + lv[k];
        if (b < CCAP) coarse[cbv[k] * CCAP + b] = pkv[k];
      }
    }
    return;
  }
  // ---- gemm1 part: NO LDS, scores + fp8 pack straight from MFMA registers ----
  const int m0 = (blockIdx.x - SCAT2_B) * 16;
  const int wv = t >> 6, lane = t & 63;
  const int lm = lane & 15, quad = lane >> 4;
  const int n0 = wv * 64;       // wave wv owns head wv's 64 channels
  f32x4 acc[4] = {{0.f,0.f,0.f,0.f},{0.f,0.f,0.f,0.f},{0.f,0.f,0.f,0.f},{0.f,0.f,0.f,0.f}};
  const float* arow = x + (size_t)(m0 + lm) * F_IN + quad * 8;
#pragma unroll
  for (int kc = 0; kc < F_IN; kc += 32) {
    float4 u = *(const float4*)(arow + kc);
    float4 v = *(const float4*)(arow + kc + 4);
    half8 a;
    a[0]=(_Float16)u.x; a[1]=(_Float16)u.y; a[2]=(_Float16)u.z; a[3]=(_Float16)u.w;
    a[4]=(_Float16)v.x; a[5]=(_Float16)v.y; a[6]=(_Float16)v.z; a[7]=(_Float16)v.w;
#pragma unroll
    for (int tn = 0; tn < 4; ++tn) {
      half8 b = *(const half8*)(W1T + (size_t)(n0 + tn * 16 + lm) * F_IN + kc + quad * 8);
      acc[tn] = __builtin_amdgcn_mfma_f32_16x16x32_f16(a, b, acc[tn], 0, 0, 0);
    }
  }
  // acc[tn][r] = h[m0 + quad*4 + r][n0 + tn*16 + lm]
  // scores from registers: s[row][wv] = sum acc[tn][r] * a[n0+tn*16+lm], reduce over lm
  {
    float asv[4], adv[4];
#pragma unroll
    for (int tn = 0; tn < 4; ++tn) {
      asv[tn] = asrc[n0 + tn * 16 + lm];
      adv[tn] = adst[n0 + tn * 16 + lm];
    }
#pragma unroll
    for (int r = 0; r < 4; ++r) {
      float ps = acc[0][r] * asv[0] + acc[1][r] * asv[1]
               + acc[2][r] * asv[2] + acc[3][r] * asv[3];
      float pd = acc[0][r] * adv[0] + acc[1][r] * adv[1]
               + acc[2][r] * adv[2] + acc[3][r] * adv[3];
#pragma unroll
      for (int o = 1; o < 16; o <<= 1) {
        ps += __shfl_xor(ps, o, 64);
        pd += __shfl_xor(pd, o, 64);
      }
      if (lm == 0) {
        int row = m0 + quad * 4 + r;
        ssrc[row * HEADS + wv] = ps;
        sdst[row * HEADS + wv] = pd;
      }
    }
  }
  // h1 fp8 pack directly from registers into permuted layout:
  // group g = wv*16+lm, byte tn; addr = node*256 + g*4
  {
    const unsigned goff = (unsigned)((wv * 16 + lm) * 4);
#pragma unroll
    for (int r = 0; r < 4; ++r) {
      unsigned pk = pack_fp8x4(acc[0][r], acc[1][r], acc[2][r], acc[3][r]);
      *(unsigned*)(h1 + (size_t)(m0 + quad * 4 + r) * HC1 + goff) = pk;
    }
  }
}

// ================= phase-2: build per-dst buckets from coarse buckets ================
__global__ __launch_bounds__(1024) void bucket_build_kernel(
    const int* __restrict__ ccnt, const int* __restrict__ coarse,
    int* __restrict__ cnt, int* __restrict__ bucket) {
  __shared__ int hist2[NDB];
  const int cb = blockIdx.x, t = threadIdx.x;
  if (t < NDB) hist2[t] = 0;
  __syncthreads();
  const int n = min(ccnt[cb * CPAD], CCAP);
  const int* cbase = coarse + cb * CCAP;
  int j = t;
  int v = (j < n) ? cbase[j] : 0;
  while (j < n) {
    int jn = j + 1024;
    int vn = (jn < n) ? cbase[jn] : 0;        // prefetch next round
    int s = v & 0xFFFF, dlow = (v >> 16) & (NDB - 1);
    int l = atomicAdd(&hist2[dlow], 1);
    if (l < CAP) bucket[(size_t)((cb << CB_SHIFT) | dlow) * CAP + l] = s;
    j = jn; v = vn;
  }
  __syncthreads();
  int d = (cb << CB_SHIFT) | t;
  if (t < NDB && d < NN) cnt[d] = hist2[t];
}

// ================= fused GAT gather, layer 1 (H=4, fp8 h, permuted channels) =========
// One wave per dst; lane owns group lane (4 channels). Alphas staged in LDS
// (zero-padded), src quads read uniform from bucket (clamped).
__global__ __launch_bounds__(256) void gat_gather4_kernel(
    const int* __restrict__ cnt, const int* __restrict__ bucket,
    const float* __restrict__ ss, const float* __restrict__ sd,
    const unsigned char* __restrict__ h, const float* __restrict__ biasp,
    __half* __restrict__ outp) {
  __shared__ float paS[4][HEADS][40];    // [wave][head][slot], pitch 40 for bank spread
  const int wv   = threadIdx.x >> 6;
  const int lane = threadIdx.x & 63;
  const int d    = (blockIdx.x * 256 + threadIdx.x) >> 6;
  if (d >= NN) return;
  const int start = d * CAP;
  const int deg   = min(cnt[d], CAP);
  const int hsel  = lane & 3;            // score-phase head
  const int j0    = lane >> 2;           // score-phase edge
  const int head  = lane >> 4;           // agg-phase head of this lane's group
  const float sdv = sd[d * 4 + hsel];
  float (*pa)[40] = paS[wv];

  f32x2 acA = {0.f, 0.f}, acB = {0.f, 0.f};
  const unsigned char* hb = h + (unsigned)(lane * 4);

  if (deg <= 32) {
    int s0 = 0, s1 = 0;
    float v0 = -INFINITY, v1 = -INFINITY;
    if (j0 < deg)      { s0 = bucket[start + j0];      v0 = lrelu(ss[s0 * 4 + hsel] + sdv); }
    if (j0 + 16 < deg) { s1 = bucket[start + j0 + 16]; v1 = lrelu(ss[s1 * 4 + hsel] + sdv); }
    float mx = fmaxf(v0, v1);
#pragma unroll
    for (int o = 4; o < 64; o <<= 1) mx = fmaxf(mx, __shfl_xor(mx, o, 64));
    float p0 = (j0 < deg)      ? __expf(v0 - mx) : 0.f;
    float p1 = (j0 + 16 < deg) ? __expf(v1 - mx) : 0.f;
    float den = p0 + p1;
#pragma unroll
    for (int o = 4; o < 64; o <<= 1) den += __shfl_xor(den, o, 64);
    const float inv = 1.f / (den + 1e-16f);
    pa[hsel][j0]      = p0 * inv;        // zeros where invalid -> pad slots are 0
    pa[hsel][j0 + 16] = p1 * inv;
    const int nq = (deg + 3) >> 2;
    for (int q = 0; q < nq; ++q) {
      int4   sv = *(const int4*)(bucket + start + q * 4);      // uniform
      float4 av = *(const float4*)&pa[head][q * 4];
      {
        unsigned sj = min((unsigned)sv.x, (unsigned)(NN - 1));
        agg_ch4(acA, acB, *(const unsigned*)(hb + (sj << 8)), av.x);
      }
      {
        unsigned sj = min((unsigned)sv.y, (unsigned)(NN - 1));
        agg_ch4(acA, acB, *(const unsigned*)(hb + (sj << 8)), av.y);
      }
      {
        unsigned sj = min((unsigned)sv.z, (unsigned)(NN - 1));
        agg_ch4(acA, acB, *(const unsigned*)(hb + (sj << 8)), av.z);
      }
      {
        unsigned sj = min((unsigned)sv.w, (unsigned)(NN - 1));
        agg_ch4(acA, acB, *(const unsigned*)(hb + (sj << 8)), av.w);
      }
    }
  } else {
    // chunked (rare): 16 edges per chunk, alphas staged per chunk
    float mx = -INFINITY;
    for (int base = 0; base < deg; base += 16) {
      int j = base + j0;
      float v = (j < deg) ? lrelu(ss[bucket[start + j] * 4 + hsel] + sdv) : -INFINITY;
#pragma unroll
      for (int o = 4; o < 64; o <<= 1) v = fmaxf(v, __shfl_xor(v, o, 64));
      mx = fmaxf(mx, v);
    }
    float den = 0.f;
    for (int base = 0; base < deg; base += 16) {
      int j = base + j0;
      float p = (j < deg) ? __expf(lrelu(ss[bucket[start + j] * 4 + hsel] + sdv) - mx) : 0.f;
#pragma unroll
      for (int o = 4; o < 64; o <<= 1) p += __shfl_xor(p, o, 64);
      den += p;
    }
    const float inv = 1.f / (den + 1e-16f);
    for (int base = 0; base < deg; base += 16) {
      int j = base + j0;
      float pav = 0.f;
      if (j < deg) pav = __expf(lrelu(ss[bucket[start + j] * 4 + hsel] + sdv) - mx) * inv;
      pa[hsel][j0] = pav;
      const int m  = min(16, deg - base);
      const int nq = (m + 3) >> 2;
      for (int q = 0; q < nq; ++q) {
        int4   sv = *(const int4*)(bucket + start + base + q * 4);
        float4 av = *(const float4*)&pa[head][q * 4];
        {
          unsigned sj = min((unsigned)sv.x, (unsigned)(NN - 1));
          agg_ch4(acA, acB, *(const unsigned*)(hb + (sj << 8)), av.x);
        }
        {
          unsigned sj = min((unsigned)sv.y, (unsigned)(NN - 1));
          agg_ch4(acA, acB, *(const unsigned*)(hb + (sj << 8)), av.y);
        }
        {
          unsigned sj = min((unsigned)sv.z, (unsigned)(NN - 1));
          agg_ch4(acA, acB, *(const unsigned*)(hb + (sj << 8)), av.z);
        }
        {
          unsigned sj = min((unsigned)sv.w, (unsigned)(NN - 1));
          agg_ch4(acA, acB, *(const unsigned*)(hb + (sj << 8)), av.w);
        }
      }
    }
  }
  // epilogue: permuted bias + elu + fp16 store (permuted o1), 8B/lane contiguous
  float4 bv = *(const float4*)(biasp + lane * 4);
  float e0 = elu(acA[0] + bv.x), e1 = elu(acA[1] + bv.y);
  float e2 = elu(acB[0] + bv.z), e3 = elu(acB[1] + bv.w);
  union { __half2 h2[2]; uint2 u; } pk;
  pk.h2[0] = __floats2half2_rn(e0, e1);
  pk.h2[1] = __floats2half2_rn(e2, e3);
  *(uint2*)(outp + (size_t)d * HC1 + lane * 4) = pk.u;
}

// ================= fused GAT gather, layer 2 (H=1, fp8 h) ===========================
__global__ __launch_bounds__(256) void gat_gather1_kernel(
    const int* __restrict__ cnt, const int* __restrict__ bucket,
    const float* __restrict__ ss, const float* __restrict__ sd,
    const unsigned char* __restrict__ h, const float* __restrict__ bias,
    float* __restrict__ outp) {
  __shared__ float paS[4][68];
  const int wv   = threadIdx.x >> 6;
  const int lane = threadIdx.x & 63;
  const int d    = (blockIdx.x * 256 + threadIdx.x) >> 6;
  if (d >= NN) return;
  const int start = d * CAP;
  const int deg   = min(cnt[d], CAP);
  const int eg    = lane >> 4;    // edge subgroup (0..3)
  const int cpos  = lane & 15;    // 4B chunk within 64B fp8 row
  const float sdv = sd[d];
  float* pa = paS[wv];
  f32x2 acA = {0.f, 0.f}, acB = {0.f, 0.f};
  const unsigned char* hb = h + (unsigned)(cpos * 4);

  if (deg <= 64) {
    int s = 0; float v = -INFINITY;
    if (lane < deg) { s = bucket[start + lane]; v = lrelu(ss[s] + sdv); }
    float mx = v;
#pragma unroll
    for (int o = 1; o < 64; o <<= 1) mx = fmaxf(mx, __shfl_xor(mx, o, 64));
    float p = (lane < deg) ? __expf(v - mx) : 0.f;
    float den = p;
#pragma unroll
    for (int o = 1; o < 64; o <<= 1) den += __shfl_xor(den, o, 64);
    pa[lane] = p / (den + 1e-16f);       // zeros where invalid -> pad slots are 0
    const int nq = (deg + 3) >> 2;
    for (int q = 0; q < nq; ++q) {
      int slot = q * 4 + eg;
      int sj = bucket[start + slot];
      float al = pa[slot];
      unsigned sc = min((unsigned)sj, (unsigned)(NN - 1));
      agg_ch4(acA, acB, *(const unsigned*)(hb + (sc << 6)), al);
    }
  } else {
    float mx = -INFINITY;
    for (int base = 0; base < deg; base += 64) {
      int j = base + lane;
      float v = (j < deg) ? lrelu(ss[bucket[start + j]] + sdv) : -INFINITY;
#pragma unroll
      for (int o = 1; o < 64; o <<= 1) v = fmaxf(v, __shfl_xor(v, o, 64));
      mx = fmaxf(mx, v);
    }
    float den = 0.f;
    for (int base = 0; base < deg; base += 64) {
      int j = base + lane;
      float p = (j < deg) ? __expf(lrelu(ss[bucket[start + j]] + sdv) - mx) : 0.f;
#pragma unroll
      for (int o = 1; o < 64; o <<= 1) p += __shfl_xor(p, o, 64);
      den += p;
    }
    const float inv = 1.f / (den + 1e-16f);
    for (int base = 0; base < deg; base += 64) {
      int j = base + lane;
      float pav = 0.f;
      if (j < deg) pav = __expf(lrelu(ss[bucket[start + j]] + sdv) - mx) * inv;
      pa[lane] = pav;
      const int m  = min(64, deg - base);
      const int nq = (m + 3) >> 2;
      for (int q = 0; q < nq; ++q) {
        int slot = q * 4 + eg;
        int sj = bucket[start + base + slot];
        float al = pa[slot];
        unsigned sc = min((unsigned)sj, (unsigned)(NN - 1));
        agg_ch4(acA, acB, *(const unsigned*)(hb + (sc << 6)), al);
      }
    }
  }
  // combine the 4 edge subgroups (2 shuffle rounds)
#pragma unroll
  for (int o = 16; o < 64; o <<= 1) {
    f32x2 tv;
    tv[0] = __shfl_xor(acA[0], o, 64); tv[1] = __shfl_xor(acA[1], o, 64); acA += tv;
    tv[0] = __shfl_xor(acB[0], o, 64); tv[1] = __shfl_xor(acB[1], o, 64); acB += tv;
  }
  if (eg == 0) {
    float4 bv = *(const float4*)(bias + cpos * 4);
    float4 r;
    r.x = elu(acA[0] + bv.x);
    r.y = elu(acA[1] + bv.y);
    r.z = elu(acB[0] + bv.z);
    r.w = elu(acB[1] + bv.w);
    *(float4*)(outp + (size_t)d * HID + cpos * 4) = r;
  }
}

// ================= gemm2 (MFMA): consumes permuted o1/W2T; output h2 unpermuted ======
__global__ __launch_bounds__(256) void gemm2_mfma(
    const __half* __restrict__ o1h, const __half* __restrict__ W2T,
    const float* __restrict__ asrc, const float* __restrict__ adst,
    unsigned char* __restrict__ h2, float* __restrict__ ssrc, float* __restrict__ sdst) {
  __shared__ float hs[16][HID + 1];
  const int m0 = blockIdx.x * 16;
  const int t = threadIdx.x;
  const int wv = t >> 6, lane = t & 63;
  const int lm = lane & 15, quad = lane >> 4;
  f32x4 acc = {0.f, 0.f, 0.f, 0.f};
  const __half* arow = o1h + (size_t)(m0 + lm) * HC1 + quad * 8;
#pragma unroll
  for (int kc = 0; kc < HC1; kc += 32) {
    half8 a = *(const half8*)(arow + kc);
    half8 b = *(const half8*)(W2T + (size_t)(wv * 16 + lm) * HC1 + kc + quad * 8);
    acc = __builtin_amdgcn_mfma_f32_16x16x32_f16(a, b, acc, 0, 0, 0);
  }
#pragma unroll
  for (int r = 0; r < 4; ++r)
    hs[quad * 4 + r][wv * 16 + lm] = acc[r];
  __syncthreads();
  {
    int row = t >> 4, c4 = (t & 15) * 4;
    unsigned pk = pack_fp8x4(hs[row][c4], hs[row][c4 + 1], hs[row][c4 + 2], hs[row][c4 + 3]);
    *(unsigned*)(h2 + (size_t)(m0 + row) * HID + c4) = pk;
  }
  if (t < 64) {
    int task = t >> 1, part = t & 1;
    int r = task >> 1, isdst = task & 1;
    const float* a = isdst ? adst : asrc;
    float s = 0.f;
    int c0 = part * 32;
    for (int c = c0; c < c0 + 32; ++c) s += hs[r][c] * a[c];
    s += __shfl_xor(s, 1, 64);
    if (part == 0) (isdst ? sdst : ssrc)[m0 + r] = s;
  }
}

// ---------------- fused pool + FC + log_softmax (gstart inline): one block/graph -------
__global__ __launch_bounds__(1024) void pool_head_kernel(const float* __restrict__ o2,
                                                         const int* __restrict__ batch,
                                                         const float* __restrict__ fcw,
                                                         const float* __restrict__ fcb,
                                                         float* __restrict__ out) {
  __shared__ float red[16][HID];
  __shared__ int sbound[2];
  int g = blockIdx.x;
  int t = threadIdx.x;
  if (t < 2) {                         // graph boundaries via binary search
    int gg = g + t, lo = 0, hi = NN;
    while (lo < hi) { int mid = (lo + hi) >> 1; if (batch[mid] < gg) lo = mid + 1; else hi = mid; }
    sbound[t] = lo;
  }
  __syncthreads();
  int s0 = sbound[0], s1 = sbound[1];
  int c = t & 63, r = t >> 6;          // 16 node-rows in flight
  float acc = 0.f;
  for (int n = s0 + r; n < s1; n += 16) acc += o2[(size_t)n * HID + c];
  red[r][c] = acc;
  __syncthreads();
  if (r == 0) {                        // threads 0..63 = one wave
    float v = 0.f;
#pragma unroll
    for (int k = 0; k < 16; ++k) v += red[k][c];
    v /= fmaxf((float)(s1 - s0), 1.f);
    float p0 = v * fcw[c * 2 + 0];
    float p1 = v * fcw[c * 2 + 1];
#pragma unroll
    for (int o = 1; o < 64; o <<= 1) {
      p0 += __shfl_xor(p0, o, 64);
      p1 += __shfl_xor(p1, o, 64);
    }
    if (c == 0) {
      float l0 = p0 + fcb[0], l1 = p1 + fcb[1];
      float mx = fmaxf(l0, l1);
      float lse = mx + logf(expf(l0 - mx) + expf(l1 - mx));
      out[g * 2 + 0] = l0 - lse;
      out[g * 2 + 1] = l1 - lse;
    }
  }
}

// ---------------- launch ----------------
extern "C" void kernel_launch(void* const* d_in, const int* in_sizes, int n_in,
                              void* d_out, int out_size, void* d_ws, size_t ws_size,
                              hipStream_t stream) {
  const float* x    = (const float*)d_in[0];
  const int*   ei   = (const int*)d_in[1];
  const int*   batch= (const int*)d_in[2];
  const float* W1   = (const float*)d_in[3];
  const float* as1  = (const float*)d_in[4];
  const float* ad1  = (const float*)d_in[5];
  const float* b1   = (const float*)d_in[6];
  const float* W2   = (const float*)d_in[7];
  const float* as2  = (const float*)d_in[8];
  const float* ad2  = (const float*)d_in[9];
  const float* b2   = (const float*)d_in[10];
  const float* fcw  = (const float*)d_in[11];
  const float* fcb  = (const float*)d_in[12];
  float* out = (float*)d_out;
  float* ws  = (float*)d_ws;

  const int* esrc = ei;
  const int* edst = ei + NE;

  // ---- workspace layout (float units) ----
  size_t off = 0;
  float* hreg  = ws + off; off += (size_t)NN * HC1 / 4;  // h1 fp8 [NN,256] (permuted ch)
  float* o1reg = ws + off; off += (size_t)NN * HC1 / 2;  // o1 fp16 [NN,256] (permuted ch)
  float* l2reg = ws + off; off += (size_t)NN * HC1 / 2;  // h2 fp8 + o2 fp32 (also coarse, earlier)
  float* ss1 = ws + off; off += (size_t)NN * HEADS;
  float* sd1 = ws + off; off += (size_t)NN * HEADS;
  float* ss2 = ws + off; off += NN;
  float* sd2 = ws + off; off += NN;
  __half* W1T = (__half*)(ws + off); off += (size_t)HC1 * F_IN / 2;
  __half* W2T = (__half*)(ws + off); off += (size_t)HID * HC1 / 2;
  float* b1p  = ws + off; off += HC1;                    // permuted bias1
  int* bucket = (int*)(ws + off); off += (size_t)NN * CAP;   // 25.6 MB
  int* cnt    = (int*)(ws + off); off += NN;                 // fully written by phase-2
  unsigned char* h1 = (unsigned char*)hreg;            // [NN, 256] fp8 e4m3 (permuted)
  __half* o1h = (__half*)o1reg;                        // [NN, 256] fp16 (permuted)
  unsigned char* h2 = (unsigned char*)l2reg;           // [NN, 64] fp8 e4m3
  float*  o2  = l2reg + (size_t)NN * HID / 4;          // [NN, 64] fp32
  // coarse scatter buffers alias l2reg (dead until gemm2): ~4.8 MB < 25.6 MB
  int* coarse = (int*)l2reg;                           // [NCB][CCAP] packed (src | dlow<<16)
  int* ccnt   = (int*)l2reg + (size_t)NCB * CCAP;      // [NCB*CPAD] padded counters

  // ---- prep: transposes + coarse-cnt zero + b1 permute ----
  prep_kernel<<<(TW_TOT + NCB * CPAD + HC1 + 255) / 256, 256, 0, stream>>>(
      W1, W2, b1, W1T, W2T, ccnt, b1p);

  // ---- phase-1 coarse scatter || layer-1 GEMM (independent; co-scheduled) ----
  gemm1_scatter_kernel<<<SCAT2_B + GEMM1_B, 256, 0, stream>>>(
      x, W1T, as1, ad1, h1, ss1, sd1, esrc, edst, ccnt, coarse);

  // ---- phase-2: LDS-atomic bucket build (one block per coarse bucket) ----
  bucket_build_kernel<<<NCB, 1024, 0, stream>>>(ccnt, coarse, cnt, bucket);

  // ---- layer 1 gather ----
  gat_gather4_kernel<<<(NN + 3) / 4, 256, 0, stream>>>(cnt, bucket, ss1, sd1, h1, b1p, o1h);

  // ---- layer 2 ----
  gemm2_mfma<<<NN / 16, 256, 0, stream>>>(o1h, W2T, as2, ad2, h2, ss2, sd2);
  gat_gather1_kernel<<<(NN + 3) / 4, 256, 0, stream>>>(cnt, bucket, ss2, sd2, h2, b2, o2);

  // ---- pool + head (fused, gstart inline) ----
  pool_head_kernel<<<NG, 1024, 0, stream>>>(o2, batch, fcw, fcb, out);
}

// Round 6
// 279.913 us; speedup vs baseline: 1.1671x; 1.0073x over previous
//
#include <hip/hip_runtime.h>
#include <hip/hip_fp16.h>
#include <hip/hip_fp8.h>
#include <math.h>

// ---------------- problem constants ----------------
constexpr int NN   = 50000;          // nodes
constexpr int NE   = 800000;         // edges (before self loops)
constexpr int ETOT = NE + NN;        // 850000 with self loops
constexpr int F_IN = 128;
constexpr int HID  = 64;
constexpr int HEADS = 4;
constexpr int HC1  = HEADS * HID;    // 256
constexpr int NG   = 64;             // graphs
constexpr float SLOPE = 0.2f;
constexpr int TW_TOT = F_IN * HC1 + HC1 * HID;   // transpose work items (49152)
constexpr int CAP  = 128;            // bucket capacity per dst (max deg ~45 for this input)
constexpr int GEMM1_B = NN / 16;     // 3125 gemm blocks

// ---- atomic-free two-phase counting scatter ----
constexpr int CB_SHIFT = 7;                      // 128 dsts per coarse bucket
constexpr int NDB  = 1 << CB_SHIFT;              // 128
constexpr int NCB  = (NN + NDB - 1) >> CB_SHIFT; // 391 coarse buckets
constexpr int SEPB = 8192;                       // edges per scatter block
constexpr int SCAT_ITER = SEPB / (256 * 8);      // 4 macro-iterations
constexpr int NSB  = (ETOT + SEPB - 1) / SEPB;   // 104 scatter blocks

// h1/o1 channel permutation: group g = head*16 + lm (4 bytes tn=0..3),
// orig channel = head*64 + tn*16 + lm. Producer packs MFMA regs directly;
// consumers (gather4 groups, b1p, W2T K-axis) all use the same permutation.

typedef _Float16 half8 __attribute__((ext_vector_type(8)));
typedef float f32x4 __attribute__((ext_vector_type(4)));
typedef float f32x2 __attribute__((ext_vector_type(2)));

__device__ __forceinline__ float lrelu(float v) { return v >= 0.f ? v : SLOPE * v; }
__device__ __forceinline__ float elu(float v) { return v > 0.f ? v : expm1f(v); }

// ---- fp8 e4m3 helpers (OCP; gfx950 HW cvt when available) ----
__device__ __forceinline__ unsigned pack_fp8x4(float a, float b, float c, float d) {
#if __has_builtin(__builtin_amdgcn_cvt_pk_fp8_f32)
  int v = 0;
  v = __builtin_amdgcn_cvt_pk_fp8_f32(a, b, v, false);
  v = __builtin_amdgcn_cvt_pk_fp8_f32(c, d, v, true);
  return (unsigned)v;
#else
  __hip_fp8_e4m3 fa(a), fb(b), fc(c), fd(d);
  return (unsigned)fa.__x | ((unsigned)fb.__x << 8) |
         ((unsigned)fc.__x << 16) | ((unsigned)fd.__x << 24);
#endif
}

__device__ __forceinline__ float fp8_1(unsigned byte) {   // manual e4m3fn -> f32
  unsigned s = (byte & 0x80u) << 24;
  unsigned em = (byte & 0x7fu) << 20;
  return __uint_as_float(s | em) * 0x1p+120f;
}

// 4-channel fp8 accumulate: acA gets bytes{0,1}, acB gets bytes{2,3}.
__device__ __forceinline__ void agg_ch4(f32x2& acA, f32x2& acB, unsigned u, float al) {
#if __has_builtin(__builtin_amdgcn_cvt_pk_f32_fp8)
  f32x2 lo = __builtin_amdgcn_cvt_pk_f32_fp8((int)u, false);
  f32x2 hi = __builtin_amdgcn_cvt_pk_f32_fp8((int)u, true);
  f32x2 a2 = {al, al};
  asm("v_pk_fma_f32 %0, %1, %2, %0" : "+v"(acA) : "v"(lo), "v"(a2));
  asm("v_pk_fma_f32 %0, %1, %2, %0" : "+v"(acB) : "v"(hi), "v"(a2));
#else
  acA[0] += al * fp8_1(u & 0xffu);
  acA[1] += al * fp8_1((u >> 8) & 0xffu);
  acB[0] += al * fp8_1((u >> 16) & 0xffu);
  acB[1] += al * fp8_1(u >> 24);
#endif
}

// ---- edge macro-load: 8 edges per thread at e0 (ETOT%8==0, NE%8==0) ----
__device__ __forceinline__ void load_edges8(const int* __restrict__ esrc,
                                            const int* __restrict__ edst,
                                            int e0, int* sarr, int* darr) {
  if (e0 < NE) {
    int4 a = *(const int4*)(esrc + e0);
    int4 b = *(const int4*)(esrc + e0 + 4);
    int4 c = *(const int4*)(edst + e0);
    int4 d4 = *(const int4*)(edst + e0 + 4);
    sarr[0]=a.x; sarr[1]=a.y; sarr[2]=a.z; sarr[3]=a.w;
    sarr[4]=b.x; sarr[5]=b.y; sarr[6]=b.z; sarr[7]=b.w;
    darr[0]=c.x; darr[1]=c.y; darr[2]=c.z; darr[3]=c.w;
    darr[4]=d4.x; darr[5]=d4.y; darr[6]=d4.z; darr[7]=d4.w;
  } else {                                // self-loops
#pragma unroll
    for (int k = 0; k < 8; ++k) { sarr[k] = e0 - NE + k; darr[k] = sarr[k]; }
  }
}

// ================= prep: weight transposes + b1 permute ==============================
__global__ void prep_kernel(const float* __restrict__ W1, const float* __restrict__ W2,
                            const float* __restrict__ b1,
                            __half* __restrict__ W1T, __half* __restrict__ W2T,
                            float* __restrict__ b1p) {
  int i = blockIdx.x * blockDim.x + threadIdx.x;
  if (i < F_IN * HC1) {                       // W1 [128][256] -> W1T [256][128]
    int k = i / HC1, n = i - k * HC1;
    W1T[n * F_IN + k] = __float2half(W1[i]);
  } else if (i < TW_TOT) {                    // W2 [256][64] -> W2T [64][256], K permuted
    int j = i - F_IN * HC1;
    int k = j / HID, n = j - k * HID;
    // kp(k): head=k>>6, tn=(k>>4)&3, lm=k&15 -> g=head*16+lm, k' = g*4+tn
    int kp = (((k >> 6) * 16 + (k & 15)) << 2) | ((k >> 4) & 3);
    W2T[n * HC1 + kp] = __float2half(W2[j]);
  } else if (i < TW_TOT + HC1) {
    int g4 = i - TW_TOT;
    int g = g4 >> 2, tn = g4 & 3;
    b1p[g4] = b1[(g >> 4) * 64 + tn * 16 + (g & 15)];
  }
}

// ================= mega kernel: atomic-free scatter blocks || gemm1 blocks ===========
__global__ __launch_bounds__(256) void gemm1_scatter_kernel(
    const float* __restrict__ x, const __half* __restrict__ W1T,
    const float* __restrict__ asrc, const float* __restrict__ adst,
    unsigned char* __restrict__ h1, float* __restrict__ ssrc, float* __restrict__ sdst,
    const int* __restrict__ esrc, const int* __restrict__ edst,
    int* __restrict__ blockcnt, int* __restrict__ blockoff, int* __restrict__ scmp) {
  const int t = threadIdx.x;
  if (blockIdx.x < NSB) {
    // ---- phase-1: block-local segmented scatter, ZERO global atomics ----
    __shared__ int hist[512];     // coarse histogram (padded to 512 for scan)
    __shared__ int buf2[512];     // scan double-buffer / base
    __shared__ int cursor[512];   // per-cb write cursor
    for (int i = t; i < 512; i += 256) { hist[i] = 0; cursor[i] = 0; }
    __syncthreads();
    const int ebase = blockIdx.x * SEPB;
    // pass A: histogram
    for (int it = 0; it < SCAT_ITER; ++it) {
      int e0 = ebase + it * 2048 + t * 8;
      if (e0 < ETOT) {
        int sarr[8], darr[8];
        load_edges8(esrc, edst, e0, sarr, darr);
#pragma unroll
        for (int k = 0; k < 8; ++k) atomicAdd(&hist[darr[k] >> CB_SHIFT], 1);
      }
    }
    __syncthreads();
    // per-block counts out (coalesced)
    for (int i = t; i < NCB; i += 256) blockcnt[blockIdx.x * NCB + i] = hist[i];
    // Hillis-Steele inclusive scan over 512 entries
    int* src = hist; int* dst = buf2;
    for (int off = 1; off < 512; off <<= 1) {
      for (int i = t; i < 512; i += 256) {
        int v = src[i];
        if (i >= off) v += src[i - off];
        dst[i] = v;
      }
      __syncthreads();
      int* tmp = src; src = dst; dst = tmp;
    }
    // exclusive base into dst; offsets out
    for (int i = t; i < NCB; i += 256) {
      int b = (i == 0) ? 0 : src[i - 1];
      dst[i] = b;
      blockoff[blockIdx.x * NCB + i] = ebase + b;
    }
    __syncthreads();
    // pass B: reload edges (L2-hot) and pack grouped-by-cb into own segment
    for (int it = 0; it < SCAT_ITER; ++it) {
      int e0 = ebase + it * 2048 + t * 8;
      if (e0 < ETOT) {
        int sarr[8], darr[8];
        load_edges8(esrc, edst, e0, sarr, darr);
#pragma unroll
        for (int k = 0; k < 8; ++k) {
          int d = darr[k];
          int cb = d >> CB_SHIFT;
          int pkv = sarr[k] | ((d & (NDB - 1)) << 16);   // src < 65536 fits 16 bits
          int slot = dst[cb] + atomicAdd(&cursor[cb], 1);  // LDS only
          scmp[ebase + slot] = pkv;                        // dense, own segment
        }
      }
    }
    return;
  }
  // ---- gemm1 part: NO LDS, scores + fp8 pack straight from MFMA registers ----
  const int m0 = (blockIdx.x - NSB) * 16;
  const int wv = t >> 6, lane = t & 63;
  const int lm = lane & 15, quad = lane >> 4;
  const int n0 = wv * 64;       // wave wv owns head wv's 64 channels
  f32x4 acc[4] = {{0.f,0.f,0.f,0.f},{0.f,0.f,0.f,0.f},{0.f,0.f,0.f,0.f},{0.f,0.f,0.f,0.f}};
  const float* arow = x + (size_t)(m0 + lm) * F_IN + quad * 8;
#pragma unroll
  for (int kc = 0; kc < F_IN; kc += 32) {
    float4 u = *(const float4*)(arow + kc);
    float4 v = *(const float4*)(arow + kc + 4);
    half8 a;
    a[0]=(_Float16)u.x; a[1]=(_Float16)u.y; a[2]=(_Float16)u.z; a[3]=(_Float16)u.w;
    a[4]=(_Float16)v.x; a[5]=(_Float16)v.y; a[6]=(_Float16)v.z; a[7]=(_Float16)v.w;
#pragma unroll
    for (int tn = 0; tn < 4; ++tn) {
      half8 b = *(const half8*)(W1T + (size_t)(n0 + tn * 16 + lm) * F_IN + kc + quad * 8);
      acc[tn] = __builtin_amdgcn_mfma_f32_16x16x32_f16(a, b, acc[tn], 0, 0, 0);
    }
  }
  // acc[tn][r] = h[m0 + quad*4 + r][n0 + tn*16 + lm]
  // scores from registers: s[row][wv] = sum acc[tn][r] * a[n0+tn*16+lm], reduce over lm
  {
    float asv[4], adv[4];
#pragma unroll
    for (int tn = 0; tn < 4; ++tn) {
      asv[tn] = asrc[n0 + tn * 16 + lm];
      adv[tn] = adst[n0 + tn * 16 + lm];
    }
#pragma unroll
    for (int r = 0; r < 4; ++r) {
      float ps = acc[0][r] * asv[0] + acc[1][r] * asv[1]
               + acc[2][r] * asv[2] + acc[3][r] * asv[3];
      float pd = acc[0][r] * adv[0] + acc[1][r] * adv[1]
               + acc[2][r] * adv[2] + acc[3][r] * adv[3];
#pragma unroll
      for (int o = 1; o < 16; o <<= 1) {
        ps += __shfl_xor(ps, o, 64);
        pd += __shfl_xor(pd, o, 64);
      }
      if (lm == 0) {
        int row = m0 + quad * 4 + r;
        ssrc[row * HEADS + wv] = ps;
        sdst[row * HEADS + wv] = pd;
      }
    }
  }
  // h1 fp8 pack directly from registers into permuted layout:
  // group g = wv*16+lm, byte tn; addr = node*256 + g*4
  {
    const unsigned goff = (unsigned)((wv * 16 + lm) * 4);
#pragma unroll
    for (int r = 0; r < 4; ++r) {
      unsigned pk = pack_fp8x4(acc[0][r], acc[1][r], acc[2][r], acc[3][r]);
      *(unsigned*)(h1 + (size_t)(m0 + quad * 4 + r) * HC1 + goff) = pk;
    }
  }
}

// ================= phase-2: concatenate per-block runs into per-dst buckets =========
// One block per coarse bucket; wave w walks runs b = w, w+16, ...; LDS-only atomics.
__global__ __launch_bounds__(1024) void bucket_build_kernel(
    const int* __restrict__ blockcnt, const int* __restrict__ blockoff,
    const int* __restrict__ scmp, int* __restrict__ cnt, int* __restrict__ bucket) {
  __shared__ int hist2[NDB];
  const int cb = blockIdx.x, t = threadIdx.x;
  const int wv = t >> 6, lane = t & 63;
  if (t < NDB) hist2[t] = 0;
  __syncthreads();
  for (int b = wv; b < NSB; b += 16) {
    int n   = blockcnt[b * NCB + cb];
    int off = blockoff[b * NCB + cb];
    for (int j = lane; j < n; j += 64) {
      int v = scmp[off + j];
      int s = v & 0xFFFF, dlow = (v >> 16) & (NDB - 1);
      int l = atomicAdd(&hist2[dlow], 1);
      if (l < CAP) bucket[(size_t)((cb << CB_SHIFT) | dlow) * CAP + l] = s;
    }
  }
  __syncthreads();
  int d = (cb << CB_SHIFT) | t;
  if (t < NDB && d < NN) cnt[d] = hist2[t];
}

// ================= fused GAT gather, layer 1 (H=4, fp8 h, permuted channels) =========
// One wave per dst; lane owns group lane (4 channels). Alphas staged in LDS
// (zero-padded), src quads read uniform from bucket (clamped).
__global__ __launch_bounds__(256) void gat_gather4_kernel(
    const int* __restrict__ cnt, const int* __restrict__ bucket,
    const float* __restrict__ ss, const float* __restrict__ sd,
    const unsigned char* __restrict__ h, const float* __restrict__ biasp,
    __half* __restrict__ outp) {
  __shared__ float paS[4][HEADS][40];    // [wave][head][slot], pitch 40 for bank spread
  const int wv   = threadIdx.x >> 6;
  const int lane = threadIdx.x & 63;
  const int d    = (blockIdx.x * 256 + threadIdx.x) >> 6;
  if (d >= NN) return;
  const int start = d * CAP;
  const int deg   = min(cnt[d], CAP);
  const int hsel  = lane & 3;            // score-phase head
  const int j0    = lane >> 2;           // score-phase edge
  const int head  = lane >> 4;           // agg-phase head of this lane's group
  const float sdv = sd[d * 4 + hsel];
  float (*pa)[40] = paS[wv];

  f32x2 acA = {0.f, 0.f}, acB = {0.f, 0.f};
  const unsigned char* hb = h + (unsigned)(lane * 4);

  if (deg <= 32) {
    int s0 = 0, s1 = 0;
    float v0 = -INFINITY, v1 = -INFINITY;
    if (j0 < deg)      { s0 = bucket[start + j0];      v0 = lrelu(ss[s0 * 4 + hsel] + sdv); }
    if (j0 + 16 < deg) { s1 = bucket[start + j0 + 16]; v1 = lrelu(ss[s1 * 4 + hsel] + sdv); }
    float mx = fmaxf(v0, v1);
#pragma unroll
    for (int o = 4; o < 64; o <<= 1) mx = fmaxf(mx, __shfl_xor(mx, o, 64));
    float p0 = (j0 < deg)      ? __expf(v0 - mx) : 0.f;
    float p1 = (j0 + 16 < deg) ? __expf(v1 - mx) : 0.f;
    float den = p0 + p1;
#pragma unroll
    for (int o = 4; o < 64; o <<= 1) den += __shfl_xor(den, o, 64);
    const float inv = 1.f / (den + 1e-16f);
    pa[hsel][j0]      = p0 * inv;        // zeros where invalid -> pad slots are 0
    pa[hsel][j0 + 16] = p1 * inv;
    const int nq = (deg + 3) >> 2;
    for (int q = 0; q < nq; ++q) {
      int4   sv = *(const int4*)(bucket + start + q * 4);      // uniform
      float4 av = *(const float4*)&pa[head][q * 4];
      {
        unsigned sj = min((unsigned)sv.x, (unsigned)(NN - 1));
        agg_ch4(acA, acB, *(const unsigned*)(hb + (sj << 8)), av.x);
      }
      {
        unsigned sj = min((unsigned)sv.y, (unsigned)(NN - 1));
        agg_ch4(acA, acB, *(const unsigned*)(hb + (sj << 8)), av.y);
      }
      {
        unsigned sj = min((unsigned)sv.z, (unsigned)(NN - 1));
        agg_ch4(acA, acB, *(const unsigned*)(hb + (sj << 8)), av.z);
      }
      {
        unsigned sj = min((unsigned)sv.w, (unsigned)(NN - 1));
        agg_ch4(acA, acB, *(const unsigned*)(hb + (sj << 8)), av.w);
      }
    }
  } else {
    // chunked (rare): 16 edges per chunk, alphas staged per chunk
    float mx = -INFINITY;
    for (int base = 0; base < deg; base += 16) {
      int j = base + j0;
      float v = (j < deg) ? lrelu(ss[bucket[start + j] * 4 + hsel] + sdv) : -INFINITY;
#pragma unroll
      for (int o = 4; o < 64; o <<= 1) v = fmaxf(v, __shfl_xor(v, o, 64));
      mx = fmaxf(mx, v);
    }
    float den = 0.f;
    for (int base = 0; base < deg; base += 16) {
      int j = base + j0;
      float p = (j < deg) ? __expf(lrelu(ss[bucket[start + j] * 4 + hsel] + sdv) - mx) : 0.f;
#pragma unroll
      for (int o = 4; o < 64; o <<= 1) p += __shfl_xor(p, o, 64);
      den += p;
    }
    const float inv = 1.f / (den + 1e-16f);
    for (int base = 0; base < deg; base += 16) {
      int j = base + j0;
      float pav = 0.f;
      if (j < deg) pav = __expf(lrelu(ss[bucket[start + j] * 4 + hsel] + sdv) - mx) * inv;
      pa[hsel][j0] = pav;
      const int m  = min(16, deg - base);
      const int nq = (m + 3) >> 2;
      for (int q = 0; q < nq; ++q) {
        int4   sv = *(const int4*)(bucket + start + base + q * 4);
        float4 av = *(const float4*)&pa[head][q * 4];
        {
          unsigned sj = min((unsigned)sv.x, (unsigned)(NN - 1));
          agg_ch4(acA, acB, *(const unsigned*)(hb + (sj << 8)), av.x);
        }
        {
          unsigned sj = min((unsigned)sv.y, (unsigned)(NN - 1));
          agg_ch4(acA, acB, *(const unsigned*)(hb + (sj << 8)), av.y);
        }
        {
          unsigned sj = min((unsigned)sv.z, (unsigned)(NN - 1));
          agg_ch4(acA, acB, *(const unsigned*)(hb + (sj << 8)), av.z);
        }
        {
          unsigned sj = min((unsigned)sv.w, (unsigned)(NN - 1));
          agg_ch4(acA, acB, *(const unsigned*)(hb + (sj << 8)), av.w);
        }
      }
    }
  }
  // epilogue: permuted bias + elu + fp16 store (permuted o1), 8B/lane contiguous
  float4 bv = *(const float4*)(biasp + lane * 4);
  float e0 = elu(acA[0] + bv.x), e1 = elu(acA[1] + bv.y);
  float e2 = elu(acB[0] + bv.z), e3 = elu(acB[1] + bv.w);
  union { __half2 h2[2]; uint2 u; } pk;
  pk.h2[0] = __floats2half2_rn(e0, e1);
  pk.h2[1] = __floats2half2_rn(e2, e3);
  *(uint2*)(outp + (size_t)d * HC1 + lane * 4) = pk.u;
}

// ================= fused GAT gather, layer 2 (H=1, fp8 h) ===========================
__global__ __launch_bounds__(256) void gat_gather1_kernel(
    const int* __restrict__ cnt, const int* __restrict__ bucket,
    const float* __restrict__ ss, const float* __restrict__ sd,
    const unsigned char* __restrict__ h, const float* __restrict__ bias,
    float* __restrict__ outp) {
  __shared__ float paS[4][68];
  const int wv   = threadIdx.x >> 6;
  const int lane = threadIdx.x & 63;
  const int d    = (blockIdx.x * 256 + threadIdx.x) >> 6;
  if (d >= NN) return;
  const int start = d * CAP;
  const int deg   = min(cnt[d], CAP);
  const int eg    = lane >> 4;    // edge subgroup (0..3)
  const int cpos  = lane & 15;    // 4B chunk within 64B fp8 row
  const float sdv = sd[d];
  float* pa = paS[wv];
  f32x2 acA = {0.f, 0.f}, acB = {0.f, 0.f};
  const unsigned char* hb = h + (unsigned)(cpos * 4);

  if (deg <= 64) {
    int s = 0; float v = -INFINITY;
    if (lane < deg) { s = bucket[start + lane]; v = lrelu(ss[s] + sdv); }
    float mx = v;
#pragma unroll
    for (int o = 1; o < 64; o <<= 1) mx = fmaxf(mx, __shfl_xor(mx, o, 64));
    float p = (lane < deg) ? __expf(v - mx) : 0.f;
    float den = p;
#pragma unroll
    for (int o = 1; o < 64; o <<= 1) den += __shfl_xor(den, o, 64);
    pa[lane] = p / (den + 1e-16f);       // zeros where invalid -> pad slots are 0
    const int nq = (deg + 3) >> 2;
    for (int q = 0; q < nq; ++q) {
      int slot = q * 4 + eg;
      int sj = bucket[start + slot];
      float al = pa[slot];
      unsigned sc = min((unsigned)sj, (unsigned)(NN - 1));
      agg_ch4(acA, acB, *(const unsigned*)(hb + (sc << 6)), al);
    }
  } else {
    float mx = -INFINITY;
    for (int base = 0; base < deg; base += 64) {
      int j = base + lane;
      float v = (j < deg) ? lrelu(ss[bucket[start + j]] + sdv) : -INFINITY;
#pragma unroll
      for (int o = 1; o < 64; o <<= 1) v = fmaxf(v, __shfl_xor(v, o, 64));
      mx = fmaxf(mx, v);
    }
    float den = 0.f;
    for (int base = 0; base < deg; base += 64) {
      int j = base + lane;
      float p = (j < deg) ? __expf(lrelu(ss[bucket[start + j]] + sdv) - mx) : 0.f;
#pragma unroll
      for (int o = 1; o < 64; o <<= 1) p += __shfl_xor(p, o, 64);
      den += p;
    }
    const float inv = 1.f / (den + 1e-16f);
    for (int base = 0; base < deg; base += 64) {
      int j = base + lane;
      float pav = 0.f;
      if (j < deg) pav = __expf(lrelu(ss[bucket[start + j]] + sdv) - mx) * inv;
      pa[lane] = pav;
      const int m  = min(64, deg - base);
      const int nq = (m + 3) >> 2;
      for (int q = 0; q < nq; ++q) {
        int slot = q * 4 + eg;
        int sj = bucket[start + base + slot];
        float al = pa[slot];
        unsigned sc = min((unsigned)sj, (unsigned)(NN - 1));
        agg_ch4(acA, acB, *(const unsigned*)(hb + (sc << 6)), al);
      }
    }
  }
  // combine the 4 edge subgroups (2 shuffle rounds)
#pragma unroll
  for (int o = 16; o < 64; o <<= 1) {
    f32x2 tv;
    tv[0] = __shfl_xor(acA[0], o, 64); tv[1] = __shfl_xor(acA[1], o, 64); acA += tv;
    tv[0] = __shfl_xor(acB[0], o, 64); tv[1] = __shfl_xor(acB[1], o, 64); acB += tv;
  }
  if (eg == 0) {
    float4 bv = *(const float4*)(bias + cpos * 4);
    float4 r;
    r.x = elu(acA[0] + bv.x);
    r.y = elu(acA[1] + bv.y);
    r.z = elu(acB[0] + bv.z);
    r.w = elu(acB[1] + bv.w);
    *(float4*)(outp + (size_t)d * HID + cpos * 4) = r;
  }
}

// ================= gemm2 (MFMA): consumes permuted o1/W2T; output h2 unpermuted ======
__global__ __launch_bounds__(256) void gemm2_mfma(
    const __half* __restrict__ o1h, const __half* __restrict__ W2T,
    const float* __restrict__ asrc, const float* __restrict__ adst,
    unsigned char* __restrict__ h2, float* __restrict__ ssrc, float* __restrict__ sdst) {
  __shared__ float hs[16][HID + 1];
  const int m0 = blockIdx.x * 16;
  const int t = threadIdx.x;
  const int wv = t >> 6, lane = t & 63;
  const int lm = lane & 15, quad = lane >> 4;
  f32x4 acc = {0.f, 0.f, 0.f, 0.f};
  const __half* arow = o1h + (size_t)(m0 + lm) * HC1 + quad * 8;
#pragma unroll
  for (int kc = 0; kc < HC1; kc += 32) {
    half8 a = *(const half8*)(arow + kc);
    half8 b = *(const half8*)(W2T + (size_t)(wv * 16 + lm) * HC1 + kc + quad * 8);
    acc = __builtin_amdgcn_mfma_f32_16x16x32_f16(a, b, acc, 0, 0, 0);
  }
#pragma unroll
  for (int r = 0; r < 4; ++r)
    hs[quad * 4 + r][wv * 16 + lm] = acc[r];
  __syncthreads();
  {
    int row = t >> 4, c4 = (t & 15) * 4;
    unsigned pk = pack_fp8x4(hs[row][c4], hs[row][c4 + 1], hs[row][c4 + 2], hs[row][c4 + 3]);
    *(unsigned*)(h2 + (size_t)(m0 + row) * HID + c4) = pk;
  }
  if (t < 64) {
    int task = t >> 1, part = t & 1;
    int r = task >> 1, isdst = task & 1;
    const float* a = isdst ? adst : asrc;
    float s = 0.f;
    int c0 = part * 32;
    for (int c = c0; c < c0 + 32; ++c) s += hs[r][c] * a[c];
    s += __shfl_xor(s, 1, 64);
    if (part == 0) (isdst ? sdst : ssrc)[m0 + r] = s;
  }
}

// ---------------- fused pool + FC + log_softmax (gstart inline): one block/graph -------
__global__ __launch_bounds__(1024) void pool_head_kernel(const float* __restrict__ o2,
                                                         const int* __restrict__ batch,
                                                         const float* __restrict__ fcw,
                                                         const float* __restrict__ fcb,
                                                         float* __restrict__ out) {
  __shared__ float red[16][HID];
  __shared__ int sbound[2];
  int g = blockIdx.x;
  int t = threadIdx.x;
  if (t < 2) {                         // graph boundaries via binary search
    int gg = g + t, lo = 0, hi = NN;
    while (lo < hi) { int mid = (lo + hi) >> 1; if (batch[mid] < gg) lo = mid + 1; else hi = mid; }
    sbound[t] = lo;
  }
  __syncthreads();
  int s0 = sbound[0], s1 = sbound[1];
  int c = t & 63, r = t >> 6;          // 16 node-rows in flight
  float acc = 0.f;
  for (int n = s0 + r; n < s1; n += 16) acc += o2[(size_t)n * HID + c];
  red[r][c] = acc;
  __syncthreads();
  if (r == 0) {                        // threads 0..63 = one wave
    float v = 0.f;
#pragma unroll
    for (int k = 0; k < 16; ++k) v += red[k][c];
    v /= fmaxf((float)(s1 - s0), 1.f);
    float p0 = v * fcw[c * 2 + 0];
    float p1 = v * fcw[c * 2 + 1];
#pragma unroll
    for (int o = 1; o < 64; o <<= 1) {
      p0 += __shfl_xor(p0, o, 64);
      p1 += __shfl_xor(p1, o, 64);
    }
    if (c == 0) {
      float l0 = p0 + fcb[0], l1 = p1 + fcb[1];
      float mx = fmaxf(l0, l1);
      float lse = mx + logf(expf(l0 - mx) + expf(l1 - mx));
      out[g * 2 + 0] = l0 - lse;
      out[g * 2 + 1] = l1 - lse;
    }
  }
}

// ---------------- launch ----------------
extern "C" void kernel_launch(void* const* d_in, const int* in_sizes, int n_in,
                              void* d_out, int out_size, void* d_ws, size_t ws_size,
                              hipStream_t stream) {
  const float* x    = (const float*)d_in[0];
  const int*   ei   = (const int*)d_in[1];
  const int*   batch= (const int*)d_in[2];
  const float* W1   = (const float*)d_in[3];
  const float* as1  = (const float*)d_in[4];
  const float* ad1  = (const float*)d_in[5];
  const float* b1   = (const float*)d_in[6];
  const float* W2   = (const float*)d_in[7];
  const float* as2  = (const float*)d_in[8];
  const float* ad2  = (const float*)d_in[9];
  const float* b2   = (const float*)d_in[10];
  const float* fcw  = (const float*)d_in[11];
  const float* fcb  = (const float*)d_in[12];
  float* out = (float*)d_out;
  float* ws  = (float*)d_ws;

  const int* esrc = ei;
  const int* edst = ei + NE;

  // ---- workspace layout (float units) ----
  size_t off = 0;
  float* hreg  = ws + off; off += (size_t)NN * HC1 / 4;  // h1 fp8 [NN,256] (permuted ch)
  float* o1reg = ws + off; off += (size_t)NN * HC1 / 2;  // o1 fp16 [NN,256] (permuted ch)
  float* l2reg = ws + off; off += (size_t)NN * HC1 / 2;  // h2 fp8 + o2 fp32 (also scmp, earlier)
  float* ss1 = ws + off; off += (size_t)NN * HEADS;
  float* sd1 = ws + off; off += (size_t)NN * HEADS;
  float* ss2 = ws + off; off += NN;
  float* sd2 = ws + off; off += NN;
  __half* W1T = (__half*)(ws + off); off += (size_t)HC1 * F_IN / 2;
  __half* W2T = (__half*)(ws + off); off += (size_t)HID * HC1 / 2;
  float* b1p  = ws + off; off += HC1;                    // permuted bias1
  int* bucket = (int*)(ws + off); off += (size_t)NN * CAP;   // 25.6 MB
  int* cnt    = (int*)(ws + off); off += NN;                 // fully written by phase-2
  unsigned char* h1 = (unsigned char*)hreg;            // [NN, 256] fp8 e4m3 (permuted)
  __half* o1h = (__half*)o1reg;                        // [NN, 256] fp16 (permuted)
  unsigned char* h2 = (unsigned char*)l2reg;           // [NN, 64] fp8 e4m3
  float*  o2  = l2reg + (size_t)NN * HID / 4;          // [NN, 64] fp32
  // scatter staging aliases l2reg (dead until gemm2): 3.4 + 0.33 MB < 25.6 MB
  int* scmp     = (int*)l2reg;                         // [ETOT] packed (src | dlow<<16)
  int* blockcnt = (int*)l2reg + ETOT;                  // [NSB][NCB]
  int* blockoff = blockcnt + (size_t)NSB * NCB;        // [NSB][NCB]

  // ---- prep: transposes + b1 permute (no counter zeroing needed) ----
  prep_kernel<<<(TW_TOT + HC1 + 255) / 256, 256, 0, stream>>>(
      W1, W2, b1, W1T, W2T, b1p);

  // ---- phase-1 atomic-free scatter || layer-1 GEMM (independent; co-scheduled) ----
  gemm1_scatter_kernel<<<NSB + GEMM1_B, 256, 0, stream>>>(
      x, W1T, as1, ad1, h1, ss1, sd1, esrc, edst, blockcnt, blockoff, scmp);

  // ---- phase-2: run-concatenating bucket build (one block per coarse bucket) ----
  bucket_build_kernel<<<NCB, 1024, 0, stream>>>(blockcnt, blockoff, scmp, cnt, bucket);

  // ---- layer 1 gather ----
  gat_gather4_kernel<<<(NN + 3) / 4, 256, 0, stream>>>(cnt, bucket, ss1, sd1, h1, b1p, o1h);

  // ---- layer 2 ----
  gemm2_mfma<<<NN / 16, 256, 0, stream>>>(o1h, W2T, as2, ad2, h2, ss2, sd2);
  gat_gather1_kernel<<<(NN + 3) / 4, 256, 0, stream>>>(cnt, bucket, ss2, sd2, h2, b2, o2);

  // ---- pool + head (fused, gstart inline) ----
  pool_head_kernel<<<NG, 1024, 0, stream>>>(o2, batch, fcw, fcb, out);
}

// Round 7
// 268.830 us; speedup vs baseline: 1.2152x; 1.0412x over previous
//
#include <hip/hip_runtime.h>
#include <hip/hip_fp16.h>
#include <hip/hip_fp8.h>
#include <math.h>

// ---------------- problem constants ----------------
constexpr int NN   = 50000;          // nodes
constexpr int NE   = 800000;         // edges (before self loops)
constexpr int ETOT = NE + NN;        // 850000 with self loops
constexpr int F_IN = 128;
constexpr int HID  = 64;
constexpr int HEADS = 4;
constexpr int HC1  = HEADS * HID;    // 256
constexpr int NG   = 64;             // graphs
constexpr float SLOPE = 0.2f;
constexpr int TW_TOT = F_IN * HC1 + HC1 * HID;   // transpose work items (49152)
constexpr int CAP  = 128;            // bucket capacity per dst (max deg ~45 for this input)
constexpr int GEMM1_B = NN / 16;     // 3125 gemm blocks

// ---- atomic-free two-phase counting scatter ----
constexpr int CB_SHIFT = 7;                      // 128 dsts per coarse bucket
constexpr int NDB  = 1 << CB_SHIFT;              // 128
constexpr int NCB  = (NN + NDB - 1) >> CB_SHIFT; // 391 coarse buckets
constexpr int SEPB = 8192;                       // edges per scatter block
constexpr int SCAT_ITER = SEPB / (256 * 8);      // 4 macro-iterations
constexpr int NSB  = (ETOT + SEPB - 1) / SEPB;   // 104 scatter blocks

// h1/o1 channel permutation: group g = head*16 + lm (4 bytes tn=0..3),
// orig channel = head*64 + tn*16 + lm. Producer packs MFMA regs directly;
// consumers (gather4 groups, b1p, W2T K-axis) all use the same permutation.

typedef _Float16 half8 __attribute__((ext_vector_type(8)));
typedef float f32x4 __attribute__((ext_vector_type(4)));
typedef float f32x2 __attribute__((ext_vector_type(2)));

__device__ __forceinline__ float lrelu(float v) { return v >= 0.f ? v : SLOPE * v; }
__device__ __forceinline__ float elu(float v) { return v > 0.f ? v : expm1f(v); }

// ---- fp8 e4m3 helpers (OCP; gfx950 HW cvt when available) ----
__device__ __forceinline__ unsigned pack_fp8x4(float a, float b, float c, float d) {
#if __has_builtin(__builtin_amdgcn_cvt_pk_fp8_f32)
  int v = 0;
  v = __builtin_amdgcn_cvt_pk_fp8_f32(a, b, v, false);
  v = __builtin_amdgcn_cvt_pk_fp8_f32(c, d, v, true);
  return (unsigned)v;
#else
  __hip_fp8_e4m3 fa(a), fb(b), fc(c), fd(d);
  return (unsigned)fa.__x | ((unsigned)fb.__x << 8) |
         ((unsigned)fc.__x << 16) | ((unsigned)fd.__x << 24);
#endif
}

__device__ __forceinline__ float fp8_1(unsigned byte) {   // manual e4m3fn -> f32
  unsigned s = (byte & 0x80u) << 24;
  unsigned em = (byte & 0x7fu) << 20;
  return __uint_as_float(s | em) * 0x1p+120f;
}

// 4-channel fp8 accumulate: acA gets bytes{0,1}, acB gets bytes{2,3}.
__device__ __forceinline__ void agg_ch4(f32x2& acA, f32x2& acB, unsigned u, float al) {
#if __has_builtin(__builtin_amdgcn_cvt_pk_f32_fp8)
  f32x2 lo = __builtin_amdgcn_cvt_pk_f32_fp8((int)u, false);
  f32x2 hi = __builtin_amdgcn_cvt_pk_f32_fp8((int)u, true);
  f32x2 a2 = {al, al};
  asm("v_pk_fma_f32 %0, %1, %2, %0" : "+v"(acA) : "v"(lo), "v"(a2));
  asm("v_pk_fma_f32 %0, %1, %2, %0" : "+v"(acB) : "v"(hi), "v"(a2));
#else
  acA[0] += al * fp8_1(u & 0xffu);
  acA[1] += al * fp8_1((u >> 8) & 0xffu);
  acB[0] += al * fp8_1((u >> 16) & 0xffu);
  acB[1] += al * fp8_1(u >> 24);
#endif
}

// ---- edge macro-load: 8 edges per thread at e0 (ETOT%8==0, NE%8==0) ----
__device__ __forceinline__ void load_edges8(const int* __restrict__ esrc,
                                            const int* __restrict__ edst,
                                            int e0, int* sarr, int* darr) {
  if (e0 < NE) {
    int4 a = *(const int4*)(esrc + e0);
    int4 b = *(const int4*)(esrc + e0 + 4);
    int4 c = *(const int4*)(edst + e0);
    int4 d4 = *(const int4*)(edst + e0 + 4);
    sarr[0]=a.x; sarr[1]=a.y; sarr[2]=a.z; sarr[3]=a.w;
    sarr[4]=b.x; sarr[5]=b.y; sarr[6]=b.z; sarr[7]=b.w;
    darr[0]=c.x; darr[1]=c.y; darr[2]=c.z; darr[3]=c.w;
    darr[4]=d4.x; darr[5]=d4.y; darr[6]=d4.z; darr[7]=d4.w;
  } else {                                // self-loops
#pragma unroll
    for (int k = 0; k < 8; ++k) { sarr[k] = e0 - NE + k; darr[k] = sarr[k]; }
  }
}

// ================= prep: weight transposes + b1 permute ==============================
__global__ void prep_kernel(const float* __restrict__ W1, const float* __restrict__ W2,
                            const float* __restrict__ b1,
                            __half* __restrict__ W1T, __half* __restrict__ W2T,
                            float* __restrict__ b1p) {
  int i = blockIdx.x * blockDim.x + threadIdx.x;
  if (i < F_IN * HC1) {                       // W1 [128][256] -> W1T [256][128]
    int k = i / HC1, n = i - k * HC1;
    W1T[n * F_IN + k] = __float2half(W1[i]);
  } else if (i < TW_TOT) {                    // W2 [256][64] -> W2T [64][256], K permuted
    int j = i - F_IN * HC1;
    int k = j / HID, n = j - k * HID;
    // kp(k): head=k>>6, tn=(k>>4)&3, lm=k&15 -> g=head*16+lm, k' = g*4+tn
    int kp = (((k >> 6) * 16 + (k & 15)) << 2) | ((k >> 4) & 3);
    W2T[n * HC1 + kp] = __float2half(W2[j]);
  } else if (i < TW_TOT + HC1) {
    int g4 = i - TW_TOT;
    int g = g4 >> 2, tn = g4 & 3;
    b1p[g4] = b1[(g >> 4) * 64 + tn * 16 + (g & 15)];
  }
}

// ================= mega kernel: atomic-free scatter blocks || gemm1 blocks ===========
__global__ __launch_bounds__(256) void gemm1_scatter_kernel(
    const float* __restrict__ x, const __half* __restrict__ W1T,
    const float* __restrict__ asrc, const float* __restrict__ adst,
    unsigned char* __restrict__ h1, float* __restrict__ ssrc, float* __restrict__ sdst,
    const int* __restrict__ esrc, const int* __restrict__ edst,
    int* __restrict__ blockcnt, int* __restrict__ blockoff, int* __restrict__ scmp) {
  const int t = threadIdx.x;
  if (blockIdx.x < NSB) {
    // ---- phase-1: block-local segmented scatter, ZERO global atomics ----
    __shared__ int hist[512];     // coarse histogram (padded to 512 for scan)
    __shared__ int buf2[512];     // scan double-buffer / base
    __shared__ int cursor[512];   // per-cb write cursor
    for (int i = t; i < 512; i += 256) { hist[i] = 0; cursor[i] = 0; }
    __syncthreads();
    const int ebase = blockIdx.x * SEPB;
    // pass A: histogram
    for (int it = 0; it < SCAT_ITER; ++it) {
      int e0 = ebase + it * 2048 + t * 8;
      if (e0 < ETOT) {
        int sarr[8], darr[8];
        load_edges8(esrc, edst, e0, sarr, darr);
#pragma unroll
        for (int k = 0; k < 8; ++k) atomicAdd(&hist[darr[k] >> CB_SHIFT], 1);
      }
    }
    __syncthreads();
    // per-block counts out (coalesced)
    for (int i = t; i < NCB; i += 256) blockcnt[blockIdx.x * NCB + i] = hist[i];
    // Hillis-Steele inclusive scan over 512 entries
    int* src = hist; int* dst = buf2;
    for (int off = 1; off < 512; off <<= 1) {
      for (int i = t; i < 512; i += 256) {
        int v = src[i];
        if (i >= off) v += src[i - off];
        dst[i] = v;
      }
      __syncthreads();
      int* tmp = src; src = dst; dst = tmp;
    }
    // exclusive base into dst; offsets out
    for (int i = t; i < NCB; i += 256) {
      int b = (i == 0) ? 0 : src[i - 1];
      dst[i] = b;
      blockoff[blockIdx.x * NCB + i] = ebase + b;
    }
    __syncthreads();
    // pass B: reload edges (L2-hot) and pack grouped-by-cb into own segment
    for (int it = 0; it < SCAT_ITER; ++it) {
      int e0 = ebase + it * 2048 + t * 8;
      if (e0 < ETOT) {
        int sarr[8], darr[8];
        load_edges8(esrc, edst, e0, sarr, darr);
#pragma unroll
        for (int k = 0; k < 8; ++k) {
          int d = darr[k];
          int cb = d >> CB_SHIFT;
          int pkv = sarr[k] | ((d & (NDB - 1)) << 16);   // src < 65536 fits 16 bits
          int slot = dst[cb] + atomicAdd(&cursor[cb], 1);  // LDS only
          scmp[ebase + slot] = pkv;                        // dense, own segment
        }
      }
    }
    return;
  }
  // ---- gemm1 part: NO LDS, scores + fp8 pack straight from MFMA registers ----
  const int m0 = (blockIdx.x - NSB) * 16;
  const int wv = t >> 6, lane = t & 63;
  const int lm = lane & 15, quad = lane >> 4;
  const int n0 = wv * 64;       // wave wv owns head wv's 64 channels
  f32x4 acc[4] = {{0.f,0.f,0.f,0.f},{0.f,0.f,0.f,0.f},{0.f,0.f,0.f,0.f},{0.f,0.f,0.f,0.f}};
  const float* arow = x + (size_t)(m0 + lm) * F_IN + quad * 8;
#pragma unroll
  for (int kc = 0; kc < F_IN; kc += 32) {
    float4 u = *(const float4*)(arow + kc);
    float4 v = *(const float4*)(arow + kc + 4);
    half8 a;
    a[0]=(_Float16)u.x; a[1]=(_Float16)u.y; a[2]=(_Float16)u.z; a[3]=(_Float16)u.w;
    a[4]=(_Float16)v.x; a[5]=(_Float16)v.y; a[6]=(_Float16)v.z; a[7]=(_Float16)v.w;
#pragma unroll
    for (int tn = 0; tn < 4; ++tn) {
      half8 b = *(const half8*)(W1T + (size_t)(n0 + tn * 16 + lm) * F_IN + kc + quad * 8);
      acc[tn] = __builtin_amdgcn_mfma_f32_16x16x32_f16(a, b, acc[tn], 0, 0, 0);
    }
  }
  // acc[tn][r] = h[m0 + quad*4 + r][n0 + tn*16 + lm]
  // scores from registers: s[row][wv] = sum acc[tn][r] * a[n0+tn*16+lm], reduce over lm
  {
    float asv[4], adv[4];
#pragma unroll
    for (int tn = 0; tn < 4; ++tn) {
      asv[tn] = asrc[n0 + tn * 16 + lm];
      adv[tn] = adst[n0 + tn * 16 + lm];
    }
#pragma unroll
    for (int r = 0; r < 4; ++r) {
      float ps = acc[0][r] * asv[0] + acc[1][r] * asv[1]
               + acc[2][r] * asv[2] + acc[3][r] * asv[3];
      float pd = acc[0][r] * adv[0] + acc[1][r] * adv[1]
               + acc[2][r] * adv[2] + acc[3][r] * adv[3];
#pragma unroll
      for (int o = 1; o < 16; o <<= 1) {
        ps += __shfl_xor(ps, o, 64);
        pd += __shfl_xor(pd, o, 64);
      }
      if (lm == 0) {
        int row = m0 + quad * 4 + r;
        ssrc[row * HEADS + wv] = ps;
        sdst[row * HEADS + wv] = pd;
      }
    }
  }
  // h1 fp8 pack directly from registers into permuted layout:
  // group g = wv*16+lm, byte tn; addr = node*256 + g*4
  {
    const unsigned goff = (unsigned)((wv * 16 + lm) * 4);
#pragma unroll
    for (int r = 0; r < 4; ++r) {
      unsigned pk = pack_fp8x4(acc[0][r], acc[1][r], acc[2][r], acc[3][r]);
      *(unsigned*)(h1 + (size_t)(m0 + quad * 4 + r) * HC1 + goff) = pk;
    }
  }
}

// ================= phase-2: concatenate per-block runs into per-dst buckets =========
// One block per coarse bucket; wave w walks runs b = w, w+16, ...; LDS-only atomics.
__global__ __launch_bounds__(1024) void bucket_build_kernel(
    const int* __restrict__ blockcnt, const int* __restrict__ blockoff,
    const int* __restrict__ scmp, int* __restrict__ cnt, int* __restrict__ bucket) {
  __shared__ int hist2[NDB];
  const int cb = blockIdx.x, t = threadIdx.x;
  const int wv = t >> 6, lane = t & 63;
  if (t < NDB) hist2[t] = 0;
  __syncthreads();
  for (int b = wv; b < NSB; b += 16) {
    int n   = blockcnt[b * NCB + cb];
    int off = blockoff[b * NCB + cb];
    for (int j = lane; j < n; j += 64) {
      int v = scmp[off + j];
      int s = v & 0xFFFF, dlow = (v >> 16) & (NDB - 1);
      int l = atomicAdd(&hist2[dlow], 1);
      if (l < CAP) bucket[(size_t)((cb << CB_SHIFT) | dlow) * CAP + l] = s;
    }
  }
  __syncthreads();
  int d = (cb << CB_SHIFT) | t;
  if (t < NDB && d < NN) cnt[d] = hist2[t];
}

// ================= fused GAT gather, layer 1 (H=4, fp8 h, permuted channels) =========
// One wave per dst; lane owns group lane (4 channels). Bucket quads PREFETCHED into
// registers before softmax; agg loop statically unrolled (wave-uniform break).
__global__ __launch_bounds__(256) void gat_gather4_kernel(
    const int* __restrict__ cnt, const int* __restrict__ bucket,
    const float* __restrict__ ss, const float* __restrict__ sd,
    const unsigned char* __restrict__ h, const float* __restrict__ biasp,
    __half* __restrict__ outp) {
  __shared__ float paS[4][HEADS][40];    // [wave][head][slot], pitch 40 for bank spread
  const int wv   = threadIdx.x >> 6;
  const int lane = threadIdx.x & 63;
  const int d    = (blockIdx.x * 256 + threadIdx.x) >> 6;
  if (d >= NN) return;
  const int start = d * CAP;
  const int deg   = min(cnt[d], CAP);
  const int hsel  = lane & 3;            // score-phase head
  const int j0    = lane >> 2;           // score-phase edge
  const int head  = lane >> 4;           // agg-phase head of this lane's group
  const float sdv = sd[d * 4 + hsel];
  float (*pa)[40] = paS[wv];

  f32x2 acA = {0.f, 0.f}, acB = {0.f, 0.f};
  const unsigned char* hb = h + (unsigned)(lane * 4);

  if (deg <= 32) {
    // prefetch all 8 bucket quads up-front (in-bounds: CAP=128; pad slots get alpha 0)
    int4 svq[8];
#pragma unroll
    for (int q = 0; q < 8; ++q) svq[q] = *(const int4*)(bucket + start + q * 4);
    int s0 = 0, s1 = 0;
    float v0 = -INFINITY, v1 = -INFINITY;
    if (j0 < deg)      { s0 = bucket[start + j0];      v0 = lrelu(ss[s0 * 4 + hsel] + sdv); }
    if (j0 + 16 < deg) { s1 = bucket[start + j0 + 16]; v1 = lrelu(ss[s1 * 4 + hsel] + sdv); }
    float mx = fmaxf(v0, v1);
#pragma unroll
    for (int o = 4; o < 64; o <<= 1) mx = fmaxf(mx, __shfl_xor(mx, o, 64));
    float p0 = (j0 < deg)      ? __expf(v0 - mx) : 0.f;
    float p1 = (j0 + 16 < deg) ? __expf(v1 - mx) : 0.f;
    float den = p0 + p1;
#pragma unroll
    for (int o = 4; o < 64; o <<= 1) den += __shfl_xor(den, o, 64);
    const float inv = 1.f / (den + 1e-16f);
    pa[hsel][j0]      = p0 * inv;        // zeros where invalid -> pad slots are 0
    pa[hsel][j0 + 16] = p1 * inv;
    const int nq = (deg + 3) >> 2;
#pragma unroll
    for (int q = 0; q < 8; ++q) {
      if (q >= nq) break;                // wave-uniform exit; q compile-time per block
      float4 av = *(const float4*)&pa[head][q * 4];
      {
        unsigned sj = min((unsigned)svq[q].x, (unsigned)(NN - 1));
        agg_ch4(acA, acB, *(const unsigned*)(hb + (sj << 8)), av.x);
      }
      {
        unsigned sj = min((unsigned)svq[q].y, (unsigned)(NN - 1));
        agg_ch4(acA, acB, *(const unsigned*)(hb + (sj << 8)), av.y);
      }
      {
        unsigned sj = min((unsigned)svq[q].z, (unsigned)(NN - 1));
        agg_ch4(acA, acB, *(const unsigned*)(hb + (sj << 8)), av.z);
      }
      {
        unsigned sj = min((unsigned)svq[q].w, (unsigned)(NN - 1));
        agg_ch4(acA, acB, *(const unsigned*)(hb + (sj << 8)), av.w);
      }
    }
  } else {
    // chunked (rare): 16 edges per chunk, alphas staged per chunk
    float mx = -INFINITY;
    for (int base = 0; base < deg; base += 16) {
      int j = base + j0;
      float v = (j < deg) ? lrelu(ss[bucket[start + j] * 4 + hsel] + sdv) : -INFINITY;
#pragma unroll
      for (int o = 4; o < 64; o <<= 1) v = fmaxf(v, __shfl_xor(v, o, 64));
      mx = fmaxf(mx, v);
    }
    float den = 0.f;
    for (int base = 0; base < deg; base += 16) {
      int j = base + j0;
      float p = (j < deg) ? __expf(lrelu(ss[bucket[start + j] * 4 + hsel] + sdv) - mx) : 0.f;
#pragma unroll
      for (int o = 4; o < 64; o <<= 1) p += __shfl_xor(p, o, 64);
      den += p;
    }
    const float inv = 1.f / (den + 1e-16f);
    for (int base = 0; base < deg; base += 16) {
      int j = base + j0;
      float pav = 0.f;
      if (j < deg) pav = __expf(lrelu(ss[bucket[start + j] * 4 + hsel] + sdv) - mx) * inv;
      pa[hsel][j0] = pav;
      const int m  = min(16, deg - base);
      const int nq = (m + 3) >> 2;
      for (int q = 0; q < nq; ++q) {
        int4   sv = *(const int4*)(bucket + start + base + q * 4);
        float4 av = *(const float4*)&pa[head][q * 4];
        {
          unsigned sj = min((unsigned)sv.x, (unsigned)(NN - 1));
          agg_ch4(acA, acB, *(const unsigned*)(hb + (sj << 8)), av.x);
        }
        {
          unsigned sj = min((unsigned)sv.y, (unsigned)(NN - 1));
          agg_ch4(acA, acB, *(const unsigned*)(hb + (sj << 8)), av.y);
        }
        {
          unsigned sj = min((unsigned)sv.z, (unsigned)(NN - 1));
          agg_ch4(acA, acB, *(const unsigned*)(hb + (sj << 8)), av.z);
        }
        {
          unsigned sj = min((unsigned)sv.w, (unsigned)(NN - 1));
          agg_ch4(acA, acB, *(const unsigned*)(hb + (sj << 8)), av.w);
        }
      }
    }
  }
  // epilogue: permuted bias + elu + fp16 store (permuted o1), 8B/lane contiguous
  float4 bv = *(const float4*)(biasp + lane * 4);
  float e0 = elu(acA[0] + bv.x), e1 = elu(acA[1] + bv.y);
  float e2 = elu(acB[0] + bv.z), e3 = elu(acB[1] + bv.w);
  union { __half2 h2[2]; uint2 u; } pk;
  pk.h2[0] = __floats2half2_rn(e0, e1);
  pk.h2[1] = __floats2half2_rn(e2, e3);
  *(uint2*)(outp + (size_t)d * HC1 + lane * 4) = pk.u;
}

// ================= fused GAT gather, layer 2 (H=1, fp8 h): NO LDS ====================
// One wave per dst; srcs+alphas live in registers, broadcast via __shfl from lane=slot.
__global__ __launch_bounds__(256) void gat_gather1_kernel(
    const int* __restrict__ cnt, const int* __restrict__ bucket,
    const float* __restrict__ ss, const float* __restrict__ sd,
    const unsigned char* __restrict__ h, const float* __restrict__ bias,
    float* __restrict__ outp) {
  const int lane = threadIdx.x & 63;
  const int d    = (blockIdx.x * 256 + threadIdx.x) >> 6;
  if (d >= NN) return;
  const int start = d * CAP;
  const int deg   = min(cnt[d], CAP);
  const int eg    = lane >> 4;    // edge subgroup (0..3)
  const int cpos  = lane & 15;    // 4B chunk within 64B fp8 row
  const float sdv = sd[d];
  f32x2 acA = {0.f, 0.f}, acB = {0.f, 0.f};
  const unsigned char* hb = h + (unsigned)(cpos * 4);

  if (deg <= 64) {
    int s = 0; float v = -INFINITY;
    if (lane < deg) { s = bucket[start + lane]; v = lrelu(ss[s] + sdv); }
    float mx = v;
#pragma unroll
    for (int o = 1; o < 64; o <<= 1) mx = fmaxf(mx, __shfl_xor(mx, o, 64));
    float p = (lane < deg) ? __expf(v - mx) : 0.f;
    float den = p;
#pragma unroll
    for (int o = 1; o < 64; o <<= 1) den += __shfl_xor(den, o, 64);
    const float par = p / (den + 1e-16f);   // 0 for lanes >= deg -> pad alpha 0
    const int nq = (deg + 3) >> 2;
#pragma unroll
    for (int q = 0; q < 16; ++q) {
      if (q >= nq) break;                   // wave-uniform exit
      int slot = q * 4 + eg;
      float al = __shfl(par, slot, 64);     // 0 automatically when slot >= deg
      int   sj = __shfl(s, slot, 64);       // 0 (valid row) when slot >= deg
      unsigned sc = min((unsigned)sj, (unsigned)(NN - 1));
      agg_ch4(acA, acB, *(const unsigned*)(hb + (sc << 6)), al);
    }
  } else {
    float mx = -INFINITY;
    for (int base = 0; base < deg; base += 64) {
      int j = base + lane;
      float v = (j < deg) ? lrelu(ss[bucket[start + j]] + sdv) : -INFINITY;
#pragma unroll
      for (int o = 1; o < 64; o <<= 1) v = fmaxf(v, __shfl_xor(v, o, 64));
      mx = fmaxf(mx, v);
    }
    float den = 0.f;
    for (int base = 0; base < deg; base += 64) {
      int j = base + lane;
      float p = (j < deg) ? __expf(lrelu(ss[bucket[start + j]] + sdv) - mx) : 0.f;
#pragma unroll
      for (int o = 1; o < 64; o <<= 1) p += __shfl_xor(p, o, 64);
      den += p;
    }
    const float inv = 1.f / (den + 1e-16f);
    for (int base = 0; base < deg; base += 64) {
      int j = base + lane;
      int s = 0; float par = 0.f;
      if (j < deg) { s = bucket[start + j]; par = __expf(lrelu(ss[s] + sdv) - mx) * inv; }
      int cnt2 = min(64, deg - base);
      int nq = (cnt2 + 3) >> 2;
      for (int q = 0; q < nq; ++q) {
        int slot = q * 4 + eg;
        float al = (slot < cnt2) ? __shfl(par, slot, 64) : 0.f;
        int   sj = __shfl(s, slot < 63 ? slot : 63, 64);
        unsigned sc = min((unsigned)sj, (unsigned)(NN - 1));
        agg_ch4(acA, acB, *(const unsigned*)(hb + (sc << 6)), al);
      }
    }
  }
  // combine the 4 edge subgroups (2 shuffle rounds)
#pragma unroll
  for (int o = 16; o < 64; o <<= 1) {
    f32x2 tv;
    tv[0] = __shfl_xor(acA[0], o, 64); tv[1] = __shfl_xor(acA[1], o, 64); acA += tv;
    tv[0] = __shfl_xor(acB[0], o, 64); tv[1] = __shfl_xor(acB[1], o, 64); acB += tv;
  }
  if (eg == 0) {
    float4 bv = *(const float4*)(bias + cpos * 4);
    float4 r;
    r.x = elu(acA[0] + bv.x);
    r.y = elu(acA[1] + bv.y);
    r.z = elu(acB[0] + bv.z);
    r.w = elu(acB[1] + bv.w);
    *(float4*)(outp + (size_t)d * HID + cpos * 4) = r;
  }
}

// ================= gemm2 (MFMA): consumes permuted o1/W2T; output h2 unpermuted ======
__global__ __launch_bounds__(256) void gemm2_mfma(
    const __half* __restrict__ o1h, const __half* __restrict__ W2T,
    const float* __restrict__ asrc, const float* __restrict__ adst,
    unsigned char* __restrict__ h2, float* __restrict__ ssrc, float* __restrict__ sdst) {
  __shared__ float hs[16][HID + 1];
  const int m0 = blockIdx.x * 16;
  const int t = threadIdx.x;
  const int wv = t >> 6, lane = t & 63;
  const int lm = lane & 15, quad = lane >> 4;
  f32x4 acc = {0.f, 0.f, 0.f, 0.f};
  const __half* arow = o1h + (size_t)(m0 + lm) * HC1 + quad * 8;
#pragma unroll
  for (int kc = 0; kc < HC1; kc += 32) {
    half8 a = *(const half8*)(arow + kc);
    half8 b = *(const half8*)(W2T + (size_t)(wv * 16 + lm) * HC1 + kc + quad * 8);
    acc = __builtin_amdgcn_mfma_f32_16x16x32_f16(a, b, acc, 0, 0, 0);
  }
#pragma unroll
  for (int r = 0; r < 4; ++r)
    hs[quad * 4 + r][wv * 16 + lm] = acc[r];
  __syncthreads();
  {
    int row = t >> 4, c4 = (t & 15) * 4;
    unsigned pk = pack_fp8x4(hs[row][c4], hs[row][c4 + 1], hs[row][c4 + 2], hs[row][c4 + 3]);
    *(unsigned*)(h2 + (size_t)(m0 + row) * HID + c4) = pk;
  }
  if (t < 64) {
    int task = t >> 1, part = t & 1;
    int r = task >> 1, isdst = task & 1;
    const float* a = isdst ? adst : asrc;
    float s = 0.f;
    int c0 = part * 32;
    for (int c = c0; c < c0 + 32; ++c) s += hs[r][c] * a[c];
    s += __shfl_xor(s, 1, 64);
    if (part == 0) (isdst ? sdst : ssrc)[m0 + r] = s;
  }
}

// ---------------- fused pool + FC + log_softmax (gstart inline): one block/graph -------
__global__ __launch_bounds__(1024) void pool_head_kernel(const float* __restrict__ o2,
                                                         const int* __restrict__ batch,
                                                         const float* __restrict__ fcw,
                                                         const float* __restrict__ fcb,
                                                         float* __restrict__ out) {
  __shared__ float red[16][HID];
  __shared__ int sbound[2];
  int g = blockIdx.x;
  int t = threadIdx.x;
  if (t < 2) {                         // graph boundaries via binary search
    int gg = g + t, lo = 0, hi = NN;
    while (lo < hi) { int mid = (lo + hi) >> 1; if (batch[mid] < gg) lo = mid + 1; else hi = mid; }
    sbound[t] = lo;
  }
  __syncthreads();
  int s0 = sbound[0], s1 = sbound[1];
  int c = t & 63, r = t >> 6;          // 16 node-rows in flight
  float acc = 0.f;
  for (int n = s0 + r; n < s1; n += 16) acc += o2[(size_t)n * HID + c];
  red[r][c] = acc;
  __syncthreads();
  if (r == 0) {                        // threads 0..63 = one wave
    float v = 0.f;
#pragma unroll
    for (int k = 0; k < 16; ++k) v += red[k][c];
    v /= fmaxf((float)(s1 - s0), 1.f);
    float p0 = v * fcw[c * 2 + 0];
    float p1 = v * fcw[c * 2 + 1];
#pragma unroll
    for (int o = 1; o < 64; o <<= 1) {
      p0 += __shfl_xor(p0, o, 64);
      p1 += __shfl_xor(p1, o, 64);
    }
    if (c == 0) {
      float l0 = p0 + fcb[0], l1 = p1 + fcb[1];
      float mx = fmaxf(l0, l1);
      float lse = mx + logf(expf(l0 - mx) + expf(l1 - mx));
      out[g * 2 + 0] = l0 - lse;
      out[g * 2 + 1] = l1 - lse;
    }
  }
}

// ---------------- launch ----------------
extern "C" void kernel_launch(void* const* d_in, const int* in_sizes, int n_in,
                              void* d_out, int out_size, void* d_ws, size_t ws_size,
                              hipStream_t stream) {
  const float* x    = (const float*)d_in[0];
  const int*   ei   = (const int*)d_in[1];
  const int*   batch= (const int*)d_in[2];
  const float* W1   = (const float*)d_in[3];
  const float* as1  = (const float*)d_in[4];
  const float* ad1  = (const float*)d_in[5];
  const float* b1   = (const float*)d_in[6];
  const float* W2   = (const float*)d_in[7];
  const float* as2  = (const float*)d_in[8];
  const float* ad2  = (const float*)d_in[9];
  const float* b2   = (const float*)d_in[10];
  const float* fcw  = (const float*)d_in[11];
  const float* fcb  = (const float*)d_in[12];
  float* out = (float*)d_out;
  float* ws  = (float*)d_ws;

  const int* esrc = ei;
  const int* edst = ei + NE;

  // ---- workspace layout (float units) ----
  size_t off = 0;
  float* hreg  = ws + off; off += (size_t)NN * HC1 / 4;  // h1 fp8 [NN,256] (permuted ch)
  float* o1reg = ws + off; off += (size_t)NN * HC1 / 2;  // o1 fp16 [NN,256] (permuted ch)
  float* l2reg = ws + off; off += (size_t)NN * HC1 / 2;  // h2 fp8 + o2 fp32 (also scmp, earlier)
  float* ss1 = ws + off; off += (size_t)NN * HEADS;
  float* sd1 = ws + off; off += (size_t)NN * HEADS;
  float* ss2 = ws + off; off += NN;
  float* sd2 = ws + off; off += NN;
  __half* W1T = (__half*)(ws + off); off += (size_t)HC1 * F_IN / 2;
  __half* W2T = (__half*)(ws + off); off += (size_t)HID * HC1 / 2;
  float* b1p  = ws + off; off += HC1;                    // permuted bias1
  int* bucket = (int*)(ws + off); off += (size_t)NN * CAP;   // 25.6 MB
  int* cnt    = (int*)(ws + off); off += NN;                 // fully written by phase-2
  unsigned char* h1 = (unsigned char*)hreg;            // [NN, 256] fp8 e4m3 (permuted)
  __half* o1h = (__half*)o1reg;                        // [NN, 256] fp16 (permuted)
  unsigned char* h2 = (unsigned char*)l2reg;           // [NN, 64] fp8 e4m3
  float*  o2  = l2reg + (size_t)NN * HID / 4;          // [NN, 64] fp32
  // scatter staging aliases l2reg (dead until gemm2): 3.4 + 0.33 MB < 25.6 MB
  int* scmp     = (int*)l2reg;                         // [ETOT] packed (src | dlow<<16)
  int* blockcnt = (int*)l2reg + ETOT;                  // [NSB][NCB]
  int* blockoff = blockcnt + (size_t)NSB * NCB;        // [NSB][NCB]

  // ---- prep: transposes + b1 permute (no counter zeroing needed) ----
  prep_kernel<<<(TW_TOT + HC1 + 255) / 256, 256, 0, stream>>>(
      W1, W2, b1, W1T, W2T, b1p);

  // ---- phase-1 atomic-free scatter || layer-1 GEMM (independent; co-scheduled) ----
  gemm1_scatter_kernel<<<NSB + GEMM1_B, 256, 0, stream>>>(
      x, W1T, as1, ad1, h1, ss1, sd1, esrc, edst, blockcnt, blockoff, scmp);

  // ---- phase-2: run-concatenating bucket build (one block per coarse bucket) ----
  bucket_build_kernel<<<NCB, 1024, 0, stream>>>(blockcnt, blockoff, scmp, cnt, bucket);

  // ---- layer 1 gather ----
  gat_gather4_kernel<<<(NN + 3) / 4, 256, 0, stream>>>(cnt, bucket, ss1, sd1, h1, b1p, o1h);

  // ---- layer 2 ----
  gemm2_mfma<<<NN / 16, 256, 0, stream>>>(o1h, W2T, as2, ad2, h2, ss2, sd2);
  gat_gather1_kernel<<<(NN + 3) / 4, 256, 0, stream>>>(cnt, bucket, ss2, sd2, h2, b2, o2);

  // ---- pool + head (fused, gstart inline) ----
  pool_head_kernel<<<NG, 1024, 0, stream>>>(o2, batch, fcw, fcb, out);
}